// Round 3
// baseline (303976.611 us; speedup 1.0000x reference)
//
#include <hip/hip_runtime.h>
#include <hip/hip_fp16.h>
#include <math.h>

// betaChessAI forward: 10 blocks of {conv-bn-conv-bn residual, windowed attention, MLP}
// Layouts:
//   spatial activations: act[(b*64 + p)*128 + c], p = y*8+x   (== feat layout for head)
//   token activations:   t[(b*16 + n)*512 + d],  d = (p1*2+p2)*128 + c, n = hy*4+wx
//   mapping: (y,x) = (2*hy+p1, 2*wx+p2)
// Workspace (float slots), ~213 MB total:
//   act f32 (33.55M) | z1 fp16 (16.78M slots) | wT1 13824 | wTa 1.47M | wTb 1.47M | stats 256 | bnp 256
//   head reuses z1 region: L1 (4.19M f32) + logits (2.62M f32)

#define NBATCH 4096
#define NPOSR  (NBATCH*64)

#define OFF_ACT   0
#define OFF_Z1H   33554432              // float-slot offset; holds 33,554,432 halfs
#define OFF_WT1   (OFF_Z1H + 16777216)
#define OFF_WTA   (OFF_WT1 + 13824)
#define OFF_WTB   (OFF_WTA + 1474560)
#define OFF_STATS (OFF_WTB + 1474560)
#define OFF_BNP   (OFF_STATS + 256)
#define WS_NEED_FLOATS (OFF_BNP + 256)

__device__ inline float4 ld_half4(const __half* p) {
  float2 a = __half22float2(*(const __half2*)p);
  float2 b = __half22float2(*(const __half2*)(p + 2));
  return make_float4(a.x, a.y, b.x, b.y);
}

// ---------------- utility ----------------
__global__ void k_zero(float* __restrict__ s) { s[threadIdx.x] = 0.f; }

__global__ void k_sentinel(float* __restrict__ out, int n, float val) {
  for (int i = blockIdx.x*blockDim.x + threadIdx.x; i < n; i += gridDim.x*blockDim.x)
    out[i] = val;
}

// src[l][co][ci][kk] (co=128,kk=9) -> dst[l][(kk*Cin+ci)*128+co]
__global__ void k_wprep(const float* __restrict__ src, float* __restrict__ dst, int L, int Cin) {
  int total = L * 128 * Cin * 9;
  for (int idx = blockIdx.x*blockDim.x + threadIdx.x; idx < total; idx += gridDim.x*blockDim.x) {
    int kk = idx % 9; int t2 = idx / 9;
    int ci = t2 % Cin; t2 /= Cin;
    int co = t2 % 128; int l  = t2 / 128;
    dst[((size_t)(l*9 + kk)*Cin + ci)*128 + co] = src[idx];
  }
}

// ---------------- encode + conv1 (one-hot lookup), output f32 act ----------------
__global__ __launch_bounds__(256) void k_conv1(const int* __restrict__ xin,
    const float* __restrict__ wT1, const float* __restrict__ b1,
    float* __restrict__ out) {
  __shared__ int s_w[64], s_b[64];
  int b = blockIdx.x, t = threadIdx.x;
  if (t < 64) { s_w[t] = xin[b*128 + t]; s_b[t] = xin[b*128 + 64 + t]; }
  __syncthreads();
  int p = t >> 2, i = t & 3;           // 64 positions x 4 groups of 32 channels
  int y = p >> 3, x = p & 7;
  float acc[32];
  #pragma unroll
  for (int j = 0; j < 32; ++j) acc[j] = b1[i*32 + j];
  #pragma unroll
  for (int kk = 0; kk < 9; ++kk) {
    int ny = y + kk/3 - 1, nx = x + kk%3 - 1;
    if (ny < 0 || ny > 7 || nx < 0 || nx > 7) continue;
    int np = ny*8 + nx;
    int wp = s_w[np], bp = s_b[np];
    if (wp >= 1 && wp <= 6) {
      const float* w = &wT1[(size_t)(kk*12 + (wp-1))*128 + i*32];
      #pragma unroll
      for (int j = 0; j < 32; ++j) acc[j] += w[j];
    }
    if (bp >= 1 && bp <= 6) {
      const float* w = &wT1[(size_t)(kk*12 + 6 + (bp-1))*128 + i*32];
      #pragma unroll
      for (int j = 0; j < 32; ++j) acc[j] += w[j];
    }
  }
  float* o = &out[((size_t)b*64 + p)*128 + i*32];
  #pragma unroll
  for (int j = 0; j < 8; ++j)
    *(float4*)&o[j*4] = make_float4(acc[j*4], acc[j*4+1], acc[j*4+2], acc[j*4+3]);
}

// ---------------- residual 3x3 conv: out(h16) = conv3x3(relu(bn?(in))) + bias ----------------
// Safe for in == out: full image staged to LDS before any write.
__device__ inline float cvt_in(float v) { return v; }
__device__ inline float cvt_in(__half v) { return __half2float(v); }

template<typename TIN>
__global__ __launch_bounds__(512) void k_conv(const TIN* __restrict__ in,
    const float* __restrict__ wT, const float* __restrict__ bias,
    const float* __restrict__ bnp, int use_bn, __half* __restrict__ out) {
  __shared__ float s_in[64*132];       // stride 132: kills 8-way bank conflict
  int b = blockIdx.x, t = threadIdx.x;
  const TIN* gin = &in[(size_t)b*8192];
  for (int idx = t; idx < 8192; idx += 512) {
    int row = idx >> 7, ci = idx & 127;
    float v = cvt_in(gin[idx]);
    if (use_bn) v = bnp[ci]*v + bnp[128+ci];
    s_in[row*132 + ci] = fmaxf(v, 0.f);
  }
  __syncthreads();
  int p = t >> 3, i = t & 7;           // 64 positions x 8 groups of 16 channels
  int y = p >> 3, x = p & 7;
  float acc[16];
  #pragma unroll
  for (int j = 0; j < 16; ++j) acc[j] = bias[i*16 + j];
  #pragma unroll
  for (int kk = 0; kk < 9; ++kk) {
    int ny = y + kk/3 - 1, nx = x + kk%3 - 1;
    if (ny < 0 || ny > 7 || nx < 0 || nx > 7) continue;
    const float* sv = &s_in[(ny*8 + nx)*132];
    const float* wrow = &wT[(size_t)kk*16384 + i*16];
    for (int ci = 0; ci < 128; ++ci) {
      float a = sv[ci];
      const float4* w4 = (const float4*)(wrow + (size_t)ci*128);
      #pragma unroll
      for (int j = 0; j < 4; ++j) {
        float4 w = w4[j];
        acc[j*4+0] += a*w.x; acc[j*4+1] += a*w.y; acc[j*4+2] += a*w.z; acc[j*4+3] += a*w.w;
      }
    }
  }
  __half2* o = (__half2*)&out[(size_t)b*8192 + p*128 + i*16];
  #pragma unroll
  for (int j = 0; j < 8; ++j)
    o[j] = __floats2half2_rn(acc[j*2], acc[j*2+1]);
}

// ---------------- per-channel batch stats (sum, sumsq) over fp16 z ----------------
__global__ __launch_bounds__(256) void k_stats(const __half* __restrict__ z, float* __restrict__ stats) {
  int t = threadIdx.x;
  int c = t & 127, rl = t >> 7;        // 128 channels x 2 row lanes
  int r0 = blockIdx.x * 512;
  float s = 0.f, q = 0.f;
  for (int r = r0 + rl; r < r0 + 512; r += 2) {
    float v = __half2float(z[(size_t)r*128 + c]);
    s += v; q += v*v;
  }
  __shared__ float sh[256];
  sh[t] = s; __syncthreads();
  if (rl == 0) atomicAdd(&stats[c], sh[c] + sh[128+c]);
  __syncthreads();
  sh[t] = q; __syncthreads();
  if (rl == 0) atomicAdd(&stats[128+c], sh[c] + sh[128+c]);
}

// scale/shift from stats; re-zero stats for next use
__global__ void k_bnfin(float* __restrict__ stats, const float* __restrict__ g,
                        const float* __restrict__ bb, float* __restrict__ bnp) {
  int c = threadIdx.x;                 // 128 threads
  const float invN = 1.f / (float)NPOSR;
  float m = stats[c] * invN;
  float v = stats[128+c] * invN - m*m;
  float sc = g[c] * rsqrtf(v + 1e-5f);
  bnp[c] = sc;
  bnp[128+c] = bb[c] - m*sc;
  stats[c] = 0.f; stats[128+c] = 0.f;
}

// ---------------- fused attention per image (no global scratch) ----------------
// Stages t = window_partition(act + bn2(z1h)) + pos into LDS; computes
// t2 = t + LN(attn(t)@Wp + bp); writes t2 into act image region (TOKEN layout).
__global__ __launch_bounds__(512) void k_attn(const float* __restrict__ actG,
    const __half* __restrict__ z1G, const float* __restrict__ bnp,
    const float* __restrict__ pos,
    const float* __restrict__ Wqkv, const float* __restrict__ bqkv,
    const float* __restrict__ Wp, const float* __restrict__ bpv,
    float* __restrict__ t2G /* = act */) {
  __shared__ float  s_t[8192];         // 32 KB
  __shared__ float  s_q[16*64];        // 4 KB
  __shared__ float  s_k[16*65];        // 4.06 KB (padded rows)
  __shared__ __half s_v[16*64];        // 2 KB
  __shared__ float  s_S[256];          // 1 KB
  __shared__ __half s_o[16*512];       // 16 KB   (total 60.5 KB)
  int b = blockIdx.x, t = threadIdx.x;
  // staging: build t in token layout
  for (int idx4 = t; idx4 < 2048; idx4 += 512) {
    int n = idx4 >> 7, d4 = idx4 & 127;
    int d = d4*4, c = d & 127, q = d >> 7;
    int y = ((n>>2)<<1) + (q>>1), xx = ((n&3)<<1) + (q&1);
    size_t sp = ((size_t)b*64 + y*8 + xx)*128 + c;
    float4 a  = *(const float4*)&actG[sp];
    float4 z  = ld_half4(&z1G[sp]);
    float4 sc = *(const float4*)&bnp[c];
    float4 sh = *(const float4*)&bnp[128+c];
    float4 pe = *(const float4*)&pos[n*512 + d];
    float4 o;
    o.x = a.x + sc.x*z.x + sh.x + pe.x;
    o.y = a.y + sc.y*z.y + sh.y + pe.y;
    o.z = a.z + sc.z*z.z + sh.z + pe.z;
    o.w = a.w + sc.w*z.w + sh.w + pe.w;
    *(float4*)&s_t[n*512 + d] = o;
  }
  __syncthreads();
  int tok = t >> 5, i = t & 31;
  const float* trow = &s_t[tok*512];
  for (int h = 0; h < 8; ++h) {
    int col = h*64 + 2*i;
    float aq0=0,aq1=0,ak0=0,ak1=0,av0=0,av1=0;
    for (int k = 0; k < 512; ++k) {
      float a = trow[k];
      const float* wr = &Wqkv[(size_t)k*1536 + col];
      float2 wq = *(const float2*)wr;
      float2 wk = *(const float2*)(wr + 512);
      float2 wv = *(const float2*)(wr + 1024);
      aq0 += a*wq.x; aq1 += a*wq.y;
      ak0 += a*wk.x; ak1 += a*wk.y;
      av0 += a*wv.x; av1 += a*wv.y;
    }
    s_q[tok*64 + 2*i]   = (aq0 + bqkv[col])   * 0.125f;   // hd^-0.5
    s_q[tok*64 + 2*i+1] = (aq1 + bqkv[col+1]) * 0.125f;
    s_k[tok*65 + 2*i]   = ak0 + bqkv[512+col];
    s_k[tok*65 + 2*i+1] = ak1 + bqkv[512+col+1];
    *(__half2*)&s_v[tok*64 + 2*i] = __floats2half2_rn(av0 + bqkv[1024+col], av1 + bqkv[1024+col+1]);
    __syncthreads();
    if (t < 256) {
      int qi = t >> 4, ki = t & 15;
      float s = 0.f;
      #pragma unroll
      for (int d = 0; d < 64; ++d) s += s_q[qi*64 + d] * s_k[ki*65 + d];
      s_S[t] = s;
    }
    __syncthreads();
    if (t < 16) {
      float mx = -1e30f;
      #pragma unroll
      for (int ki = 0; ki < 16; ++ki) mx = fmaxf(mx, s_S[t*16+ki]);
      float e[16]; float sm = 0.f;
      #pragma unroll
      for (int ki = 0; ki < 16; ++ki) { e[ki] = expf(s_S[t*16+ki] - mx); sm += e[ki]; }
      float inv = 1.f / sm;
      #pragma unroll
      for (int ki = 0; ki < 16; ++ki) s_S[t*16+ki] = e[ki]*inv;
    }
    __syncthreads();
    {
      int o = t*2; int qi = o >> 6; int dh = o & 63;
      float a0 = 0.f, a1 = 0.f;
      #pragma unroll
      for (int ki = 0; ki < 16; ++ki) {
        float s = s_S[qi*16 + ki];
        float2 v2 = __half22float2(*(const __half2*)&s_v[ki*64 + dh]);
        a0 += s*v2.x; a1 += s*v2.y;
      }
      *(__half2*)&s_o[qi*512 + h*64 + dh] = __floats2half2_rn(a0, a1);
    }
    __syncthreads();
  }
  // proj + LN + residual (reads s_o from LDS)
  float acc[16];
  #pragma unroll
  for (int j = 0; j < 16; ++j) acc[j] = 0.f;
  const __half2* orow = (const __half2*)&s_o[tok*512];
  for (int k2 = 0; k2 < 256; ++k2) {
    float2 a2 = __half22float2(orow[k2]);
    const float* wr0 = &Wp[(size_t)(2*k2)*512];
    const float* wr1 = &Wp[(size_t)(2*k2+1)*512];
    #pragma unroll
    for (int j = 0; j < 4; ++j) {
      float4 w0 = *(const float4*)&wr0[j*128 + i*4];
      float4 w1 = *(const float4*)&wr1[j*128 + i*4];
      acc[j*4+0] += a2.x*w0.x + a2.y*w1.x;
      acc[j*4+1] += a2.x*w0.y + a2.y*w1.y;
      acc[j*4+2] += a2.x*w0.z + a2.y*w1.z;
      acc[j*4+3] += a2.x*w0.w + a2.y*w1.w;
    }
  }
  float s1 = 0.f, s2 = 0.f;
  #pragma unroll
  for (int j = 0; j < 4; ++j) {
    int c = j*128 + i*4;
    #pragma unroll
    for (int jj = 0; jj < 4; ++jj) {
      float v = acc[j*4+jj] + bpv[c+jj];
      acc[j*4+jj] = v;
      s1 += v; s2 += v*v;
    }
  }
  #pragma unroll
  for (int m = 16; m >= 1; m >>= 1) { s1 += __shfl_xor(s1, m); s2 += __shfl_xor(s2, m); }
  float mean = s1 * (1.f/512.f);
  float var  = s2 * (1.f/512.f) - mean*mean;
  float rs = rsqrtf(var + 1e-6f);
  #pragma unroll
  for (int j = 0; j < 4; ++j) {
    int c = j*128 + i*4;
    float4 tv = *(const float4*)&s_t[tok*512 + c];
    float4 o;
    o.x = tv.x + (acc[j*4+0] - mean)*rs;
    o.y = tv.y + (acc[j*4+1] - mean)*rs;
    o.z = tv.z + (acc[j*4+2] - mean)*rs;
    o.w = tv.w + (acc[j*4+3] - mean)*rs;
    *(float4*)&t2G[((size_t)b*16 + tok)*512 + c] = o;
  }
}

// ---------------- fused MLP per image + window_reverse (h1 in LDS) ----------------
// Reads t2 (TOKEN layout) from act image region, writes block output (SPATIAL) back.
__global__ __launch_bounds__(512) void k_mlp(const float* __restrict__ t2G,
    const float* __restrict__ W1, const float* __restrict__ b1v,
    const float* __restrict__ W2, const float* __restrict__ b2v,
    float* __restrict__ actout /* = act */) {
  __shared__ float  s_t[8192];         // 32 KB
  __shared__ __half s_h1[16*512];      // 16 KB
  int b = blockIdx.x, t = threadIdx.x;
  for (int idx = t; idx < 8192; idx += 512) s_t[idx] = t2G[(size_t)b*8192 + idx];
  __syncthreads();
  int tok = t >> 5, i = t & 31;
  float acc[16];
  #pragma unroll
  for (int j = 0; j < 16; ++j) acc[j] = 0.f;
  for (int k = 0; k < 512; ++k) {
    float a = s_t[tok*512 + k];
    #pragma unroll
    for (int j = 0; j < 4; ++j) {
      float4 w = *(const float4*)&W1[(size_t)k*512 + j*128 + i*4];
      acc[j*4+0] += a*w.x; acc[j*4+1] += a*w.y; acc[j*4+2] += a*w.z; acc[j*4+3] += a*w.w;
    }
  }
  #pragma unroll
  for (int j = 0; j < 4; ++j) {
    int c = j*128 + i*4;
    *(__half2*)&s_h1[tok*512 + c]     = __floats2half2_rn(fmaxf(acc[j*4+0] + b1v[c+0], 0.f),
                                                          fmaxf(acc[j*4+1] + b1v[c+1], 0.f));
    *(__half2*)&s_h1[tok*512 + c + 2] = __floats2half2_rn(fmaxf(acc[j*4+2] + b1v[c+2], 0.f),
                                                          fmaxf(acc[j*4+3] + b1v[c+3], 0.f));
  }
  __syncthreads();
  #pragma unroll
  for (int j = 0; j < 16; ++j) acc[j] = 0.f;
  const __half2* hrow = (const __half2*)&s_h1[tok*512];
  for (int k2 = 0; k2 < 256; ++k2) {
    float2 a2 = __half22float2(hrow[k2]);
    const float* wr0 = &W2[(size_t)(2*k2)*512];
    const float* wr1 = &W2[(size_t)(2*k2+1)*512];
    #pragma unroll
    for (int j = 0; j < 4; ++j) {
      float4 w0 = *(const float4*)&wr0[j*128 + i*4];
      float4 w1 = *(const float4*)&wr1[j*128 + i*4];
      acc[j*4+0] += a2.x*w0.x + a2.y*w1.x;
      acc[j*4+1] += a2.x*w0.y + a2.y*w1.y;
      acc[j*4+2] += a2.x*w0.z + a2.y*w1.z;
      acc[j*4+3] += a2.x*w0.w + a2.y*w1.w;
    }
  }
  float s1 = 0.f, s2 = 0.f;
  #pragma unroll
  for (int j = 0; j < 4; ++j) {
    int c = j*128 + i*4;
    #pragma unroll
    for (int jj = 0; jj < 4; ++jj) {
      float v = acc[j*4+jj] + b2v[c+jj];
      acc[j*4+jj] = v;
      s1 += v; s2 += v*v;
    }
  }
  #pragma unroll
  for (int m = 16; m >= 1; m >>= 1) { s1 += __shfl_xor(s1, m); s2 += __shfl_xor(s2, m); }
  float mean = s1 * (1.f/512.f);
  float var  = s2 * (1.f/512.f) - mean*mean;
  float rs = rsqrtf(var + 1e-6f);
  int hy = tok >> 2, wx = tok & 3;
  #pragma unroll
  for (int j = 0; j < 4; ++j) {
    int c = j*128 + i*4;
    int y = hy*2 + (j >> 1), xx = wx*2 + (j & 1);
    float4 tv = *(const float4*)&s_t[tok*512 + c];
    float4 o;
    o.x = tv.x + (acc[j*4+0] - mean)*rs;
    o.y = tv.y + (acc[j*4+1] - mean)*rs;
    o.z = tv.z + (acc[j*4+2] - mean)*rs;
    o.w = tv.w + (acc[j*4+3] - mean)*rs;
    *(float4*)&actout[((size_t)b*64 + y*8 + xx)*128 + i*4] = o;
  }
}

// ---------------- tiled fp32 GEMM: C = act(A@B + bias), 64x64 tiles ----------------
template<int ACT>
__global__ __launch_bounds__(256) void k_gemm(const float* __restrict__ A,
    const float* __restrict__ Bm, const float* __restrict__ bias,
    float* __restrict__ Cm, int M, int N, int K) {
  __shared__ float sA[16][64];
  __shared__ float sB[16][64];
  int bm = blockIdx.x*64, bn = blockIdx.y*64;
  int t = threadIdx.x;
  int tx = t & 15, ty = t >> 4;
  int ar = t >> 2, ak = (t & 3)*4;
  int br = t >> 4, bc = (t & 15)*4;
  float acc[4][4];
  #pragma unroll
  for (int a_ = 0; a_ < 4; ++a_)
    #pragma unroll
    for (int b_ = 0; b_ < 4; ++b_) acc[a_][b_] = 0.f;
  for (int k0 = 0; k0 < K; k0 += 16) {
    float4 av = *(const float4*)&A[(size_t)(bm + ar)*K + k0 + ak];
    float4 bv = *(const float4*)&Bm[(size_t)(k0 + br)*N + bn + bc];
    sA[ak+0][ar] = av.x; sA[ak+1][ar] = av.y; sA[ak+2][ar] = av.z; sA[ak+3][ar] = av.w;
    *(float4*)&sB[br][bc] = bv;
    __syncthreads();
    #pragma unroll
    for (int kk = 0; kk < 16; ++kk) {
      float4 a4 = *(const float4*)&sA[kk][ty*4];
      float4 b4 = *(const float4*)&sB[kk][tx*4];
      acc[0][0] += a4.x*b4.x; acc[0][1] += a4.x*b4.y; acc[0][2] += a4.x*b4.z; acc[0][3] += a4.x*b4.w;
      acc[1][0] += a4.y*b4.x; acc[1][1] += a4.y*b4.y; acc[1][2] += a4.y*b4.z; acc[1][3] += a4.y*b4.w;
      acc[2][0] += a4.z*b4.x; acc[2][1] += a4.z*b4.y; acc[2][2] += a4.z*b4.z; acc[2][3] += a4.z*b4.w;
      acc[3][0] += a4.w*b4.x; acc[3][1] += a4.w*b4.y; acc[3][2] += a4.w*b4.z; acc[3][3] += a4.w*b4.w;
    }
    __syncthreads();
  }
  #pragma unroll
  for (int ii = 0; ii < 4; ++ii) {
    float4 o;
    o.x = acc[ii][0] + bias[bn + tx*4 + 0];
    o.y = acc[ii][1] + bias[bn + tx*4 + 1];
    o.z = acc[ii][2] + bias[bn + tx*4 + 2];
    o.w = acc[ii][3] + bias[bn + tx*4 + 3];
    if (ACT) { o.x = fmaxf(o.x,0.f); o.y = fmaxf(o.y,0.f); o.z = fmaxf(o.z,0.f); o.w = fmaxf(o.w,0.f); }
    *(float4*)&Cm[(size_t)(bm + ty*4 + ii)*N + bn + tx*4] = o;
  }
}

// ---------------- row softmax (640) ----------------
__global__ __launch_bounds__(256) void k_softmax(const float* __restrict__ logits, float* __restrict__ out) {
  int b = blockIdx.x, t = threadIdx.x;
  __shared__ float red[256];
  float m = -1e30f;
  for (int j = t; j < 640; j += 256) m = fmaxf(m, logits[(size_t)b*640 + j]);
  red[t] = m; __syncthreads();
  for (int s = 128; s > 0; s >>= 1) { if (t < s) red[t] = fmaxf(red[t], red[t+s]); __syncthreads(); }
  m = red[0]; __syncthreads();
  float sum = 0.f;
  for (int j = t; j < 640; j += 256) sum += expf(logits[(size_t)b*640 + j] - m);
  red[t] = sum; __syncthreads();
  for (int s = 128; s > 0; s >>= 1) { if (t < s) red[t] += red[t+s]; __syncthreads(); }
  float inv = 1.f / red[0];
  for (int j = t; j < 640; j += 256) out[(size_t)b*640 + j] = expf(logits[(size_t)b*640 + j] - m) * inv;
}

// ---------------- host ----------------
extern "C" void kernel_launch(void* const* d_in, const int* in_sizes, int n_in,
                              void* d_out, int out_size, void* d_ws, size_t ws_size,
                              hipStream_t stream) {
  (void)in_sizes; (void)n_in;
  float* out = (float*)d_out;

  // Diagnostic: if workspace is too small, emit ws_size (in MB) as the output
  // so the bench fails cleanly with absmax ~= ws_MB instead of faulting.
  if (ws_size < (size_t)WS_NEED_FLOATS * 4) {
    k_sentinel<<<2048, 256, 0, stream>>>(out, out_size, (float)(ws_size >> 20));
    return;
  }

  const int*   x       = (const int*)d_in[0];
  const float* pos     = (const float*)d_in[1];
  const float* conv1_w = (const float*)d_in[2];
  const float* conv1_b = (const float*)d_in[3];
  const float* rb1_w   = (const float*)d_in[4];
  const float* rb1_b   = (const float*)d_in[5];
  const float* bn1_g   = (const float*)d_in[6];
  const float* bn1_b   = (const float*)d_in[7];
  const float* rb2_w   = (const float*)d_in[8];
  const float* rb2_b   = (const float*)d_in[9];
  const float* bn2_g   = (const float*)d_in[10];
  const float* bn2_b   = (const float*)d_in[11];
  const float* qkv_w   = (const float*)d_in[12];
  const float* qkv_b   = (const float*)d_in[13];
  const float* proj_w  = (const float*)d_in[14];
  const float* proj_b  = (const float*)d_in[15];
  const float* fc1_w   = (const float*)d_in[16];
  const float* fc1_b   = (const float*)d_in[17];
  const float* fc2_w   = (const float*)d_in[18];
  const float* fc2_b   = (const float*)d_in[19];
  const float* lin1_w  = (const float*)d_in[20];
  const float* lin1_b  = (const float*)d_in[21];
  const float* lin2_w  = (const float*)d_in[22];
  const float* lin2_b  = (const float*)d_in[23];

  float*  ws     = (float*)d_ws;
  float*  act    = ws + OFF_ACT;
  __half* z1h    = (__half*)(ws + OFF_Z1H);
  float*  wT1    = ws + OFF_WT1;
  float*  wTa    = ws + OFF_WTA;
  float*  wTb    = ws + OFF_WTB;
  float*  stats  = ws + OFF_STATS;
  float*  bnp    = ws + OFF_BNP;
  // head reuses z1h region (dead after last k_mlp):
  float*  L1     = ws + OFF_Z1H;            // 4,194,304 f32
  float*  logits = L1 + 4194304;            // 2,621,440 f32

  k_zero<<<1, 256, 0, stream>>>(stats);
  k_wprep<<<64,   256, 0, stream>>>(conv1_w, wT1, 1, 12);
  k_wprep<<<4096, 256, 0, stream>>>(rb1_w, wTa, 10, 128);
  k_wprep<<<4096, 256, 0, stream>>>(rb2_w, wTb, 10, 128);
  k_conv1<<<NBATCH, 256, 0, stream>>>(x, wT1, conv1_b, act);

  for (int l = 0; l < 10; ++l) {
    // z1h = conv1(relu(act)) + b1
    k_conv<float><<<NBATCH, 512, 0, stream>>>(act, wTa + (size_t)l*147456, rb1_b + l*128,
                                              (const float*)nullptr, 0, z1h);
    k_stats<<<512, 256, 0, stream>>>(z1h, stats);
    k_bnfin<<<1, 128, 0, stream>>>(stats, bn1_g + l*128, bn1_b + l*128, bnp);
    // z1h = conv2(relu(bn1(z1h))) + b2   (in-place, per-image staged)
    k_conv<__half><<<NBATCH, 512, 0, stream>>>(z1h, wTb + (size_t)l*147456, rb2_b + l*128,
                                               bnp, 1, z1h);
    k_stats<<<512, 256, 0, stream>>>(z1h, stats);
    k_bnfin<<<1, 128, 0, stream>>>(stats, bn2_g + l*128, bn2_b + l*128, bnp);
    // t = wp(act + bn2(z1h)) + pos; t2 = t + LN(attn); t2 -> act (token layout)
    k_attn<<<NBATCH, 512, 0, stream>>>(act, z1h, bnp, pos,
                                       qkv_w + (size_t)l*786432, qkv_b + l*1536,
                                       proj_w + (size_t)l*262144, proj_b + l*512,
                                       act);
    // act(spatial) = window_reverse(t2 + LN(mlp(t2)))
    k_mlp<<<NBATCH, 512, 0, stream>>>(act, fc1_w + (size_t)l*262144, fc1_b + l*512,
                                      fc2_w + (size_t)l*262144, fc2_b + l*512, act);
  }
  k_gemm<1><<<dim3(64, 16), 256, 0, stream>>>(act, lin1_w, lin1_b, L1, 4096, 1024, 8192);
  k_gemm<0><<<dim3(64, 10), 256, 0, stream>>>(L1, lin2_w, lin2_b, logits, 4096, 640, 1024);
  k_softmax<<<NBATCH, 256, 0, stream>>>(logits, out);
}

// Round 4
// 153813.818 us; speedup vs baseline: 1.9763x; 1.9763x over previous
//
#include <hip/hip_runtime.h>
#include <hip/hip_fp16.h>
#include <math.h>

// betaChessAI forward: 10 blocks of {conv-bn-conv-bn residual, windowed attention, MLP}
// Layouts:
//   spatial activations: act[(b*64 + p)*128 + c], p = y*8+x   (== feat layout for head)
//   token activations:   t[(b*16 + n)*512 + d],  d = (p1*2+p2)*128 + c, n = hy*4+wx
//   mapping: (y,x) = (2*hy+p1, 2*wx+p2)
// Workspace (float slots), ~213 MB total (same as round-3 passing layout):
//   act f32 (33.55M) | big2 (16.78M f32-slots = 33.55M halfs) | wT1 | wTa | wTb | stats | bnp
// big2 usage: conv phase = z1h (full); attention phase (per 1024-image chunk):
//   attnout_h [0,8.39M) projout_h [8.39M,16.78M) h1_h [16.78M,25.17M) wT16 [25.17M,26.74M)
//   head: L1_h [0,4.19M) logits f32 [half 4.19M..] lin2T [9.44M..]

#define NBATCH 4096
#define NPOSR  (NBATCH*64)
#define CH     1024                    // images per attention chunk

#define OFF_ACT   0
#define OFF_BIG2  33554432
#define OFF_WT1   (OFF_BIG2 + 16777216)
#define OFF_WTA   (OFF_WT1 + 13824)
#define OFF_WTB   (OFF_WTA + 1474560)
#define OFF_STATS (OFF_WTB + 1474560)
#define OFF_BNP   (OFF_STATS + 256)
#define WS_NEED_FLOATS (OFF_BNP + 256)

// big2 half-offsets
#define H_ATT  0
#define H_PRJ  8388608
#define H_H1   16777216
#define H_WQT  25165824
#define H_WPT  25952256
#define H_WF1  26214400
#define H_WF2  26476544
#define H_LOG  4194304      // logits f32 start (in half-slots: float offset = /2)
#define H_L2T  9437184

typedef _Float16 f16x8 __attribute__((ext_vector_type(8)));
typedef float f32x4 __attribute__((ext_vector_type(4)));

__device__ inline f32x4 vzero4() { f32x4 z; z[0]=0.f; z[1]=0.f; z[2]=0.f; z[3]=0.f; return z; }

__device__ inline float4 ld_half4(const __half* p) {
  float2 a = __half22float2(*(const __half2*)p);
  float2 b = __half22float2(*(const __half2*)(p + 2));
  return make_float4(a.x, a.y, b.x, b.y);
}

// ---------------- utility ----------------
__global__ void k_zero(float* __restrict__ s) { s[threadIdx.x] = 0.f; }

__global__ void k_sentinel(float* __restrict__ out, int n, float val) {
  for (int i = blockIdx.x*blockDim.x + threadIdx.x; i < n; i += gridDim.x*blockDim.x)
    out[i] = val;
}

// src[l][co][ci][kk] (co=128,kk=9) -> dst[l][(kk*Cin+ci)*128+co]
__global__ void k_wprep(const float* __restrict__ src, float* __restrict__ dst, int L, int Cin) {
  int total = L * 128 * Cin * 9;
  for (int idx = blockIdx.x*blockDim.x + threadIdx.x; idx < total; idx += gridDim.x*blockDim.x) {
    int kk = idx % 9; int t2 = idx / 9;
    int ci = t2 % Cin; t2 /= Cin;
    int co = t2 % 128; int l  = t2 / 128;
    dst[((size_t)(l*9 + kk)*Cin + ci)*128 + co] = src[idx];
  }
}

// W f32 [K][N] -> WT f16 [N][K]
__global__ void k_wt16(const float* __restrict__ W, __half* __restrict__ WT, int K, int N) {
  int total = K * N;
  for (int idx = blockIdx.x*blockDim.x + threadIdx.x; idx < total; idx += gridDim.x*blockDim.x) {
    int k = idx / N, n = idx % N;
    WT[(size_t)n*K + k] = __float2half(W[idx]);
  }
}

// ---------------- encode + conv1 (one-hot lookup), output f32 act ----------------
__global__ __launch_bounds__(256) void k_conv1(const int* __restrict__ xin,
    const float* __restrict__ wT1, const float* __restrict__ b1,
    float* __restrict__ out) {
  __shared__ int s_w[64], s_b[64];
  int b = blockIdx.x, t = threadIdx.x;
  if (t < 64) { s_w[t] = xin[b*128 + t]; s_b[t] = xin[b*128 + 64 + t]; }
  __syncthreads();
  int p = t >> 2, i = t & 3;
  int y = p >> 3, x = p & 7;
  float acc[32];
  #pragma unroll
  for (int j = 0; j < 32; ++j) acc[j] = b1[i*32 + j];
  #pragma unroll
  for (int kk = 0; kk < 9; ++kk) {
    int ny = y + kk/3 - 1, nx = x + kk%3 - 1;
    if (ny < 0 || ny > 7 || nx < 0 || nx > 7) continue;
    int np = ny*8 + nx;
    int wp = s_w[np], bp = s_b[np];
    if (wp >= 1 && wp <= 6) {
      const float* w = &wT1[(size_t)(kk*12 + (wp-1))*128 + i*32];
      #pragma unroll
      for (int j = 0; j < 32; ++j) acc[j] += w[j];
    }
    if (bp >= 1 && bp <= 6) {
      const float* w = &wT1[(size_t)(kk*12 + 6 + (bp-1))*128 + i*32];
      #pragma unroll
      for (int j = 0; j < 32; ++j) acc[j] += w[j];
    }
  }
  float* o = &out[((size_t)b*64 + p)*128 + i*32];
  #pragma unroll
  for (int j = 0; j < 8; ++j)
    *(float4*)&o[j*4] = make_float4(acc[j*4], acc[j*4+1], acc[j*4+2], acc[j*4+3]);
}

// ---------------- residual 3x3 conv: out(h16) = conv3x3(relu(bn?(in))) + bias ----------------
__device__ inline float cvt_in(float v) { return v; }
__device__ inline float cvt_in(__half v) { return __half2float(v); }

template<typename TIN>
__global__ __launch_bounds__(512) void k_conv(const TIN* __restrict__ in,
    const float* __restrict__ wT, const float* __restrict__ bias,
    const float* __restrict__ bnp, int use_bn, __half* __restrict__ out) {
  __shared__ float s_in[64*132];
  int b = blockIdx.x, t = threadIdx.x;
  const TIN* gin = &in[(size_t)b*8192];
  for (int idx = t; idx < 8192; idx += 512) {
    int row = idx >> 7, ci = idx & 127;
    float v = cvt_in(gin[idx]);
    if (use_bn) v = bnp[ci]*v + bnp[128+ci];
    s_in[row*132 + ci] = fmaxf(v, 0.f);
  }
  __syncthreads();
  int p = t >> 3, i = t & 7;
  int y = p >> 3, x = p & 7;
  float acc[16];
  #pragma unroll
  for (int j = 0; j < 16; ++j) acc[j] = bias[i*16 + j];
  #pragma unroll
  for (int kk = 0; kk < 9; ++kk) {
    int ny = y + kk/3 - 1, nx = x + kk%3 - 1;
    if (ny < 0 || ny > 7 || nx < 0 || nx > 7) continue;
    const float* sv = &s_in[(ny*8 + nx)*132];
    const float* wrow = &wT[(size_t)kk*16384 + i*16];
    for (int ci = 0; ci < 128; ++ci) {
      float a = sv[ci];
      const float4* w4 = (const float4*)(wrow + (size_t)ci*128);
      #pragma unroll
      for (int j = 0; j < 4; ++j) {
        float4 w = w4[j];
        acc[j*4+0] += a*w.x; acc[j*4+1] += a*w.y; acc[j*4+2] += a*w.z; acc[j*4+3] += a*w.w;
      }
    }
  }
  __half2* o = (__half2*)&out[(size_t)b*8192 + p*128 + i*16];
  #pragma unroll
  for (int j = 0; j < 8; ++j)
    o[j] = __floats2half2_rn(acc[j*2], acc[j*2+1]);
}

// ---------------- per-channel batch stats (sum, sumsq) over fp16 z ----------------
__global__ __launch_bounds__(256) void k_stats(const __half* __restrict__ z, float* __restrict__ stats) {
  int t = threadIdx.x;
  int c = t & 127, rl = t >> 7;
  int r0 = blockIdx.x * 512;
  float s = 0.f, q = 0.f;
  for (int r = r0 + rl; r < r0 + 512; r += 2) {
    float v = __half2float(z[(size_t)r*128 + c]);
    s += v; q += v*v;
  }
  __shared__ float sh[256];
  sh[t] = s; __syncthreads();
  if (rl == 0) atomicAdd(&stats[c], sh[c] + sh[128+c]);
  __syncthreads();
  sh[t] = q; __syncthreads();
  if (rl == 0) atomicAdd(&stats[128+c], sh[c] + sh[128+c]);
}

__global__ void k_bnfin(float* __restrict__ stats, const float* __restrict__ g,
                        const float* __restrict__ bb, float* __restrict__ bnp) {
  int c = threadIdx.x;
  const float invN = 1.f / (float)NPOSR;
  float m = stats[c] * invN;
  float v = stats[128+c] * invN - m*m;
  float sc = g[c] * rsqrtf(v + 1e-5f);
  bnp[c] = sc;
  bnp[128+c] = bb[c] - m*sc;
  stats[c] = 0.f; stats[128+c] = 0.f;
}

// ---------------- t = window_partition(act + bn2(z1h)) + pos, in-place per image ----------------
__global__ __launch_bounds__(256) void k_make_t(float* __restrict__ act,
    const __half* __restrict__ z1h, const float* __restrict__ bnp,
    const float* __restrict__ pos) {
  __shared__ float s_t[8192];
  int b = blockIdx.x, t = threadIdx.x;
  for (int idx4 = t; idx4 < 2048; idx4 += 256) {
    int n = idx4 >> 7, d4 = idx4 & 127;
    int d = d4*4, c = d & 127, q = d >> 7;
    int y = ((n>>2)<<1) + (q>>1), xx = ((n&3)<<1) + (q&1);
    size_t sp = ((size_t)b*64 + y*8 + xx)*128 + c;
    float4 a  = *(const float4*)&act[sp];
    float4 z  = ld_half4(&z1h[sp]);
    float4 sc = *(const float4*)&bnp[c];
    float4 sh = *(const float4*)&bnp[128+c];
    float4 pe = *(const float4*)&pos[n*512 + d];
    float4 o;
    o.x = a.x + sc.x*z.x + sh.x + pe.x;
    o.y = a.y + sc.y*z.y + sh.y + pe.y;
    o.z = a.z + sc.z*z.z + sh.z + pe.z;
    o.w = a.w + sc.w*z.w + sh.w + pe.w;
    *(float4*)&s_t[n*512 + d] = o;
  }
  __syncthreads();
  for (int idx4 = t; idx4 < 2048; idx4 += 256)
    *(float4*)&act[(size_t)b*8192 + idx4*4] = *(float4*)&s_t[idx4*4];
}

// ---------------- fused qkv GEMM + windowed attention (per 8 images x 1 head) ----------------
// A = t f32 (chunk token rows), B = WqkvT f16 [1536][512]; out attnout_h chunk [16384][512]
__global__ __launch_bounds__(256) void k_qkv_attn(const float* __restrict__ tG,
    const __half* __restrict__ WqkvT, const float* __restrict__ bqkv,
    __half* __restrict__ attnout) {
  union SmemU {
    struct { _Float16 A[128][40]; _Float16 B[192][40]; } g;
    struct { _Float16 qkv[128][200]; float S[2048]; } e;
  };
  __shared__ SmemU u;
  int t = threadIdx.x;
  int bx = blockIdx.x, h = blockIdx.y;
  int w = t >> 6, lane = t & 63;
  int wm = (w >> 1) * 64, wn = (w & 1) * 96;
  int fr = lane & 15, fq = lane >> 4;
  f32x4 acc[4][6];
  #pragma unroll
  for (int mt = 0; mt < 4; ++mt)
    #pragma unroll
    for (int nt = 0; nt < 6; ++nt) acc[mt][nt] = vzero4();
  int srow = t >> 1, skh = (t & 1) * 16;
  for (int k0 = 0; k0 < 512; k0 += 32) {
    // stage A (f32 -> f16)
    {
      const float4* src = (const float4*)&tG[(size_t)(bx*128 + srow)*512 + k0 + skh];
      float4 v0 = src[0], v1 = src[1], v2 = src[2], v3 = src[3];
      f16x8 h0, h1;
      h0[0]=(_Float16)v0.x; h0[1]=(_Float16)v0.y; h0[2]=(_Float16)v0.z; h0[3]=(_Float16)v0.w;
      h0[4]=(_Float16)v1.x; h0[5]=(_Float16)v1.y; h0[6]=(_Float16)v1.z; h0[7]=(_Float16)v1.w;
      h1[0]=(_Float16)v2.x; h1[1]=(_Float16)v2.y; h1[2]=(_Float16)v2.z; h1[3]=(_Float16)v2.w;
      h1[4]=(_Float16)v3.x; h1[5]=(_Float16)v3.y; h1[6]=(_Float16)v3.z; h1[7]=(_Float16)v3.w;
      *(f16x8*)&u.g.A[srow][skh] = h0;
      *(f16x8*)&u.g.A[srow][skh+8] = h1;
    }
    // stage B from WqkvT rows {h*64+n | 512+h*64+n | 1024+h*64+n}
    for (int r = t; r < 384; r += 256) {
      int n = r >> 1, kh = (r & 1) * 16;
      int ng = ((n >> 6) * 512) + h*64 + (n & 63);
      const ulonglong2* src = (const ulonglong2*)&WqkvT[(size_t)ng*512 + k0 + kh];
      *(ulonglong2*)&u.g.B[n][kh]   = src[0];
      *(ulonglong2*)&u.g.B[n][kh+8] = src[1];
    }
    __syncthreads();
    f16x8 af[4], bf[6];
    #pragma unroll
    for (int mt = 0; mt < 4; ++mt) af[mt] = *(const f16x8*)&u.g.A[wm + mt*16 + fr][fq*8];
    #pragma unroll
    for (int nt = 0; nt < 6; ++nt) bf[nt] = *(const f16x8*)&u.g.B[wn + nt*16 + fr][fq*8];
    #pragma unroll
    for (int mt = 0; mt < 4; ++mt)
      #pragma unroll
      for (int nt = 0; nt < 6; ++nt)
        acc[mt][nt] = __builtin_amdgcn_mfma_f32_16x16x32_f16(af[mt], bf[nt], acc[mt][nt], 0, 0, 0);
    __syncthreads();
  }
  // epilogue: bias (+q scale) -> s_qkv
  #pragma unroll
  for (int mt = 0; mt < 4; ++mt)
    #pragma unroll
    for (int nt = 0; nt < 6; ++nt) {
      int col = wn + nt*16 + fr;
      int which = col >> 6, dh = col & 63;
      float bv = bqkv[which*512 + h*64 + dh];
      float sc = (which == 0) ? 0.125f : 1.f;
      #pragma unroll
      for (int j = 0; j < 4; ++j) {
        int row = wm + mt*16 + fq*4 + j;
        u.e.qkv[row][col] = (_Float16)((acc[mt][nt][j] + bv) * sc);
      }
    }
  __syncthreads();
  // scores S[i][qi][ki]
  {
    int i = t >> 5, qi = (t >> 1) & 15, kio = (t & 1) * 8;
    for (int ki = kio; ki < kio + 8; ++ki) {
      float s = 0.f;
      const _Float16* qr = &u.e.qkv[i*16 + qi][0];
      const _Float16* kr = &u.e.qkv[i*16 + ki][64];
      #pragma unroll
      for (int d = 0; d < 64; ++d) s += (float)qr[d] * (float)kr[d];
      u.e.S[i*256 + qi*16 + ki] = s;
    }
  }
  __syncthreads();
  if (t < 128) {
    int i = t >> 4, qi = t & 15;
    float* Sr = &u.e.S[i*256 + qi*16];
    float mx = -1e30f;
    #pragma unroll
    for (int ki = 0; ki < 16; ++ki) mx = fmaxf(mx, Sr[ki]);
    float sm = 0.f;
    float e[16];
    #pragma unroll
    for (int ki = 0; ki < 16; ++ki) { e[ki] = expf(Sr[ki] - mx); sm += e[ki]; }
    float inv = 1.f / sm;
    #pragma unroll
    for (int ki = 0; ki < 16; ++ki) Sr[ki] = e[ki]*inv;
  }
  __syncthreads();
  // out = P @ v -> attnout[tok][h*64+dh]
  {
    int i = t >> 5, q2 = t & 31;
    int qi = q2 >> 1, dh0 = (q2 & 1) * 32;
    const float* Sr = &u.e.S[i*256 + qi*16];
    size_t orow = ((size_t)(bx*8 + i)*16 + qi)*512 + h*64;
    for (int dh = dh0; dh < dh0 + 32; dh += 2) {
      float a0 = 0.f, a1 = 0.f;
      #pragma unroll
      for (int ki = 0; ki < 16; ++ki) {
        float p = Sr[ki];
        a0 += p * (float)u.e.qkv[i*16 + ki][128 + dh];
        a1 += p * (float)u.e.qkv[i*16 + ki][128 + dh + 1];
      }
      *(__half2*)&attnout[orow + dh] = __floats2half2_rn(a0, a1);
    }
  }
}

// ---------------- generic MFMA GEMM: C = act(A@B + bias), 128x128x32 tiles ----------------
// A row-major [M][K] (f16 or f32->cvt); B: B16 ? BT f16 [N][K] : B f32 [K][N]
template<int A16, int B16, int RELU, int OUT16>
__global__ __launch_bounds__(256) void k_mgemm(const void* __restrict__ Ap,
    const void* __restrict__ Bp, const float* __restrict__ bias,
    void* __restrict__ Cp, int M, int N, int K) {
  __shared__ _Float16 sA[128][40];
  __shared__ _Float16 sB[128][40];
  int t = threadIdx.x;
  int bm = blockIdx.x * 128, bn = blockIdx.y * 128;
  int w = t >> 6, lane = t & 63;
  int wm = (w >> 1) * 64, wn = (w & 1) * 64;
  int fr = lane & 15, fq = lane >> 4;
  f32x4 acc[4][4];
  #pragma unroll
  for (int mt = 0; mt < 4; ++mt)
    #pragma unroll
    for (int nt = 0; nt < 4; ++nt) acc[mt][nt] = vzero4();
  int srow = t >> 1, skh = (t & 1) * 16;
  for (int k0 = 0; k0 < K; k0 += 32) {
    if (A16) {
      const __half* A = (const __half*)Ap;
      const ulonglong2* src = (const ulonglong2*)&A[(size_t)(bm + srow)*K + k0 + skh];
      *(ulonglong2*)&sA[srow][skh]   = src[0];
      *(ulonglong2*)&sA[srow][skh+8] = src[1];
    } else {
      const float* A = (const float*)Ap;
      const float4* src = (const float4*)&A[(size_t)(bm + srow)*K + k0 + skh];
      float4 v0 = src[0], v1 = src[1], v2 = src[2], v3 = src[3];
      f16x8 h0, h1;
      h0[0]=(_Float16)v0.x; h0[1]=(_Float16)v0.y; h0[2]=(_Float16)v0.z; h0[3]=(_Float16)v0.w;
      h0[4]=(_Float16)v1.x; h0[5]=(_Float16)v1.y; h0[6]=(_Float16)v1.z; h0[7]=(_Float16)v1.w;
      h1[0]=(_Float16)v2.x; h1[1]=(_Float16)v2.y; h1[2]=(_Float16)v2.z; h1[3]=(_Float16)v2.w;
      h1[4]=(_Float16)v3.x; h1[5]=(_Float16)v3.y; h1[6]=(_Float16)v3.z; h1[7]=(_Float16)v3.w;
      *(f16x8*)&sA[srow][skh]   = h0;
      *(f16x8*)&sA[srow][skh+8] = h1;
    }
    if (B16) {
      const __half* BT = (const __half*)Bp;
      const ulonglong2* src = (const ulonglong2*)&BT[(size_t)(bn + srow)*K + k0 + skh];
      *(ulonglong2*)&sB[srow][skh]   = src[0];
      *(ulonglong2*)&sB[srow][skh+8] = src[1];
    } else {
      const float* B = (const float*)Bp;
      int kr = t >> 3, n0 = (t & 7) * 16;
      #pragma unroll
      for (int g = 0; g < 4; ++g) {
        float4 v = *(const float4*)&B[(size_t)(k0 + kr)*N + bn + n0 + g*4];
        sB[n0+g*4+0][kr] = (_Float16)v.x;
        sB[n0+g*4+1][kr] = (_Float16)v.y;
        sB[n0+g*4+2][kr] = (_Float16)v.z;
        sB[n0+g*4+3][kr] = (_Float16)v.w;
      }
    }
    __syncthreads();
    f16x8 af[4], bf[4];
    #pragma unroll
    for (int mt = 0; mt < 4; ++mt) af[mt] = *(const f16x8*)&sA[wm + mt*16 + fr][fq*8];
    #pragma unroll
    for (int nt = 0; nt < 4; ++nt) bf[nt] = *(const f16x8*)&sB[wn + nt*16 + fr][fq*8];
    #pragma unroll
    for (int mt = 0; mt < 4; ++mt)
      #pragma unroll
      for (int nt = 0; nt < 4; ++nt)
        acc[mt][nt] = __builtin_amdgcn_mfma_f32_16x16x32_f16(af[mt], bf[nt], acc[mt][nt], 0, 0, 0);
    __syncthreads();
  }
  #pragma unroll
  for (int mt = 0; mt < 4; ++mt)
    #pragma unroll
    for (int nt = 0; nt < 4; ++nt) {
      int col = bn + wn + nt*16 + fr;
      float bv = bias[col];
      #pragma unroll
      for (int j = 0; j < 4; ++j) {
        int row = bm + wm + mt*16 + fq*4 + j;
        float v = acc[mt][nt][j] + bv;
        if (RELU) v = fmaxf(v, 0.f);
        if (OUT16) ((__half*)Cp)[(size_t)row*N + col] = __float2half(v);
        else       ((float*)Cp)[(size_t)row*N + col] = v;
      }
    }
}

// ---------------- t2 = t + LN(gemm_out): token-wise, writes back into act (token layout) ----------------
__global__ __launch_bounds__(256) void k_lnres(const __half* __restrict__ pout,
    float* __restrict__ tact) {
  int t = threadIdx.x;
  int tok = blockIdx.x*4 + (t >> 6);
  int lane = t & 63;
  f16x8 hv = *(const f16x8*)&pout[(size_t)tok*512 + lane*8];
  float v[8]; float s1 = 0.f, s2 = 0.f;
  #pragma unroll
  for (int j = 0; j < 8; ++j) { v[j] = (float)hv[j]; s1 += v[j]; s2 += v[j]*v[j]; }
  #pragma unroll
  for (int m = 32; m >= 1; m >>= 1) { s1 += __shfl_xor(s1, m); s2 += __shfl_xor(s2, m); }
  float mean = s1 * (1.f/512.f);
  float var  = s2 * (1.f/512.f) - mean*mean;
  float rs = rsqrtf(var + 1e-6f);
  float* ar = &tact[(size_t)tok*512 + lane*8];
  #pragma unroll
  for (int j = 0; j < 8; ++j) ar[j] += (v[j] - mean)*rs;
}

// ---------------- t2 + LN(fc2out), window_reverse to spatial, per image in-place ----------------
__global__ __launch_bounds__(256) void k_lnres2(const __half* __restrict__ fout,
    float* __restrict__ actimg /* act + chunk_img_base*8192 */) {
  __shared__ float s_t2[8192];
  int bimg = blockIdx.x, t = threadIdx.x;
  int lane = t & 63;
  for (int tg = 0; tg < 4; ++tg) {
    int n = tg*4 + (t >> 6);
    size_t row = (size_t)bimg*16 + n;
    f16x8 hv = *(const f16x8*)&fout[row*512 + lane*8];
    float v[8]; float s1 = 0.f, s2 = 0.f;
    #pragma unroll
    for (int j = 0; j < 8; ++j) { v[j] = (float)hv[j]; s1 += v[j]; s2 += v[j]*v[j]; }
    #pragma unroll
    for (int m = 32; m >= 1; m >>= 1) { s1 += __shfl_xor(s1, m); s2 += __shfl_xor(s2, m); }
    float mean = s1 * (1.f/512.f);
    float var  = s2 * (1.f/512.f) - mean*mean;
    float rs = rsqrtf(var + 1e-6f);
    const float* ar = &actimg[row*512 + lane*8];
    #pragma unroll
    for (int j = 0; j < 8; ++j) s_t2[n*512 + lane*8 + j] = ar[j] + (v[j] - mean)*rs;
  }
  __syncthreads();
  for (int idx = t; idx < 2048; idx += 256) {
    int p = idx >> 5, c = (idx & 31)*4;
    int y = p >> 3, x = p & 7;
    int n = (y >> 1)*4 + (x >> 1);
    int d = ((y & 1)*2 + (x & 1))*128 + c;
    *(float4*)&actimg[(size_t)bimg*8192 + p*128 + c] = *(float4*)&s_t2[n*512 + d];
  }
}

// ---------------- row softmax (640) ----------------
__global__ __launch_bounds__(256) void k_softmax(const float* __restrict__ logits, float* __restrict__ out) {
  int b = blockIdx.x, t = threadIdx.x;
  __shared__ float red[256];
  float m = -1e30f;
  for (int j = t; j < 640; j += 256) m = fmaxf(m, logits[(size_t)b*640 + j]);
  red[t] = m; __syncthreads();
  for (int s = 128; s > 0; s >>= 1) { if (t < s) red[t] = fmaxf(red[t], red[t+s]); __syncthreads(); }
  m = red[0]; __syncthreads();
  float sum = 0.f;
  for (int j = t; j < 640; j += 256) sum += expf(logits[(size_t)b*640 + j] - m);
  red[t] = sum; __syncthreads();
  for (int s = 128; s > 0; s >>= 1) { if (t < s) red[t] += red[t+s]; __syncthreads(); }
  float inv = 1.f / red[0];
  for (int j = t; j < 640; j += 256) out[(size_t)b*640 + j] = expf(logits[(size_t)b*640 + j] - m) * inv;
}

// ---------------- host ----------------
extern "C" void kernel_launch(void* const* d_in, const int* in_sizes, int n_in,
                              void* d_out, int out_size, void* d_ws, size_t ws_size,
                              hipStream_t stream) {
  (void)in_sizes; (void)n_in;
  float* out = (float*)d_out;
  if (ws_size < (size_t)WS_NEED_FLOATS * 4) {
    k_sentinel<<<2048, 256, 0, stream>>>(out, out_size, (float)(ws_size >> 20));
    return;
  }

  const int*   x       = (const int*)d_in[0];
  const float* pos     = (const float*)d_in[1];
  const float* conv1_w = (const float*)d_in[2];
  const float* conv1_b = (const float*)d_in[3];
  const float* rb1_w   = (const float*)d_in[4];
  const float* rb1_b   = (const float*)d_in[5];
  const float* bn1_g   = (const float*)d_in[6];
  const float* bn1_b   = (const float*)d_in[7];
  const float* rb2_w   = (const float*)d_in[8];
  const float* rb2_b   = (const float*)d_in[9];
  const float* bn2_g   = (const float*)d_in[10];
  const float* bn2_b   = (const float*)d_in[11];
  const float* qkv_w   = (const float*)d_in[12];
  const float* qkv_b   = (const float*)d_in[13];
  const float* proj_w  = (const float*)d_in[14];
  const float* proj_b  = (const float*)d_in[15];
  const float* fc1_w   = (const float*)d_in[16];
  const float* fc1_b   = (const float*)d_in[17];
  const float* fc2_w   = (const float*)d_in[18];
  const float* fc2_b   = (const float*)d_in[19];
  const float* lin1_w  = (const float*)d_in[20];
  const float* lin1_b  = (const float*)d_in[21];
  const float* lin2_w  = (const float*)d_in[22];
  const float* lin2_b  = (const float*)d_in[23];

  float*  ws    = (float*)d_ws;
  float*  act   = ws + OFF_ACT;
  __half* big2h = (__half*)(ws + OFF_BIG2);
  float*  wT1   = ws + OFF_WT1;
  float*  wTa   = ws + OFF_WTA;
  float*  wTb   = ws + OFF_WTB;
  float*  stats = ws + OFF_STATS;
  float*  bnp   = ws + OFF_BNP;

  __half* z1h     = big2h;
  __half* attnout = big2h + H_ATT;
  __half* projout = big2h + H_PRJ;
  __half* h1      = big2h + H_H1;
  __half* fc2out  = projout;                  // aliases projout (dead after lnres)
  __half* qkvT    = big2h + H_WQT;
  __half* projT   = big2h + H_WPT;
  __half* fc1T    = big2h + H_WF1;
  __half* fc2T    = big2h + H_WF2;
  __half* L1h     = big2h;                    // head
  float*  logits  = (float*)(big2h + H_LOG);
  __half* lin2T   = big2h + H_L2T;

  k_zero<<<1, 256, 0, stream>>>(stats);
  k_wprep<<<64,   256, 0, stream>>>(conv1_w, wT1, 1, 12);
  k_wprep<<<4096, 256, 0, stream>>>(rb1_w, wTa, 10, 128);
  k_wprep<<<4096, 256, 0, stream>>>(rb2_w, wTb, 10, 128);
  k_conv1<<<NBATCH, 256, 0, stream>>>(x, wT1, conv1_b, act);

  for (int l = 0; l < 10; ++l) {
    k_conv<float><<<NBATCH, 512, 0, stream>>>(act, wTa + (size_t)l*147456, rb1_b + l*128,
                                              (const float*)nullptr, 0, z1h);
    k_stats<<<512, 256, 0, stream>>>(z1h, stats);
    k_bnfin<<<1, 128, 0, stream>>>(stats, bn1_g + l*128, bn1_b + l*128, bnp);
    k_conv<__half><<<NBATCH, 512, 0, stream>>>(z1h, wTb + (size_t)l*147456, rb2_b + l*128,
                                               bnp, 1, z1h);
    k_stats<<<512, 256, 0, stream>>>(z1h, stats);
    k_bnfin<<<1, 128, 0, stream>>>(stats, bn2_g + l*128, bn2_b + l*128, bnp);
    k_make_t<<<NBATCH, 256, 0, stream>>>(act, z1h, bnp, pos);   // z1h dead after this

    k_wt16<<<1024, 256, 0, stream>>>(qkv_w + (size_t)l*786432, qkvT, 512, 1536);
    k_wt16<<<512,  256, 0, stream>>>(proj_w + (size_t)l*262144, projT, 512, 512);
    k_wt16<<<512,  256, 0, stream>>>(fc1_w + (size_t)l*262144, fc1T, 512, 512);
    k_wt16<<<512,  256, 0, stream>>>(fc2_w + (size_t)l*262144, fc2T, 512, 512);

    for (int ch = 0; ch < NBATCH/CH; ++ch) {
      float* tchunk = act + (size_t)ch*CH*8192;
      k_qkv_attn<<<dim3(CH/8, 8), 256, 0, stream>>>(tchunk, qkvT, qkv_b + l*1536, attnout);
      k_mgemm<1,1,0,1><<<dim3(CH*16/128, 4), 256, 0, stream>>>(attnout, projT,
          proj_b + l*512, projout, CH*16, 512, 512);
      k_lnres<<<CH*16/4, 256, 0, stream>>>(projout, tchunk);
      k_mgemm<0,1,1,1><<<dim3(CH*16/128, 4), 256, 0, stream>>>(tchunk, fc1T,
          fc1_b + l*512, h1, CH*16, 512, 512);
      k_mgemm<1,1,0,1><<<dim3(CH*16/128, 4), 256, 0, stream>>>(h1, fc2T,
          fc2_b + l*512, fc2out, CH*16, 512, 512);
      k_lnres2<<<CH, 256, 0, stream>>>(fc2out, tchunk);
    }
  }
  // head
  k_mgemm<0,0,1,1><<<dim3(4096/128, 8), 256, 0, stream>>>(act, lin1_w, lin1_b, L1h,
      4096, 1024, 8192);
  k_wt16<<<512, 256, 0, stream>>>(lin2_w, lin2T, 1024, 640);
  k_mgemm<1,1,0,0><<<dim3(4096/128, 5), 256, 0, stream>>>(L1h, lin2T, lin2_b, logits,
      4096, 640, 1024);
  k_softmax<<<NBATCH, 256, 0, stream>>>(logits, out);
}

// Round 6
// 12751.792 us; speedup vs baseline: 23.8380x; 12.0621x over previous
//
#include <hip/hip_runtime.h>
#include <hip/hip_fp16.h>
#include <math.h>

// betaChessAI forward: 10 blocks of {conv-bn-conv-bn residual, windowed attention, MLP}
// Layouts:
//   spatial activations: act[(b*64 + p)*128 + c], p = y*8+x   (== feat layout for head)
//   token activations:   t[(b*16 + n)*512 + d],  d = (p1*2+p2)*128 + c, n = hy*4+wx
//   mapping: (y,x) = (2*hy+p1, 2*wx+p2)
// Workspace (float slots), ~207 MB total:
//   act f32 (33.55M) | big2 (16.78M f32-slots = 33.55M halfs) | wT1 f32 | wTa16/wTb16 f16 | stats | bnp

#define NBATCH 4096
#define NPOSR  (NBATCH*64)
#define CH     1024                    // images per attention chunk

#define OFF_ACT   0
#define OFF_BIG2  33554432
#define OFF_WT1   (OFF_BIG2 + 16777216)
#define OFF_WTA   (OFF_WT1 + 13824)    // f16 [10][128][1152] in 737,280 f32 slots
#define OFF_WTB   (OFF_WTA + 737280)
#define OFF_STATS (OFF_WTB + 737280)
#define OFF_BNP   (OFF_STATS + 256)
#define WS_NEED_FLOATS (OFF_BNP + 256)

// big2 half-offsets
#define H_ATT  0
#define H_PRJ  8388608
#define H_H1   16777216
#define H_WQT  25165824
#define H_WPT  25952256
#define H_WF1  26214400
#define H_WF2  26476544
#define H_LOG  4194304
#define H_L2T  9437184

typedef _Float16 f16x8 __attribute__((ext_vector_type(8)));
typedef _Float16 f16x4 __attribute__((ext_vector_type(4)));
typedef float f32x4 __attribute__((ext_vector_type(4)));

__device__ inline f32x4 vzero4() { f32x4 z; z[0]=0.f; z[1]=0.f; z[2]=0.f; z[3]=0.f; return z; }

__device__ inline float4 ld_half4(const __half* p) {
  float2 a = __half22float2(*(const __half2*)p);
  float2 b = __half22float2(*(const __half2*)(p + 2));
  return make_float4(a.x, a.y, b.x, b.y);
}

// ---------------- utility ----------------
__global__ void k_zero(float* __restrict__ s) { s[threadIdx.x] = 0.f; }

__global__ void k_sentinel(float* __restrict__ out, int n, float val) {
  for (int i = blockIdx.x*blockDim.x + threadIdx.x; i < n; i += gridDim.x*blockDim.x)
    out[i] = val;
}

// src[l][co][ci][kk] (co=128,ci=12,kk=9) -> dst[(kk*12+ci)*128+co]  (conv1 f32 path)
__global__ void k_wprep(const float* __restrict__ src, float* __restrict__ dst, int L, int Cin) {
  int total = L * 128 * Cin * 9;
  for (int idx = blockIdx.x*blockDim.x + threadIdx.x; idx < total; idx += gridDim.x*blockDim.x) {
    int kk = idx % 9; int t2 = idx / 9;
    int ci = t2 % Cin; t2 /= Cin;
    int co = t2 % 128; int l  = t2 / 128;
    dst[((size_t)(l*9 + kk)*Cin + ci)*128 + co] = src[idx];
  }
}

// src[l][co][ci][kk] (128x128x9) -> dst f16 [(l*128+co)*1152 + kk*128 + ci]
__global__ void k_wprep16(const float* __restrict__ src, __half* __restrict__ dst, int L) {
  int total = L * 128 * 128 * 9;
  for (int idx = blockIdx.x*blockDim.x + threadIdx.x; idx < total; idx += gridDim.x*blockDim.x) {
    int kk = idx % 9; int t2 = idx / 9;
    int ci = t2 % 128; t2 /= 128;
    int co = t2 % 128; int l  = t2 / 128;
    dst[((size_t)(l*128 + co))*1152 + kk*128 + ci] = __float2half(src[idx]);
  }
}

// W f32 [K][N] -> WT f16 [N][K]
__global__ void k_wt16(const float* __restrict__ W, __half* __restrict__ WT, int K, int N) {
  int total = K * N;
  for (int idx = blockIdx.x*blockDim.x + threadIdx.x; idx < total; idx += gridDim.x*blockDim.x) {
    int k = idx / N, n = idx % N;
    WT[(size_t)n*K + k] = __float2half(W[idx]);
  }
}

// ---------------- encode + conv1 (one-hot lookup), output f32 act ----------------
__global__ __launch_bounds__(256) void k_conv1(const int* __restrict__ xin,
    const float* __restrict__ wT1, const float* __restrict__ b1,
    float* __restrict__ out) {
  __shared__ int s_w[64], s_b[64];
  int b = blockIdx.x, t = threadIdx.x;
  if (t < 64) { s_w[t] = xin[b*128 + t]; s_b[t] = xin[b*128 + 64 + t]; }
  __syncthreads();
  int p = t >> 2, i = t & 3;
  int y = p >> 3, x = p & 7;
  float acc[32];
  #pragma unroll
  for (int j = 0; j < 32; ++j) acc[j] = b1[i*32 + j];
  #pragma unroll
  for (int kk = 0; kk < 9; ++kk) {
    int ny = y + kk/3 - 1, nx = x + kk%3 - 1;
    if (ny < 0 || ny > 7 || nx < 0 || nx > 7) continue;
    int np = ny*8 + nx;
    int wp = s_w[np], bp = s_b[np];
    if (wp >= 1 && wp <= 6) {
      const float* w = &wT1[(size_t)(kk*12 + (wp-1))*128 + i*32];
      #pragma unroll
      for (int j = 0; j < 32; ++j) acc[j] += w[j];
    }
    if (bp >= 1 && bp <= 6) {
      const float* w = &wT1[(size_t)(kk*12 + 6 + (bp-1))*128 + i*32];
      #pragma unroll
      for (int j = 0; j < 32; ++j) acc[j] += w[j];
    }
  }
  float* o = &out[((size_t)b*64 + p)*128 + i*32];
  #pragma unroll
  for (int j = 0; j < 8; ++j)
    *(float4*)&o[j*4] = make_float4(acc[j*4], acc[j*4+1], acc[j*4+2], acc[j*4+3]);
}

// ---------------- MFMA residual 3x3 conv: out(h16) = conv3x3(relu(bn?(in))) + bias ----------------
// 2 images per block, M=128 (2x64 positions), N=128 channels, K=1152 (9 taps x 128 ci).
// Image staged once into LDS (f16, bn+relu applied) with a zero row for SAME-pad halo.
__device__ inline float cvt_in(float v) { return v; }
__device__ inline float cvt_in(__half v) { return __half2float(v); }

#define IMG_W 136

template<typename TIN>
__global__ __launch_bounds__(256) void k_conv_mfma(const TIN* __restrict__ in,
    const __half* __restrict__ wT /* [128][1152] f16 */, const float* __restrict__ bias,
    const float* __restrict__ bnp, int use_bn, __half* __restrict__ out) {
  __shared__ __align__(16) _Float16 s_img[2*65*IMG_W];  // 35,360 B (row 64 = zeros)
  __shared__ __align__(16) _Float16 s_B[128][40];       // 10,240 B
  int b2 = blockIdx.x, t = threadIdx.x;
  // stage 2 images: bn+relu, -> f16
  for (int idx4 = t; idx4 < 4096; idx4 += 256) {
    int img = idx4 >> 11, rr = (idx4 >> 5) & 63, c4 = (idx4 & 31) * 4;
    const TIN* src = &in[((size_t)(b2*2 + img)*64 + rr)*128 + c4];
    float v0 = cvt_in(src[0]), v1 = cvt_in(src[1]), v2 = cvt_in(src[2]), v3 = cvt_in(src[3]);
    if (use_bn) {
      v0 = bnp[c4+0]*v0 + bnp[128+c4+0];
      v1 = bnp[c4+1]*v1 + bnp[128+c4+1];
      v2 = bnp[c4+2]*v2 + bnp[128+c4+2];
      v3 = bnp[c4+3]*v3 + bnp[128+c4+3];
    }
    f16x4 h;
    h[0] = (_Float16)fmaxf(v0, 0.f); h[1] = (_Float16)fmaxf(v1, 0.f);
    h[2] = (_Float16)fmaxf(v2, 0.f); h[3] = (_Float16)fmaxf(v3, 0.f);
    *(f16x4*)&s_img[(img*65 + rr)*IMG_W + c4] = h;
  }
  { // zero halo row per image
    int img = t >> 7, c = t & 127;
    if (t < 256) s_img[(img*65 + 64)*IMG_W + c] = (_Float16)0.f;
  }
  int w = t >> 6, lane = t & 63;
  int wm = (w >> 1)*64, wn = (w & 1)*64;
  int fr = lane & 15, fq = lane >> 4;
  int imgo[4], yy[4], xx_[4];
  #pragma unroll
  for (int mt = 0; mt < 4; ++mt) {
    int r = wm + mt*16 + fr;
    imgo[mt] = r >> 6; int p = r & 63; yy[mt] = p >> 3; xx_[mt] = p & 7;
  }
  f32x4 acc[4][4];
  #pragma unroll
  for (int mt = 0; mt < 4; ++mt)
    #pragma unroll
    for (int nt = 0; nt < 4; ++nt) acc[mt][nt] = vzero4();
  int sn = t >> 1, skh = (t & 1) * 16;
  const __half* wrow = &wT[(size_t)sn*1152];
  for (int kk = 0; kk < 9; ++kk) {
    int dy = kk/3 - 1, dx = kk%3 - 1;
    const _Float16* abase[4];
    #pragma unroll
    for (int mt = 0; mt < 4; ++mt) {
      int ny = yy[mt] + dy, nx = xx_[mt] + dx;
      int row = ((unsigned)ny < 8u && (unsigned)nx < 8u) ? (ny*8 + nx) : 64;
      abase[mt] = &s_img[(imgo[mt]*65 + row)*IMG_W];
    }
    #pragma unroll
    for (int ks = 0; ks < 4; ++ks) {
      int k0 = kk*128 + ks*32;
      __syncthreads();   // first iter also covers image staging
      *(ulonglong2*)&s_B[sn][skh]   = *(const ulonglong2*)&wrow[k0 + skh];
      *(ulonglong2*)&s_B[sn][skh+8] = *(const ulonglong2*)&wrow[k0 + skh + 8];
      __syncthreads();
      f16x8 af[4], bf[4];
      #pragma unroll
      for (int mt = 0; mt < 4; ++mt) af[mt] = *(const f16x8*)&abase[mt][ks*32 + fq*8];
      #pragma unroll
      for (int nt = 0; nt < 4; ++nt) bf[nt] = *(const f16x8*)&s_B[wn + nt*16 + fr][fq*8];
      #pragma unroll
      for (int mt = 0; mt < 4; ++mt)
        #pragma unroll
        for (int nt = 0; nt < 4; ++nt)
          acc[mt][nt] = __builtin_amdgcn_mfma_f32_16x16x32_f16(af[mt], bf[nt], acc[mt][nt], 0, 0, 0);
    }
  }
  #pragma unroll
  for (int mt = 0; mt < 4; ++mt) {
    int rbase = wm + mt*16 + fq*4;
    #pragma unroll
    for (int nt = 0; nt < 4; ++nt) {
      int col = wn + nt*16 + fr;
      float bv = bias[col];
      #pragma unroll
      for (int j = 0; j < 4; ++j) {
        int r = rbase + j;
        int img = r >> 6, p = r & 63;
        out[((size_t)(b2*2 + img)*64 + p)*128 + col] = __float2half(acc[mt][nt][j] + bv);
      }
    }
  }
}

// ---------------- per-channel batch stats (sum, sumsq) over fp16 z ----------------
__global__ __launch_bounds__(256) void k_stats(const __half* __restrict__ z, float* __restrict__ stats) {
  int t = threadIdx.x;
  int c = t & 127, rl = t >> 7;
  int r0 = blockIdx.x * 512;
  float s = 0.f, q = 0.f;
  for (int r = r0 + rl; r < r0 + 512; r += 2) {
    float v = __half2float(z[(size_t)r*128 + c]);
    s += v; q += v*v;
  }
  __shared__ float sh[256];
  sh[t] = s; __syncthreads();
  if (rl == 0) atomicAdd(&stats[c], sh[c] + sh[128+c]);
  __syncthreads();
  sh[t] = q; __syncthreads();
  if (rl == 0) atomicAdd(&stats[128+c], sh[c] + sh[128+c]);
}

__global__ void k_bnfin(float* __restrict__ stats, const float* __restrict__ g,
                        const float* __restrict__ bb, float* __restrict__ bnp) {
  int c = threadIdx.x;
  const float invN = 1.f / (float)NPOSR;
  float m = stats[c] * invN;
  float v = stats[128+c] * invN - m*m;
  float sc = g[c] * rsqrtf(v + 1e-5f);
  bnp[c] = sc;
  bnp[128+c] = bb[c] - m*sc;
  stats[c] = 0.f; stats[128+c] = 0.f;
}

// ---------------- t = window_partition(act + bn2(z1h)) + pos, in-place per image ----------------
__global__ __launch_bounds__(256) void k_make_t(float* __restrict__ act,
    const __half* __restrict__ z1h, const float* __restrict__ bnp,
    const float* __restrict__ pos) {
  __shared__ float s_t[8192];
  int b = blockIdx.x, t = threadIdx.x;
  for (int idx4 = t; idx4 < 2048; idx4 += 256) {
    int n = idx4 >> 7, d4 = idx4 & 127;
    int d = d4*4, c = d & 127, q = d >> 7;
    int y = ((n>>2)<<1) + (q>>1), xx = ((n&3)<<1) + (q&1);
    size_t sp = ((size_t)b*64 + y*8 + xx)*128 + c;
    float4 a  = *(const float4*)&act[sp];
    float4 z  = ld_half4(&z1h[sp]);
    float4 sc = *(const float4*)&bnp[c];
    float4 sh = *(const float4*)&bnp[128+c];
    float4 pe = *(const float4*)&pos[n*512 + d];
    float4 o;
    o.x = a.x + sc.x*z.x + sh.x + pe.x;
    o.y = a.y + sc.y*z.y + sh.y + pe.y;
    o.z = a.z + sc.z*z.z + sh.z + pe.z;
    o.w = a.w + sc.w*z.w + sh.w + pe.w;
    *(float4*)&s_t[n*512 + d] = o;
  }
  __syncthreads();
  for (int idx4 = t; idx4 < 2048; idx4 += 256)
    *(float4*)&act[(size_t)b*8192 + idx4*4] = *(float4*)&s_t[idx4*4];
}

// ---------------- fused qkv GEMM + windowed attention (per 8 images x 1 head) ----------------
__global__ __launch_bounds__(256) void k_qkv_attn(const float* __restrict__ tG,
    const __half* __restrict__ WqkvT, const float* __restrict__ bqkv,
    __half* __restrict__ attnout) {
  union SmemU {
    struct { _Float16 A[128][40]; _Float16 B[192][40]; } g;
    struct { _Float16 qkv[128][200]; float S[2048]; } e;
  };
  __shared__ SmemU u;
  int t = threadIdx.x;
  int bx = blockIdx.x, h = blockIdx.y;
  int w = t >> 6, lane = t & 63;
  int wm = (w >> 1) * 64, wn = (w & 1) * 96;
  int fr = lane & 15, fq = lane >> 4;
  f32x4 acc[4][6];
  #pragma unroll
  for (int mt = 0; mt < 4; ++mt)
    #pragma unroll
    for (int nt = 0; nt < 6; ++nt) acc[mt][nt] = vzero4();
  int srow = t >> 1, skh = (t & 1) * 16;
  for (int k0 = 0; k0 < 512; k0 += 32) {
    {
      const float4* src = (const float4*)&tG[(size_t)(bx*128 + srow)*512 + k0 + skh];
      float4 v0 = src[0], v1 = src[1], v2 = src[2], v3 = src[3];
      f16x8 h0, h1;
      h0[0]=(_Float16)v0.x; h0[1]=(_Float16)v0.y; h0[2]=(_Float16)v0.z; h0[3]=(_Float16)v0.w;
      h0[4]=(_Float16)v1.x; h0[5]=(_Float16)v1.y; h0[6]=(_Float16)v1.z; h0[7]=(_Float16)v1.w;
      h1[0]=(_Float16)v2.x; h1[1]=(_Float16)v2.y; h1[2]=(_Float16)v2.z; h1[3]=(_Float16)v2.w;
      h1[4]=(_Float16)v3.x; h1[5]=(_Float16)v3.y; h1[6]=(_Float16)v3.z; h1[7]=(_Float16)v3.w;
      *(f16x8*)&u.g.A[srow][skh] = h0;
      *(f16x8*)&u.g.A[srow][skh+8] = h1;
    }
    for (int r = t; r < 384; r += 256) {
      int n = r >> 1, kh = (r & 1) * 16;
      int ng = ((n >> 6) * 512) + h*64 + (n & 63);
      const ulonglong2* src = (const ulonglong2*)&WqkvT[(size_t)ng*512 + k0 + kh];
      *(ulonglong2*)&u.g.B[n][kh]   = src[0];
      *(ulonglong2*)&u.g.B[n][kh+8] = src[1];
    }
    __syncthreads();
    f16x8 af[4], bf[6];
    #pragma unroll
    for (int mt = 0; mt < 4; ++mt) af[mt] = *(const f16x8*)&u.g.A[wm + mt*16 + fr][fq*8];
    #pragma unroll
    for (int nt = 0; nt < 6; ++nt) bf[nt] = *(const f16x8*)&u.g.B[wn + nt*16 + fr][fq*8];
    #pragma unroll
    for (int mt = 0; mt < 4; ++mt)
      #pragma unroll
      for (int nt = 0; nt < 6; ++nt)
        acc[mt][nt] = __builtin_amdgcn_mfma_f32_16x16x32_f16(af[mt], bf[nt], acc[mt][nt], 0, 0, 0);
    __syncthreads();
  }
  #pragma unroll
  for (int mt = 0; mt < 4; ++mt)
    #pragma unroll
    for (int nt = 0; nt < 6; ++nt) {
      int col = wn + nt*16 + fr;
      int which = col >> 6, dh = col & 63;
      float bv = bqkv[which*512 + h*64 + dh];
      float sc = (which == 0) ? 0.125f : 1.f;
      #pragma unroll
      for (int j = 0; j < 4; ++j) {
        int row = wm + mt*16 + fq*4 + j;
        u.e.qkv[row][col] = (_Float16)((acc[mt][nt][j] + bv) * sc);
      }
    }
  __syncthreads();
  {
    int i = t >> 5, qi = (t >> 1) & 15, kio = (t & 1) * 8;
    for (int ki = kio; ki < kio + 8; ++ki) {
      float s = 0.f;
      const _Float16* qr = &u.e.qkv[i*16 + qi][0];
      const _Float16* kr = &u.e.qkv[i*16 + ki][64];
      #pragma unroll
      for (int d = 0; d < 64; ++d) s += (float)qr[d] * (float)kr[d];
      u.e.S[i*256 + qi*16 + ki] = s;
    }
  }
  __syncthreads();
  if (t < 128) {
    int i = t >> 4, qi = t & 15;
    float* Sr = &u.e.S[i*256 + qi*16];
    float mx = -1e30f;
    #pragma unroll
    for (int ki = 0; ki < 16; ++ki) mx = fmaxf(mx, Sr[ki]);
    float sm = 0.f;
    float e[16];
    #pragma unroll
    for (int ki = 0; ki < 16; ++ki) { e[ki] = expf(Sr[ki] - mx); sm += e[ki]; }
    float inv = 1.f / sm;
    #pragma unroll
    for (int ki = 0; ki < 16; ++ki) Sr[ki] = e[ki]*inv;
  }
  __syncthreads();
  {
    int i = t >> 5, q2 = t & 31;
    int qi = q2 >> 1, dh0 = (q2 & 1) * 32;
    const float* Sr = &u.e.S[i*256 + qi*16];
    size_t orow = ((size_t)(bx*8 + i)*16 + qi)*512 + h*64;
    for (int dh = dh0; dh < dh0 + 32; dh += 2) {
      float a0 = 0.f, a1 = 0.f;
      #pragma unroll
      for (int ki = 0; ki < 16; ++ki) {
        float p = Sr[ki];
        a0 += p * (float)u.e.qkv[i*16 + ki][128 + dh];
        a1 += p * (float)u.e.qkv[i*16 + ki][128 + dh + 1];
      }
      *(__half2*)&attnout[orow + dh] = __floats2half2_rn(a0, a1);
    }
  }
}

// ---------------- generic MFMA GEMM: C = act(A@B + bias), 128x128x32 tiles ----------------
template<int A16, int B16, int RELU, int OUT16>
__global__ __launch_bounds__(256) void k_mgemm(const void* __restrict__ Ap,
    const void* __restrict__ Bp, const float* __restrict__ bias,
    void* __restrict__ Cp, int M, int N, int K) {
  __shared__ _Float16 sA[128][40];
  __shared__ _Float16 sB[128][40];
  int t = threadIdx.x;
  int bm = blockIdx.x * 128, bn = blockIdx.y * 128;
  int w = t >> 6, lane = t & 63;
  int wm = (w >> 1) * 64, wn = (w & 1) * 64;
  int fr = lane & 15, fq = lane >> 4;
  f32x4 acc[4][4];
  #pragma unroll
  for (int mt = 0; mt < 4; ++mt)
    #pragma unroll
    for (int nt = 0; nt < 4; ++nt) acc[mt][nt] = vzero4();
  int srow = t >> 1, skh = (t & 1) * 16;
  for (int k0 = 0; k0 < K; k0 += 32) {
    if (A16) {
      const __half* A = (const __half*)Ap;
      const ulonglong2* src = (const ulonglong2*)&A[(size_t)(bm + srow)*K + k0 + skh];
      *(ulonglong2*)&sA[srow][skh]   = src[0];
      *(ulonglong2*)&sA[srow][skh+8] = src[1];
    } else {
      const float* A = (const float*)Ap;
      const float4* src = (const float4*)&A[(size_t)(bm + srow)*K + k0 + skh];
      float4 v0 = src[0], v1 = src[1], v2 = src[2], v3 = src[3];
      f16x8 h0, h1;
      h0[0]=(_Float16)v0.x; h0[1]=(_Float16)v0.y; h0[2]=(_Float16)v0.z; h0[3]=(_Float16)v0.w;
      h0[4]=(_Float16)v1.x; h0[5]=(_Float16)v1.y; h0[6]=(_Float16)v1.z; h0[7]=(_Float16)v1.w;
      h1[0]=(_Float16)v2.x; h1[1]=(_Float16)v2.y; h1[2]=(_Float16)v2.z; h1[3]=(_Float16)v2.w;
      h1[4]=(_Float16)v3.x; h1[5]=(_Float16)v3.y; h1[6]=(_Float16)v3.z; h1[7]=(_Float16)v3.w;
      *(f16x8*)&sA[srow][skh]   = h0;
      *(f16x8*)&sA[srow][skh+8] = h1;
    }
    if (B16) {
      const __half* BT = (const __half*)Bp;
      const ulonglong2* src = (const ulonglong2*)&BT[(size_t)(bn + srow)*K + k0 + skh];
      *(ulonglong2*)&sB[srow][skh]   = src[0];
      *(ulonglong2*)&sB[srow][skh+8] = src[1];
    } else {
      const float* B = (const float*)Bp;
      int kr = t >> 3, n0 = (t & 7) * 16;
      #pragma unroll
      for (int g = 0; g < 4; ++g) {
        float4 v = *(const float4*)&B[(size_t)(k0 + kr)*N + bn + n0 + g*4];
        sB[n0+g*4+0][kr] = (_Float16)v.x;
        sB[n0+g*4+1][kr] = (_Float16)v.y;
        sB[n0+g*4+2][kr] = (_Float16)v.z;
        sB[n0+g*4+3][kr] = (_Float16)v.w;
      }
    }
    __syncthreads();
    f16x8 af[4], bf[4];
    #pragma unroll
    for (int mt = 0; mt < 4; ++mt) af[mt] = *(const f16x8*)&sA[wm + mt*16 + fr][fq*8];
    #pragma unroll
    for (int nt = 0; nt < 4; ++nt) bf[nt] = *(const f16x8*)&sB[wn + nt*16 + fr][fq*8];
    #pragma unroll
    for (int mt = 0; mt < 4; ++mt)
      #pragma unroll
      for (int nt = 0; nt < 4; ++nt)
        acc[mt][nt] = __builtin_amdgcn_mfma_f32_16x16x32_f16(af[mt], bf[nt], acc[mt][nt], 0, 0, 0);
    __syncthreads();
  }
  #pragma unroll
  for (int mt = 0; mt < 4; ++mt)
    #pragma unroll
    for (int nt = 0; nt < 4; ++nt) {
      int col = bn + wn + nt*16 + fr;
      float bv = bias[col];
      #pragma unroll
      for (int j = 0; j < 4; ++j) {
        int row = bm + wm + mt*16 + fq*4 + j;
        float v = acc[mt][nt][j] + bv;
        if (RELU) v = fmaxf(v, 0.f);
        if (OUT16) ((__half*)Cp)[(size_t)row*N + col] = __float2half(v);
        else       ((float*)Cp)[(size_t)row*N + col] = v;
      }
    }
}

// ---------------- t2 = t + LN(gemm_out): token-wise, writes back into act (token layout) ----------------
__global__ __launch_bounds__(256) void k_lnres(const __half* __restrict__ pout,
    float* __restrict__ tact) {
  int t = threadIdx.x;
  int tok = blockIdx.x*4 + (t >> 6);
  int lane = t & 63;
  f16x8 hv = *(const f16x8*)&pout[(size_t)tok*512 + lane*8];
  float v[8]; float s1 = 0.f, s2 = 0.f;
  #pragma unroll
  for (int j = 0; j < 8; ++j) { v[j] = (float)hv[j]; s1 += v[j]; s2 += v[j]*v[j]; }
  #pragma unroll
  for (int m = 32; m >= 1; m >>= 1) { s1 += __shfl_xor(s1, m); s2 += __shfl_xor(s2, m); }
  float mean = s1 * (1.f/512.f);
  float var  = s2 * (1.f/512.f) - mean*mean;
  float rs = rsqrtf(var + 1e-6f);
  float* ar = &tact[(size_t)tok*512 + lane*8];
  #pragma unroll
  for (int j = 0; j < 8; ++j) ar[j] += (v[j] - mean)*rs;
}

// ---------------- t2 + LN(fc2out), window_reverse to spatial, per image in-place ----------------
__global__ __launch_bounds__(256) void k_lnres2(const __half* __restrict__ fout,
    float* __restrict__ actimg) {
  __shared__ float s_t2[8192];
  int bimg = blockIdx.x, t = threadIdx.x;
  int lane = t & 63;
  for (int tg = 0; tg < 4; ++tg) {
    int n = tg*4 + (t >> 6);
    size_t row = (size_t)bimg*16 + n;
    f16x8 hv = *(const f16x8*)&fout[row*512 + lane*8];
    float v[8]; float s1 = 0.f, s2 = 0.f;
    #pragma unroll
    for (int j = 0; j < 8; ++j) { v[j] = (float)hv[j]; s1 += v[j]; s2 += v[j]*v[j]; }
    #pragma unroll
    for (int m = 32; m >= 1; m >>= 1) { s1 += __shfl_xor(s1, m); s2 += __shfl_xor(s2, m); }
    float mean = s1 * (1.f/512.f);
    float var  = s2 * (1.f/512.f) - mean*mean;
    float rs = rsqrtf(var + 1e-6f);
    const float* ar = &actimg[row*512 + lane*8];
    #pragma unroll
    for (int j = 0; j < 8; ++j) s_t2[n*512 + lane*8 + j] = ar[j] + (v[j] - mean)*rs;
  }
  __syncthreads();
  for (int idx = t; idx < 2048; idx += 256) {
    int p = idx >> 5, c = (idx & 31)*4;
    int y = p >> 3, x = p & 7;
    int n = (y >> 1)*4 + (x >> 1);
    int d = ((y & 1)*2 + (x & 1))*128 + c;
    *(float4*)&actimg[(size_t)bimg*8192 + p*128 + c] = *(float4*)&s_t2[n*512 + d];
  }
}

// ---------------- row softmax (640) ----------------
__global__ __launch_bounds__(256) void k_softmax(const float* __restrict__ logits, float* __restrict__ out) {
  int b = blockIdx.x, t = threadIdx.x;
  __shared__ float red[256];
  float m = -1e30f;
  for (int j = t; j < 640; j += 256) m = fmaxf(m, logits[(size_t)b*640 + j]);
  red[t] = m; __syncthreads();
  for (int s = 128; s > 0; s >>= 1) { if (t < s) red[t] = fmaxf(red[t], red[t+s]); __syncthreads(); }
  m = red[0]; __syncthreads();
  float sum = 0.f;
  for (int j = t; j < 640; j += 256) sum += expf(logits[(size_t)b*640 + j] - m);
  red[t] = sum; __syncthreads();
  for (int s = 128; s > 0; s >>= 1) { if (t < s) red[t] += red[t+s]; __syncthreads(); }
  float inv = 1.f / red[0];
  for (int j = t; j < 640; j += 256) out[(size_t)b*640 + j] = expf(logits[(size_t)b*640 + j] - m) * inv;
}

// ---------------- host ----------------
extern "C" void kernel_launch(void* const* d_in, const int* in_sizes, int n_in,
                              void* d_out, int out_size, void* d_ws, size_t ws_size,
                              hipStream_t stream) {
  (void)in_sizes; (void)n_in;
  float* out = (float*)d_out;
  if (ws_size < (size_t)WS_NEED_FLOATS * 4) {
    k_sentinel<<<2048, 256, 0, stream>>>(out, out_size, (float)(ws_size >> 20));
    return;
  }

  const int*   x       = (const int*)d_in[0];
  const float* pos     = (const float*)d_in[1];
  const float* conv1_w = (const float*)d_in[2];
  const float* conv1_b = (const float*)d_in[3];
  const float* rb1_w   = (const float*)d_in[4];
  const float* rb1_b   = (const float*)d_in[5];
  const float* bn1_g   = (const float*)d_in[6];
  const float* bn1_b   = (const float*)d_in[7];
  const float* rb2_w   = (const float*)d_in[8];
  const float* rb2_b   = (const float*)d_in[9];
  const float* bn2_g   = (const float*)d_in[10];
  const float* bn2_b   = (const float*)d_in[11];
  const float* qkv_w   = (const float*)d_in[12];
  const float* qkv_b   = (const float*)d_in[13];
  const float* proj_w  = (const float*)d_in[14];
  const float* proj_b  = (const float*)d_in[15];
  const float* fc1_w   = (const float*)d_in[16];
  const float* fc1_b   = (const float*)d_in[17];
  const float* fc2_w   = (const float*)d_in[18];
  const float* fc2_b   = (const float*)d_in[19];
  const float* lin1_w  = (const float*)d_in[20];
  const float* lin1_b  = (const float*)d_in[21];
  const float* lin2_w  = (const float*)d_in[22];
  const float* lin2_b  = (const float*)d_in[23];

  float*  ws    = (float*)d_ws;
  float*  act   = ws + OFF_ACT;
  __half* big2h = (__half*)(ws + OFF_BIG2);
  float*  wT1   = ws + OFF_WT1;
  __half* wTa16 = (__half*)(ws + OFF_WTA);
  __half* wTb16 = (__half*)(ws + OFF_WTB);
  float*  stats = ws + OFF_STATS;
  float*  bnp   = ws + OFF_BNP;

  __half* z1h     = big2h;
  __half* attnout = big2h + H_ATT;
  __half* projout = big2h + H_PRJ;
  __half* h1      = big2h + H_H1;
  __half* fc2out  = projout;
  __half* qkvT    = big2h + H_WQT;
  __half* projT   = big2h + H_WPT;
  __half* fc1T    = big2h + H_WF1;
  __half* fc2T    = big2h + H_WF2;
  __half* L1h     = big2h;
  float*  logits  = (float*)(big2h + H_LOG);
  __half* lin2T   = big2h + H_L2T;

  k_zero<<<1, 256, 0, stream>>>(stats);
  k_wprep<<<64, 256, 0, stream>>>(conv1_w, wT1, 1, 12);
  k_wprep16<<<2048, 256, 0, stream>>>(rb1_w, wTa16, 10);
  k_wprep16<<<2048, 256, 0, stream>>>(rb2_w, wTb16, 10);
  k_conv1<<<NBATCH, 256, 0, stream>>>(x, wT1, conv1_b, act);

  for (int l = 0; l < 10; ++l) {
    k_conv_mfma<float><<<NBATCH/2, 256, 0, stream>>>(act, wTa16 + (size_t)l*147456,
        rb1_b + l*128, (const float*)nullptr, 0, z1h);
    k_stats<<<512, 256, 0, stream>>>(z1h, stats);
    k_bnfin<<<1, 128, 0, stream>>>(stats, bn1_g + l*128, bn1_b + l*128, bnp);
    k_conv_mfma<__half><<<NBATCH/2, 256, 0, stream>>>(z1h, wTb16 + (size_t)l*147456,
        rb2_b + l*128, bnp, 1, z1h);
    k_stats<<<512, 256, 0, stream>>>(z1h, stats);
    k_bnfin<<<1, 128, 0, stream>>>(stats, bn2_g + l*128, bn2_b + l*128, bnp);
    k_make_t<<<NBATCH, 256, 0, stream>>>(act, z1h, bnp, pos);   // z1h dead after this

    k_wt16<<<1024, 256, 0, stream>>>(qkv_w + (size_t)l*786432, qkvT, 512, 1536);
    k_wt16<<<512,  256, 0, stream>>>(proj_w + (size_t)l*262144, projT, 512, 512);
    k_wt16<<<512,  256, 0, stream>>>(fc1_w + (size_t)l*262144, fc1T, 512, 512);
    k_wt16<<<512,  256, 0, stream>>>(fc2_w + (size_t)l*262144, fc2T, 512, 512);

    for (int ch = 0; ch < NBATCH/CH; ++ch) {
      float* tchunk = act + (size_t)ch*CH*8192;
      k_qkv_attn<<<dim3(CH/8, 8), 256, 0, stream>>>(tchunk, qkvT, qkv_b + l*1536, attnout);
      k_mgemm<1,1,0,1><<<dim3(CH*16/128, 4), 256, 0, stream>>>(attnout, projT,
          proj_b + l*512, projout, CH*16, 512, 512);
      k_lnres<<<CH*16/4, 256, 0, stream>>>(projout, tchunk);
      k_mgemm<0,1,1,1><<<dim3(CH*16/128, 4), 256, 0, stream>>>(tchunk, fc1T,
          fc1_b + l*512, h1, CH*16, 512, 512);
      k_mgemm<1,1,0,1><<<dim3(CH*16/128, 4), 256, 0, stream>>>(h1, fc2T,
          fc2_b + l*512, fc2out, CH*16, 512, 512);
      k_lnres2<<<CH, 256, 0, stream>>>(fc2out, tchunk);
    }
  }
  k_mgemm<0,0,1,1><<<dim3(4096/128, 8), 256, 0, stream>>>(act, lin1_w, lin1_b, L1h,
      4096, 1024, 8192);
  k_wt16<<<512, 256, 0, stream>>>(lin2_w, lin2T, 1024, 640);
  k_mgemm<1,1,0,0><<<dim3(4096/128, 5), 256, 0, stream>>>(L1h, lin2T, lin2_b, logits,
      4096, 640, 1024);
  k_softmax<<<NBATCH, 256, 0, stream>>>(logits, out);
}

// Round 7
// 11710.255 us; speedup vs baseline: 25.9582x; 1.0889x over previous
//
#include <hip/hip_runtime.h>
#include <hip/hip_fp16.h>
#include <math.h>

// betaChessAI forward: 10 blocks of {conv-bn-conv-bn residual, windowed attention, MLP}
// Layouts:
//   spatial activations: act[(b*64 + p)*128 + c], p = y*8+x   (== feat layout for head)
//   token activations:   t[(b*16 + n)*512 + d],  d = (p1*2+p2)*128 + c, n = hy*4+wx
//   mapping: (y,x) = (2*hy+p1, 2*wx+p2)
// Workspace (float slots), ~210.4 MB total:
//   act f32 (33.55M) | big2 (16.78M f32 = 33.55M halfs) | wT1 f32 | wTa16/wTb16 f16 | wTt f16 | stats | bnp

#define NBATCH 4096
#define NPOSR  (NBATCH*64)
#define CH     2048                    // images per attention chunk

#define OFF_ACT   0
#define OFF_BIG2  33554432
#define OFF_WT1   (OFF_BIG2 + 16777216)
#define OFF_WTA   (OFF_WT1 + 13824)    // f16 [10][128][1152] in 737,280 f32 slots
#define OFF_WTB   (OFF_WTA + 737280)
#define OFF_WTT   (OFF_WTB + 737280)   // f16 transformer weights, 1,572,864 halfs
#define OFF_STATS (OFF_WTT + 786432)
#define OFF_BNP   (OFF_STATS + 256)
#define WS_NEED_FLOATS (OFF_BNP + 256)

// big2 half-offsets (attention phase, CH=2048)
#define H_ATT  0                       // attnout [32768][512] h, also h1 (aliased)
#define H_PRJ  16777216                // projout [32768][512] h, also fc2out
#define H_LOG  8388608                 // head: logits f32 at big2h+H_LOG (halfs 8.39M..13.63M)

// wTt half-offsets
#define T_QKV  0
#define T_PRJ  786432
#define T_F1   1048576
#define T_F2   1310720

typedef _Float16 f16x8 __attribute__((ext_vector_type(8)));
typedef _Float16 f16x4 __attribute__((ext_vector_type(4)));
typedef float f32x4 __attribute__((ext_vector_type(4)));

__device__ inline f32x4 vzero4() { f32x4 z; z[0]=0.f; z[1]=0.f; z[2]=0.f; z[3]=0.f; return z; }

__device__ inline float4 ld_half4(const __half* p) {
  float2 a = __half22float2(*(const __half2*)p);
  float2 b = __half22float2(*(const __half2*)(p + 2));
  return make_float4(a.x, a.y, b.x, b.y);
}

// ---------------- utility ----------------
__global__ void k_zero(float* __restrict__ s) { s[threadIdx.x] = 0.f; }

__global__ void k_sentinel(float* __restrict__ out, int n, float val) {
  for (int i = blockIdx.x*blockDim.x + threadIdx.x; i < n; i += gridDim.x*blockDim.x)
    out[i] = val;
}

// src[l][co][ci][kk] (co=128,ci=12,kk=9) -> dst[(kk*12+ci)*128+co]  (conv1 f32 path)
__global__ void k_wprep(const float* __restrict__ src, float* __restrict__ dst, int L, int Cin) {
  int total = L * 128 * Cin * 9;
  for (int idx = blockIdx.x*blockDim.x + threadIdx.x; idx < total; idx += gridDim.x*blockDim.x) {
    int kk = idx % 9; int t2 = idx / 9;
    int ci = t2 % Cin; t2 /= Cin;
    int co = t2 % 128; int l  = t2 / 128;
    dst[((size_t)(l*9 + kk)*Cin + ci)*128 + co] = src[idx];
  }
}

// src[l][co][ci][kk] (128x128x9) -> dst f16 [(l*128+co)*1152 + kk*128 + ci]
__global__ void k_wprep16(const float* __restrict__ src, __half* __restrict__ dst, int L) {
  int total = L * 128 * 128 * 9;
  for (int idx = blockIdx.x*blockDim.x + threadIdx.x; idx < total; idx += gridDim.x*blockDim.x) {
    int kk = idx % 9; int t2 = idx / 9;
    int ci = t2 % 128; t2 /= 128;
    int co = t2 % 128; int l  = t2 / 128;
    dst[((size_t)(l*128 + co))*1152 + kk*128 + ci] = __float2half(src[idx]);
  }
}

// W f32 [K][N] -> WT f16 [N][K]
__global__ void k_wt16(const float* __restrict__ W, __half* __restrict__ WT, int K, int N) {
  int total = K * N;
  for (int idx = blockIdx.x*blockDim.x + threadIdx.x; idx < total; idx += gridDim.x*blockDim.x) {
    int k = idx / N, n = idx % N;
    WT[(size_t)n*K + k] = __float2half(W[idx]);
  }
}

// One layer's qkv/proj/fc1/fc2 f32 -> transposed f16 into wTt
__global__ void k_wt16x4(const float* __restrict__ Wq, const float* __restrict__ Wp,
                         const float* __restrict__ W1, const float* __restrict__ W2,
                         __half* __restrict__ wTt) {
  const int TOT = 786432 + 3*262144;
  for (int idx = blockIdx.x*blockDim.x + threadIdx.x; idx < TOT; idx += gridDim.x*blockDim.x) {
    if (idx < 786432) {
      int k = idx / 1536, n = idx % 1536;
      wTt[T_QKV + (size_t)n*512 + k] = __float2half(Wq[idx]);
    } else {
      int r0 = idx - 786432;
      int s = r0 / 262144, r = r0 % 262144;
      int k = r / 512, n = r % 512;
      const float* W = (s == 0) ? Wp : (s == 1) ? W1 : W2;
      wTt[T_PRJ + s*262144 + (size_t)n*512 + k] = __float2half(W[r]);
    }
  }
}

// ---------------- encode + conv1 (one-hot lookup), output f32 act ----------------
__global__ __launch_bounds__(256) void k_conv1(const int* __restrict__ xin,
    const float* __restrict__ wT1, const float* __restrict__ b1,
    float* __restrict__ out) {
  __shared__ int s_w[64], s_b[64];
  int b = blockIdx.x, t = threadIdx.x;
  if (t < 64) { s_w[t] = xin[b*128 + t]; s_b[t] = xin[b*128 + 64 + t]; }
  __syncthreads();
  int p = t >> 2, i = t & 3;
  int y = p >> 3, x = p & 7;
  float acc[32];
  #pragma unroll
  for (int j = 0; j < 32; ++j) acc[j] = b1[i*32 + j];
  #pragma unroll
  for (int kk = 0; kk < 9; ++kk) {
    int ny = y + kk/3 - 1, nx = x + kk%3 - 1;
    if (ny < 0 || ny > 7 || nx < 0 || nx > 7) continue;
    int np = ny*8 + nx;
    int wp = s_w[np], bp = s_b[np];
    if (wp >= 1 && wp <= 6) {
      const float* w = &wT1[(size_t)(kk*12 + (wp-1))*128 + i*32];
      #pragma unroll
      for (int j = 0; j < 32; ++j) acc[j] += w[j];
    }
    if (bp >= 1 && bp <= 6) {
      const float* w = &wT1[(size_t)(kk*12 + 6 + (bp-1))*128 + i*32];
      #pragma unroll
      for (int j = 0; j < 32; ++j) acc[j] += w[j];
    }
  }
  float* o = &out[((size_t)b*64 + p)*128 + i*32];
  #pragma unroll
  for (int j = 0; j < 8; ++j)
    *(float4*)&o[j*4] = make_float4(acc[j*4], acc[j*4+1], acc[j*4+2], acc[j*4+3]);
}

// ---------------- MFMA residual 3x3 conv + fused BN stats ----------------
// out(h16) = conv3x3(relu(bn?(in))) + bias; stats += per-channel (sum, sumsq) of f32 acc.
// 2 images per block, M=128, N=128, K=1152. 36 barrier-pairs (64-K staging windows).
__device__ inline float cvt_in(float v) { return v; }
__device__ inline float cvt_in(__half v) { return __half2float(v); }

#define IMG_W 136

template<typename TIN>
__global__ __launch_bounds__(256) void k_conv_mfma(const TIN* __restrict__ in,
    const __half* __restrict__ wT /* [128][1152] f16 */, const float* __restrict__ bias,
    const float* __restrict__ bnp, int use_bn, __half* __restrict__ out,
    float* __restrict__ stats) {
  __shared__ __align__(16) _Float16 s_img[2*65*IMG_W];  // 35,360 B (row 64 = zeros)
  __shared__ __align__(16) _Float16 s_B[128][68];       // 17,408 B (64 K-cols + pad)
  __shared__ float s_sum[128], s_sq[128];               // 1 KB
  int b2 = blockIdx.x, t = threadIdx.x;
  // stage 2 images: bn+relu, -> f16
  for (int idx4 = t; idx4 < 4096; idx4 += 256) {
    int img = idx4 >> 11, rr = (idx4 >> 5) & 63, c4 = (idx4 & 31) * 4;
    const TIN* src = &in[((size_t)(b2*2 + img)*64 + rr)*128 + c4];
    float v0 = cvt_in(src[0]), v1 = cvt_in(src[1]), v2 = cvt_in(src[2]), v3 = cvt_in(src[3]);
    if (use_bn) {
      v0 = bnp[c4+0]*v0 + bnp[128+c4+0];
      v1 = bnp[c4+1]*v1 + bnp[128+c4+1];
      v2 = bnp[c4+2]*v2 + bnp[128+c4+2];
      v3 = bnp[c4+3]*v3 + bnp[128+c4+3];
    }
    f16x4 h;
    h[0] = (_Float16)fmaxf(v0, 0.f); h[1] = (_Float16)fmaxf(v1, 0.f);
    h[2] = (_Float16)fmaxf(v2, 0.f); h[3] = (_Float16)fmaxf(v3, 0.f);
    *(f16x4*)&s_img[(img*65 + rr)*IMG_W + c4] = h;
  }
  { // zero halo row per image + zero stats accumulators
    int img = t >> 7, c = t & 127;
    s_img[(img*65 + 64)*IMG_W + c] = (_Float16)0.f;
    if (t < 128) { s_sum[t] = 0.f; s_sq[t] = 0.f; }
  }
  int w = t >> 6, lane = t & 63;
  int wm = (w >> 1)*64, wn = (w & 1)*64;
  int fr = lane & 15, fq = lane >> 4;
  int imgo[4], yy[4], xx_[4];
  #pragma unroll
  for (int mt = 0; mt < 4; ++mt) {
    int r = wm + mt*16 + fr;
    imgo[mt] = r >> 6; int p = r & 63; yy[mt] = p >> 3; xx_[mt] = p & 7;
  }
  f32x4 acc[4][4];
  #pragma unroll
  for (int mt = 0; mt < 4; ++mt)
    #pragma unroll
    for (int nt = 0; nt < 4; ++nt) acc[mt][nt] = vzero4();
  int sn = t >> 1, skh2 = (t & 1) * 32;
  const __half* wrow = &wT[(size_t)sn*1152];
  for (int kk = 0; kk < 9; ++kk) {
    int dy = kk/3 - 1, dx = kk%3 - 1;
    const _Float16* abase[4];
    #pragma unroll
    for (int mt = 0; mt < 4; ++mt) {
      int ny = yy[mt] + dy, nx = xx_[mt] + dx;
      int row = ((unsigned)ny < 8u && (unsigned)nx < 8u) ? (ny*8 + nx) : 64;
      abase[mt] = &s_img[(imgo[mt]*65 + row)*IMG_W];
    }
    #pragma unroll
    for (int half = 0; half < 2; ++half) {
      int kb = kk*128 + half*64 + skh2;
      __syncthreads();   // first iter also covers image staging
      *(ulonglong2*)&s_B[sn][skh2+0]  = *(const ulonglong2*)&wrow[kb + 0];
      *(ulonglong2*)&s_B[sn][skh2+8]  = *(const ulonglong2*)&wrow[kb + 8];
      *(ulonglong2*)&s_B[sn][skh2+16] = *(const ulonglong2*)&wrow[kb + 16];
      *(ulonglong2*)&s_B[sn][skh2+24] = *(const ulonglong2*)&wrow[kb + 24];
      __syncthreads();
      #pragma unroll
      for (int ks2 = 0; ks2 < 2; ++ks2) {
        f16x8 af[4], bf[4];
        #pragma unroll
        for (int mt = 0; mt < 4; ++mt) af[mt] = *(const f16x8*)&abase[mt][half*64 + ks2*32 + fq*8];
        #pragma unroll
        for (int nt = 0; nt < 4; ++nt) bf[nt] = *(const f16x8*)&s_B[wn + nt*16 + fr][ks2*32 + fq*8];
        #pragma unroll
        for (int mt = 0; mt < 4; ++mt)
          #pragma unroll
          for (int nt = 0; nt < 4; ++nt)
            acc[mt][nt] = __builtin_amdgcn_mfma_f32_16x16x32_f16(af[mt], bf[nt], acc[mt][nt], 0, 0, 0);
      }
    }
  }
  // epilogue: bias, write f16, fused per-channel stats
  #pragma unroll
  for (int nt = 0; nt < 4; ++nt) {
    int col = wn + nt*16 + fr;
    float bv = bias[col];
    float s = 0.f, q = 0.f;
    #pragma unroll
    for (int mt = 0; mt < 4; ++mt) {
      int rbase = wm + mt*16 + fq*4;
      #pragma unroll
      for (int j = 0; j < 4; ++j) {
        int r = rbase + j;
        int img = r >> 6, p = r & 63;
        float v = acc[mt][nt][j] + bv;
        s += v; q += v*v;
        out[((size_t)(b2*2 + img)*64 + p)*128 + col] = __float2half(v);
      }
    }
    // reduce over fq lanes (xor 16, 32), then one LDS atomic per col per wave
    s += __shfl_xor(s, 16); s += __shfl_xor(s, 32);
    q += __shfl_xor(q, 16); q += __shfl_xor(q, 32);
    if (fq == 0) { atomicAdd(&s_sum[col], s); atomicAdd(&s_sq[col], q); }
  }
  __syncthreads();
  if (t < 128) {
    atomicAdd(&stats[t], s_sum[t]);
    atomicAdd(&stats[128 + t], s_sq[t]);
  }
}

__global__ void k_bnfin(float* __restrict__ stats, const float* __restrict__ g,
                        const float* __restrict__ bb, float* __restrict__ bnp) {
  int c = threadIdx.x;
  const float invN = 1.f / (float)NPOSR;
  float m = stats[c] * invN;
  float v = stats[128+c] * invN - m*m;
  float sc = g[c] * rsqrtf(v + 1e-5f);
  bnp[c] = sc;
  bnp[128+c] = bb[c] - m*sc;
  stats[c] = 0.f; stats[128+c] = 0.f;
}

// ---------------- t = window_partition(act + bn2(z1h)) + pos, in-place per image ----------------
__global__ __launch_bounds__(256) void k_make_t(float* __restrict__ act,
    const __half* __restrict__ z1h, const float* __restrict__ bnp,
    const float* __restrict__ pos) {
  __shared__ float s_t[8192];
  int b = blockIdx.x, t = threadIdx.x;
  for (int idx4 = t; idx4 < 2048; idx4 += 256) {
    int n = idx4 >> 7, d4 = idx4 & 127;
    int d = d4*4, c = d & 127, q = d >> 7;
    int y = ((n>>2)<<1) + (q>>1), xx = ((n&3)<<1) + (q&1);
    size_t sp = ((size_t)b*64 + y*8 + xx)*128 + c;
    float4 a  = *(const float4*)&act[sp];
    float4 z  = ld_half4(&z1h[sp]);
    float4 sc = *(const float4*)&bnp[c];
    float4 sh = *(const float4*)&bnp[128+c];
    float4 pe = *(const float4*)&pos[n*512 + d];
    float4 o;
    o.x = a.x + sc.x*z.x + sh.x + pe.x;
    o.y = a.y + sc.y*z.y + sh.y + pe.y;
    o.z = a.z + sc.z*z.z + sh.z + pe.z;
    o.w = a.w + sc.w*z.w + sh.w + pe.w;
    *(float4*)&s_t[n*512 + d] = o;
  }
  __syncthreads();
  for (int idx4 = t; idx4 < 2048; idx4 += 256)
    *(float4*)&act[(size_t)b*8192 + idx4*4] = *(float4*)&s_t[idx4*4];
}

// ---------------- fused qkv GEMM + windowed attention (per 8 images x 1 head) ----------------
__global__ __launch_bounds__(256) void k_qkv_attn(const float* __restrict__ tG,
    const __half* __restrict__ WqkvT, const float* __restrict__ bqkv,
    __half* __restrict__ attnout) {
  union SmemU {
    struct { _Float16 A[128][40]; _Float16 B[192][40]; } g;
    struct { _Float16 qkv[128][200]; float S[2048]; } e;
  };
  __shared__ SmemU u;
  int t = threadIdx.x;
  int bx = blockIdx.x, h = blockIdx.y;
  int w = t >> 6, lane = t & 63;
  int wm = (w >> 1) * 64, wn = (w & 1) * 96;
  int fr = lane & 15, fq = lane >> 4;
  f32x4 acc[4][6];
  #pragma unroll
  for (int mt = 0; mt < 4; ++mt)
    #pragma unroll
    for (int nt = 0; nt < 6; ++nt) acc[mt][nt] = vzero4();
  int srow = t >> 1, skh = (t & 1) * 16;
  for (int k0 = 0; k0 < 512; k0 += 32) {
    {
      const float4* src = (const float4*)&tG[(size_t)(bx*128 + srow)*512 + k0 + skh];
      float4 v0 = src[0], v1 = src[1], v2 = src[2], v3 = src[3];
      f16x8 h0, h1;
      h0[0]=(_Float16)v0.x; h0[1]=(_Float16)v0.y; h0[2]=(_Float16)v0.z; h0[3]=(_Float16)v0.w;
      h0[4]=(_Float16)v1.x; h0[5]=(_Float16)v1.y; h0[6]=(_Float16)v1.z; h0[7]=(_Float16)v1.w;
      h1[0]=(_Float16)v2.x; h1[1]=(_Float16)v2.y; h1[2]=(_Float16)v2.z; h1[3]=(_Float16)v2.w;
      h1[4]=(_Float16)v3.x; h1[5]=(_Float16)v3.y; h1[6]=(_Float16)v3.z; h1[7]=(_Float16)v3.w;
      *(f16x8*)&u.g.A[srow][skh] = h0;
      *(f16x8*)&u.g.A[srow][skh+8] = h1;
    }
    for (int r = t; r < 384; r += 256) {
      int n = r >> 1, kh = (r & 1) * 16;
      int ng = ((n >> 6) * 512) + h*64 + (n & 63);
      const ulonglong2* src = (const ulonglong2*)&WqkvT[(size_t)ng*512 + k0 + kh];
      *(ulonglong2*)&u.g.B[n][kh]   = src[0];
      *(ulonglong2*)&u.g.B[n][kh+8] = src[1];
    }
    __syncthreads();
    f16x8 af[4], bf[6];
    #pragma unroll
    for (int mt = 0; mt < 4; ++mt) af[mt] = *(const f16x8*)&u.g.A[wm + mt*16 + fr][fq*8];
    #pragma unroll
    for (int nt = 0; nt < 6; ++nt) bf[nt] = *(const f16x8*)&u.g.B[wn + nt*16 + fr][fq*8];
    #pragma unroll
    for (int mt = 0; mt < 4; ++mt)
      #pragma unroll
      for (int nt = 0; nt < 6; ++nt)
        acc[mt][nt] = __builtin_amdgcn_mfma_f32_16x16x32_f16(af[mt], bf[nt], acc[mt][nt], 0, 0, 0);
    __syncthreads();
  }
  #pragma unroll
  for (int mt = 0; mt < 4; ++mt)
    #pragma unroll
    for (int nt = 0; nt < 6; ++nt) {
      int col = wn + nt*16 + fr;
      int which = col >> 6, dh = col & 63;
      float bv = bqkv[which*512 + h*64 + dh];
      float sc = (which == 0) ? 0.125f : 1.f;
      #pragma unroll
      for (int j = 0; j < 4; ++j) {
        int row = wm + mt*16 + fq*4 + j;
        u.e.qkv[row][col] = (_Float16)((acc[mt][nt][j] + bv) * sc);
      }
    }
  __syncthreads();
  {
    int i = t >> 5, qi = (t >> 1) & 15, kio = (t & 1) * 8;
    for (int ki = kio; ki < kio + 8; ++ki) {
      float s = 0.f;
      const _Float16* qr = &u.e.qkv[i*16 + qi][0];
      const _Float16* kr = &u.e.qkv[i*16 + ki][64];
      #pragma unroll
      for (int d = 0; d < 64; ++d) s += (float)qr[d] * (float)kr[d];
      u.e.S[i*256 + qi*16 + ki] = s;
    }
  }
  __syncthreads();
  if (t < 128) {
    int i = t >> 4, qi = t & 15;
    float* Sr = &u.e.S[i*256 + qi*16];
    float mx = -1e30f;
    #pragma unroll
    for (int ki = 0; ki < 16; ++ki) mx = fmaxf(mx, Sr[ki]);
    float sm = 0.f;
    float e[16];
    #pragma unroll
    for (int ki = 0; ki < 16; ++ki) { e[ki] = expf(Sr[ki] - mx); sm += e[ki]; }
    float inv = 1.f / sm;
    #pragma unroll
    for (int ki = 0; ki < 16; ++ki) Sr[ki] = e[ki]*inv;
  }
  __syncthreads();
  {
    int i = t >> 5, q2 = t & 31;
    int qi = q2 >> 1, dh0 = (q2 & 1) * 32;
    const float* Sr = &u.e.S[i*256 + qi*16];
    size_t orow = ((size_t)(bx*8 + i)*16 + qi)*512 + h*64;
    for (int dh = dh0; dh < dh0 + 32; dh += 2) {
      float a0 = 0.f, a1 = 0.f;
      #pragma unroll
      for (int ki = 0; ki < 16; ++ki) {
        float p = Sr[ki];
        a0 += p * (float)u.e.qkv[i*16 + ki][128 + dh];
        a1 += p * (float)u.e.qkv[i*16 + ki][128 + dh + 1];
      }
      *(__half2*)&attnout[orow + dh] = __floats2half2_rn(a0, a1);
    }
  }
}

// ---------------- generic MFMA GEMM: C = act(A@B + bias), 128x128x32 tiles ----------------
template<int A16, int B16, int RELU, int OUT16>
__global__ __launch_bounds__(256) void k_mgemm(const void* __restrict__ Ap,
    const void* __restrict__ Bp, const float* __restrict__ bias,
    void* __restrict__ Cp, int M, int N, int K) {
  __shared__ _Float16 sA[128][40];
  __shared__ _Float16 sB[128][40];
  int t = threadIdx.x;
  int bm = blockIdx.x * 128, bn = blockIdx.y * 128;
  int w = t >> 6, lane = t & 63;
  int wm = (w >> 1) * 64, wn = (w & 1) * 64;
  int fr = lane & 15, fq = lane >> 4;
  f32x4 acc[4][4];
  #pragma unroll
  for (int mt = 0; mt < 4; ++mt)
    #pragma unroll
    for (int nt = 0; nt < 4; ++nt) acc[mt][nt] = vzero4();
  int srow = t >> 1, skh = (t & 1) * 16;
  for (int k0 = 0; k0 < K; k0 += 32) {
    if (A16) {
      const __half* A = (const __half*)Ap;
      const ulonglong2* src = (const ulonglong2*)&A[(size_t)(bm + srow)*K + k0 + skh];
      *(ulonglong2*)&sA[srow][skh]   = src[0];
      *(ulonglong2*)&sA[srow][skh+8] = src[1];
    } else {
      const float* A = (const float*)Ap;
      const float4* src = (const float4*)&A[(size_t)(bm + srow)*K + k0 + skh];
      float4 v0 = src[0], v1 = src[1], v2 = src[2], v3 = src[3];
      f16x8 h0, h1;
      h0[0]=(_Float16)v0.x; h0[1]=(_Float16)v0.y; h0[2]=(_Float16)v0.z; h0[3]=(_Float16)v0.w;
      h0[4]=(_Float16)v1.x; h0[5]=(_Float16)v1.y; h0[6]=(_Float16)v1.z; h0[7]=(_Float16)v1.w;
      h1[0]=(_Float16)v2.x; h1[1]=(_Float16)v2.y; h1[2]=(_Float16)v2.z; h1[3]=(_Float16)v2.w;
      h1[4]=(_Float16)v3.x; h1[5]=(_Float16)v3.y; h1[6]=(_Float16)v3.z; h1[7]=(_Float16)v3.w;
      *(f16x8*)&sA[srow][skh]   = h0;
      *(f16x8*)&sA[srow][skh+8] = h1;
    }
    if (B16) {
      const __half* BT = (const __half*)Bp;
      const ulonglong2* src = (const ulonglong2*)&BT[(size_t)(bn + srow)*K + k0 + skh];
      *(ulonglong2*)&sB[srow][skh]   = src[0];
      *(ulonglong2*)&sB[srow][skh+8] = src[1];
    } else {
      const float* B = (const float*)Bp;
      int kr = t >> 3, n0 = (t & 7) * 16;
      #pragma unroll
      for (int g = 0; g < 4; ++g) {
        float4 v = *(const float4*)&B[(size_t)(k0 + kr)*N + bn + n0 + g*4];
        sB[n0+g*4+0][kr] = (_Float16)v.x;
        sB[n0+g*4+1][kr] = (_Float16)v.y;
        sB[n0+g*4+2][kr] = (_Float16)v.z;
        sB[n0+g*4+3][kr] = (_Float16)v.w;
      }
    }
    __syncthreads();
    f16x8 af[4], bf[4];
    #pragma unroll
    for (int mt = 0; mt < 4; ++mt) af[mt] = *(const f16x8*)&sA[wm + mt*16 + fr][fq*8];
    #pragma unroll
    for (int nt = 0; nt < 4; ++nt) bf[nt] = *(const f16x8*)&sB[wn + nt*16 + fr][fq*8];
    #pragma unroll
    for (int mt = 0; mt < 4; ++mt)
      #pragma unroll
      for (int nt = 0; nt < 4; ++nt)
        acc[mt][nt] = __builtin_amdgcn_mfma_f32_16x16x32_f16(af[mt], bf[nt], acc[mt][nt], 0, 0, 0);
    __syncthreads();
  }
  #pragma unroll
  for (int mt = 0; mt < 4; ++mt)
    #pragma unroll
    for (int nt = 0; nt < 4; ++nt) {
      int col = bn + wn + nt*16 + fr;
      float bv = bias[col];
      #pragma unroll
      for (int j = 0; j < 4; ++j) {
        int row = bm + wm + mt*16 + fq*4 + j;
        float v = acc[mt][nt][j] + bv;
        if (RELU) v = fmaxf(v, 0.f);
        if (OUT16) ((__half*)Cp)[(size_t)row*N + col] = __float2half(v);
        else       ((float*)Cp)[(size_t)row*N + col] = v;
      }
    }
}

// ---------------- t2 = t + LN(gemm_out): token-wise, writes back into act (token layout) ----------------
__global__ __launch_bounds__(256) void k_lnres(const __half* __restrict__ pout,
    float* __restrict__ tact) {
  int t = threadIdx.x;
  int tok = blockIdx.x*4 + (t >> 6);
  int lane = t & 63;
  f16x8 hv = *(const f16x8*)&pout[(size_t)tok*512 + lane*8];
  float v[8]; float s1 = 0.f, s2 = 0.f;
  #pragma unroll
  for (int j = 0; j < 8; ++j) { v[j] = (float)hv[j]; s1 += v[j]; s2 += v[j]*v[j]; }
  #pragma unroll
  for (int m = 32; m >= 1; m >>= 1) { s1 += __shfl_xor(s1, m); s2 += __shfl_xor(s2, m); }
  float mean = s1 * (1.f/512.f);
  float var  = s2 * (1.f/512.f) - mean*mean;
  float rs = rsqrtf(var + 1e-6f);
  float* ar = &tact[(size_t)tok*512 + lane*8];
  #pragma unroll
  for (int j = 0; j < 8; ++j) ar[j] += (v[j] - mean)*rs;
}

// ---------------- t2 + LN(fc2out), window_reverse to spatial, per image in-place ----------------
__global__ __launch_bounds__(256) void k_lnres2(const __half* __restrict__ fout,
    float* __restrict__ actimg) {
  __shared__ float s_t2[8192];
  int bimg = blockIdx.x, t = threadIdx.x;
  int lane = t & 63;
  for (int tg = 0; tg < 4; ++tg) {
    int n = tg*4 + (t >> 6);
    size_t row = (size_t)bimg*16 + n;
    f16x8 hv = *(const f16x8*)&fout[row*512 + lane*8];
    float v[8]; float s1 = 0.f, s2 = 0.f;
    #pragma unroll
    for (int j = 0; j < 8; ++j) { v[j] = (float)hv[j]; s1 += v[j]; s2 += v[j]*v[j]; }
    #pragma unroll
    for (int m = 32; m >= 1; m >>= 1) { s1 += __shfl_xor(s1, m); s2 += __shfl_xor(s2, m); }
    float mean = s1 * (1.f/512.f);
    float var  = s2 * (1.f/512.f) - mean*mean;
    float rs = rsqrtf(var + 1e-6f);
    const float* ar = &actimg[row*512 + lane*8];
    #pragma unroll
    for (int j = 0; j < 8; ++j) s_t2[n*512 + lane*8 + j] = ar[j] + (v[j] - mean)*rs;
  }
  __syncthreads();
  for (int idx = t; idx < 2048; idx += 256) {
    int p = idx >> 5, c = (idx & 31)*4;
    int y = p >> 3, x = p & 7;
    int n = (y >> 1)*4 + (x >> 1);
    int d = ((y & 1)*2 + (x & 1))*128 + c;
    *(float4*)&actimg[(size_t)bimg*8192 + p*128 + c] = *(float4*)&s_t2[n*512 + d];
  }
}

// ---------------- row softmax (640) ----------------
__global__ __launch_bounds__(256) void k_softmax(const float* __restrict__ logits, float* __restrict__ out) {
  int b = blockIdx.x, t = threadIdx.x;
  __shared__ float red[256];
  float m = -1e30f;
  for (int j = t; j < 640; j += 256) m = fmaxf(m, logits[(size_t)b*640 + j]);
  red[t] = m; __syncthreads();
  for (int s = 128; s > 0; s >>= 1) { if (t < s) red[t] = fmaxf(red[t], red[t+s]); __syncthreads(); }
  m = red[0]; __syncthreads();
  float sum = 0.f;
  for (int j = t; j < 640; j += 256) sum += expf(logits[(size_t)b*640 + j] - m);
  red[t] = sum; __syncthreads();
  for (int s = 128; s > 0; s >>= 1) { if (t < s) red[t] += red[t+s]; __syncthreads(); }
  float inv = 1.f / red[0];
  for (int j = t; j < 640; j += 256) out[(size_t)b*640 + j] = expf(logits[(size_t)b*640 + j] - m) * inv;
}

// ---------------- host ----------------
extern "C" void kernel_launch(void* const* d_in, const int* in_sizes, int n_in,
                              void* d_out, int out_size, void* d_ws, size_t ws_size,
                              hipStream_t stream) {
  (void)in_sizes; (void)n_in;
  float* out = (float*)d_out;
  if (ws_size < (size_t)WS_NEED_FLOATS * 4) {
    k_sentinel<<<2048, 256, 0, stream>>>(out, out_size, (float)(ws_size >> 20));
    return;
  }

  const int*   x       = (const int*)d_in[0];
  const float* pos     = (const float*)d_in[1];
  const float* conv1_w = (const float*)d_in[2];
  const float* conv1_b = (const float*)d_in[3];
  const float* rb1_w   = (const float*)d_in[4];
  const float* rb1_b   = (const float*)d_in[5];
  const float* bn1_g   = (const float*)d_in[6];
  const float* bn1_b   = (const float*)d_in[7];
  const float* rb2_w   = (const float*)d_in[8];
  const float* rb2_b   = (const float*)d_in[9];
  const float* bn2_g   = (const float*)d_in[10];
  const float* bn2_b   = (const float*)d_in[11];
  const float* qkv_w   = (const float*)d_in[12];
  const float* qkv_b   = (const float*)d_in[13];
  const float* proj_w  = (const float*)d_in[14];
  const float* proj_b  = (const float*)d_in[15];
  const float* fc1_w   = (const float*)d_in[16];
  const float* fc1_b   = (const float*)d_in[17];
  const float* fc2_w   = (const float*)d_in[18];
  const float* fc2_b   = (const float*)d_in[19];
  const float* lin1_w  = (const float*)d_in[20];
  const float* lin1_b  = (const float*)d_in[21];
  const float* lin2_w  = (const float*)d_in[22];
  const float* lin2_b  = (const float*)d_in[23];

  float*  ws    = (float*)d_ws;
  float*  act   = ws + OFF_ACT;
  __half* big2h = (__half*)(ws + OFF_BIG2);
  float*  wT1   = ws + OFF_WT1;
  __half* wTa16 = (__half*)(ws + OFF_WTA);
  __half* wTb16 = (__half*)(ws + OFF_WTB);
  __half* wTt   = (__half*)(ws + OFF_WTT);
  float*  stats = ws + OFF_STATS;
  float*  bnp   = ws + OFF_BNP;

  __half* z1h     = big2h;
  __half* attnout = big2h + H_ATT;      // CH*16*512 = 16.78M halfs
  __half* projout = big2h + H_PRJ;
  __half* h1      = attnout;            // aliases attnout (dead after proj gemm)
  __half* fc2out  = projout;            // aliases projout (dead after lnres)
  __half* qkvT    = wTt + T_QKV;
  __half* projT   = wTt + T_PRJ;
  __half* fc1T    = wTt + T_F1;
  __half* fc2T    = wTt + T_F2;
  __half* L1h     = big2h;              // head
  float*  logits  = (float*)(big2h + H_LOG);
  __half* lin2T   = wTt;

  k_zero<<<1, 256, 0, stream>>>(stats);
  k_wprep<<<64, 256, 0, stream>>>(conv1_w, wT1, 1, 12);
  k_wprep16<<<2048, 256, 0, stream>>>(rb1_w, wTa16, 10);
  k_wprep16<<<2048, 256, 0, stream>>>(rb2_w, wTb16, 10);
  k_conv1<<<NBATCH, 256, 0, stream>>>(x, wT1, conv1_b, act);

  for (int l = 0; l < 10; ++l) {
    k_conv_mfma<float><<<NBATCH/2, 256, 0, stream>>>(act, wTa16 + (size_t)l*147456,
        rb1_b + l*128, (const float*)nullptr, 0, z1h, stats);
    k_bnfin<<<1, 128, 0, stream>>>(stats, bn1_g + l*128, bn1_b + l*128, bnp);
    k_conv_mfma<__half><<<NBATCH/2, 256, 0, stream>>>(z1h, wTb16 + (size_t)l*147456,
        rb2_b + l*128, bnp, 1, z1h, stats);
    k_bnfin<<<1, 128, 0, stream>>>(stats, bn2_g + l*128, bn2_b + l*128, bnp);
    k_make_t<<<NBATCH, 256, 0, stream>>>(act, z1h, bnp, pos);   // z1h dead after this

    k_wt16x4<<<2048, 256, 0, stream>>>(qkv_w + (size_t)l*786432,
        proj_w + (size_t)l*262144, fc1_w + (size_t)l*262144, fc2_w + (size_t)l*262144, wTt);

    for (int ch = 0; ch < NBATCH/CH; ++ch) {
      float* tchunk = act + (size_t)ch*CH*8192;
      k_qkv_attn<<<dim3(CH/8, 8), 256, 0, stream>>>(tchunk, qkvT, qkv_b + l*1536, attnout);
      k_mgemm<1,1,0,1><<<dim3(CH*16/128, 4), 256, 0, stream>>>(attnout, projT,
          proj_b + l*512, projout, CH*16, 512, 512);
      k_lnres<<<CH*16/4, 256, 0, stream>>>(projout, tchunk);
      k_mgemm<0,1,1,1><<<dim3(CH*16/128, 4), 256, 0, stream>>>(tchunk, fc1T,
          fc1_b + l*512, h1, CH*16, 512, 512);
      k_mgemm<1,1,0,1><<<dim3(CH*16/128, 4), 256, 0, stream>>>(h1, fc2T,
          fc2_b + l*512, fc2out, CH*16, 512, 512);
      k_lnres2<<<CH, 256, 0, stream>>>(fc2out, tchunk);
    }
  }
  k_mgemm<0,0,1,1><<<dim3(4096/128, 8), 256, 0, stream>>>(act, lin1_w, lin1_b, L1h,
      4096, 1024, 8192);
  k_wt16<<<512, 256, 0, stream>>>(lin2_w, lin2T, 1024, 640);
  k_mgemm<1,1,0,0><<<dim3(4096/128, 5), 256, 0, stream>>>(L1h, lin2T, lin2_b, logits,
      4096, 640, 1024);
  k_softmax<<<NBATCH, 256, 0, stream>>>(logits, out);
}

// Round 8
// 10439.886 us; speedup vs baseline: 29.1169x; 1.1217x over previous
//
#include <hip/hip_runtime.h>
#include <hip/hip_fp16.h>
#include <math.h>

// betaChessAI forward: 10 blocks of {conv-bn-conv-bn residual, windowed attention, MLP}
// Layouts:
//   spatial activations: act[(b*64 + p)*128 + c], p = y*8+x   (== feat layout for head)
//   token activations:   t[(b*16 + n)*512 + d],  d = (p1*2+p2)*128 + c, n = hy*4+wx
// Workspace (float slots), ~210.4 MB:
//   act f32 (33.55M) | big2 (16.78M f32 = 33.55M halfs) | wT1 f32 | wTa16/wTb16 f16 | wTt f16 | stats | bnp | biasbuf

#define NBATCH 4096
#define NPOSR  (NBATCH*64)
#define CH     1024                    // images per attention chunk
#define CHT    (CH*16)                 // tokens per chunk = 16384

#define OFF_ACT   0
#define OFF_BIG2  33554432
#define OFF_WT1   (OFF_BIG2 + 16777216)
#define OFF_WTA   (OFF_WT1 + 13824)    // f16 [10][128][1152] in 737,280 f32 slots
#define OFF_WTB   (OFF_WTA + 737280)
#define OFF_WTT   (OFF_WTB + 737280)   // f16 transformer weights, 1,572,864 halfs
#define OFF_STATS (OFF_WTT + 786432)
#define OFF_BNP   (OFF_STATS + 256)
#define OFF_BIAS  (OFF_BNP + 256)      // scaled qkv bias, 1536 f32
#define WS_NEED_FLOATS (OFF_BIAS + 1536)

// big2 half-offsets (transformer phase, CH=1024):
//   qkvbuf [0, 25.17M) ; attnout [25.17M, 33.55M)
//   after attn: projout [0, 8.39M) ; t2h [8.39M, 16.78M) ; h1 = attnout region ; fc2out [0, 8.39M)
#define H_QKVB 0
#define H_ATT  25165824
#define H_PRJ  0
#define H_T2H  8388608
#define H_LOG  8388608                 // head phase: logits f32 at halfs [8.39M, 13.63M)

// wTt half-offsets
#define T_QKV  0
#define T_PRJ  786432
#define T_F1   1048576
#define T_F2   1310720

typedef _Float16 f16x8 __attribute__((ext_vector_type(8)));
typedef _Float16 f16x4 __attribute__((ext_vector_type(4)));
typedef float f32x4 __attribute__((ext_vector_type(4)));

__device__ inline f32x4 vzero4() { f32x4 z; z[0]=0.f; z[1]=0.f; z[2]=0.f; z[3]=0.f; return z; }

__device__ inline float4 ld_half4(const __half* p) {
  float2 a = __half22float2(*(const __half2*)p);
  float2 b = __half22float2(*(const __half2*)(p + 2));
  return make_float4(a.x, a.y, b.x, b.y);
}

// ---------------- utility ----------------
__global__ void k_zero(float* __restrict__ s) { s[threadIdx.x] = 0.f; }

__global__ void k_sentinel(float* __restrict__ out, int n, float val) {
  for (int i = blockIdx.x*blockDim.x + threadIdx.x; i < n; i += gridDim.x*blockDim.x)
    out[i] = val;
}

// src[l][co][ci][kk] (co=128,ci=12,kk=9) -> dst[(kk*12+ci)*128+co]  (conv1 f32 path)
__global__ void k_wprep(const float* __restrict__ src, float* __restrict__ dst, int L, int Cin) {
  int total = L * 128 * Cin * 9;
  for (int idx = blockIdx.x*blockDim.x + threadIdx.x; idx < total; idx += gridDim.x*blockDim.x) {
    int kk = idx % 9; int t2 = idx / 9;
    int ci = t2 % Cin; t2 /= Cin;
    int co = t2 % 128; int l  = t2 / 128;
    dst[((size_t)(l*9 + kk)*Cin + ci)*128 + co] = src[idx];
  }
}

// src[l][co][ci][kk] (128x128x9) -> dst f16 [(l*128+co)*1152 + kk*128 + ci]
__global__ void k_wprep16(const float* __restrict__ src, __half* __restrict__ dst, int L) {
  int total = L * 128 * 128 * 9;
  for (int idx = blockIdx.x*blockDim.x + threadIdx.x; idx < total; idx += gridDim.x*blockDim.x) {
    int kk = idx % 9; int t2 = idx / 9;
    int ci = t2 % 128; t2 /= 128;
    int co = t2 % 128; int l  = t2 / 128;
    dst[((size_t)(l*128 + co))*1152 + kk*128 + ci] = __float2half(src[idx]);
  }
}

// W f32 [K][N] -> WT f16 [N][K]
__global__ void k_wt16(const float* __restrict__ W, __half* __restrict__ WT, int K, int N) {
  int total = K * N;
  for (int idx = blockIdx.x*blockDim.x + threadIdx.x; idx < total; idx += gridDim.x*blockDim.x) {
    int k = idx / N, n = idx % N;
    WT[(size_t)n*K + k] = __float2half(W[idx]);
  }
}

// One layer's qkv/proj/fc1/fc2 f32 -> transposed f16 into wTt.
// q columns (n<512) of Wq and qkv bias are pre-scaled by hd^-0.5 = 0.125.
__global__ void k_wt16x4(const float* __restrict__ Wq, const float* __restrict__ Wp,
                         const float* __restrict__ W1, const float* __restrict__ W2,
                         const float* __restrict__ bq,
                         __half* __restrict__ wTt, float* __restrict__ biasbuf) {
  int gid0 = blockIdx.x*blockDim.x + threadIdx.x;
  if (gid0 < 1536) biasbuf[gid0] = bq[gid0] * (gid0 < 512 ? 0.125f : 1.f);
  const int TOT = 786432 + 3*262144;
  for (int idx = gid0; idx < TOT; idx += gridDim.x*blockDim.x) {
    if (idx < 786432) {
      int k = idx / 1536, n = idx % 1536;
      float v = Wq[idx] * (n < 512 ? 0.125f : 1.f);
      wTt[T_QKV + (size_t)n*512 + k] = __float2half(v);
    } else {
      int r0 = idx - 786432;
      int s = r0 / 262144, r = r0 % 262144;
      int k = r / 512, n = r % 512;
      const float* W = (s == 0) ? Wp : (s == 1) ? W1 : W2;
      wTt[T_PRJ + s*262144 + (size_t)n*512 + k] = __float2half(W[r]);
    }
  }
}

// ---------------- encode + conv1 (one-hot lookup), output f32 act ----------------
__global__ __launch_bounds__(256) void k_conv1(const int* __restrict__ xin,
    const float* __restrict__ wT1, const float* __restrict__ b1,
    float* __restrict__ out) {
  __shared__ int s_w[64], s_b[64];
  int b = blockIdx.x, t = threadIdx.x;
  if (t < 64) { s_w[t] = xin[b*128 + t]; s_b[t] = xin[b*128 + 64 + t]; }
  __syncthreads();
  int p = t >> 2, i = t & 3;
  int y = p >> 3, x = p & 7;
  float acc[32];
  #pragma unroll
  for (int j = 0; j < 32; ++j) acc[j] = b1[i*32 + j];
  #pragma unroll
  for (int kk = 0; kk < 9; ++kk) {
    int ny = y + kk/3 - 1, nx = x + kk%3 - 1;
    if (ny < 0 || ny > 7 || nx < 0 || nx > 7) continue;
    int np = ny*8 + nx;
    int wp = s_w[np], bp = s_b[np];
    if (wp >= 1 && wp <= 6) {
      const float* w = &wT1[(size_t)(kk*12 + (wp-1))*128 + i*32];
      #pragma unroll
      for (int j = 0; j < 32; ++j) acc[j] += w[j];
    }
    if (bp >= 1 && bp <= 6) {
      const float* w = &wT1[(size_t)(kk*12 + 6 + (bp-1))*128 + i*32];
      #pragma unroll
      for (int j = 0; j < 32; ++j) acc[j] += w[j];
    }
  }
  float* o = &out[((size_t)b*64 + p)*128 + i*32];
  #pragma unroll
  for (int j = 0; j < 8; ++j)
    *(float4*)&o[j*4] = make_float4(acc[j*4], acc[j*4+1], acc[j*4+2], acc[j*4+3]);
}

// ---------------- MFMA residual 3x3 conv + fused BN stats (unchanged from R7) ----------------
__device__ inline float cvt_in(float v) { return v; }
__device__ inline float cvt_in(__half v) { return __half2float(v); }

#define IMG_W 136

template<typename TIN>
__global__ __launch_bounds__(256) void k_conv_mfma(const TIN* __restrict__ in,
    const __half* __restrict__ wT /* [128][1152] f16 */, const float* __restrict__ bias,
    const float* __restrict__ bnp, int use_bn, __half* __restrict__ out,
    float* __restrict__ stats) {
  __shared__ __align__(16) _Float16 s_img[2*65*IMG_W];
  __shared__ __align__(16) _Float16 s_B[128][68];
  __shared__ float s_sum[128], s_sq[128];
  int b2 = blockIdx.x, t = threadIdx.x;
  for (int idx4 = t; idx4 < 4096; idx4 += 256) {
    int img = idx4 >> 11, rr = (idx4 >> 5) & 63, c4 = (idx4 & 31) * 4;
    const TIN* src = &in[((size_t)(b2*2 + img)*64 + rr)*128 + c4];
    float v0 = cvt_in(src[0]), v1 = cvt_in(src[1]), v2 = cvt_in(src[2]), v3 = cvt_in(src[3]);
    if (use_bn) {
      v0 = bnp[c4+0]*v0 + bnp[128+c4+0];
      v1 = bnp[c4+1]*v1 + bnp[128+c4+1];
      v2 = bnp[c4+2]*v2 + bnp[128+c4+2];
      v3 = bnp[c4+3]*v3 + bnp[128+c4+3];
    }
    f16x4 h;
    h[0] = (_Float16)fmaxf(v0, 0.f); h[1] = (_Float16)fmaxf(v1, 0.f);
    h[2] = (_Float16)fmaxf(v2, 0.f); h[3] = (_Float16)fmaxf(v3, 0.f);
    *(f16x4*)&s_img[(img*65 + rr)*IMG_W + c4] = h;
  }
  {
    int img = t >> 7, c = t & 127;
    s_img[(img*65 + 64)*IMG_W + c] = (_Float16)0.f;
    if (t < 128) { s_sum[t] = 0.f; s_sq[t] = 0.f; }
  }
  int w = t >> 6, lane = t & 63;
  int wm = (w >> 1)*64, wn = (w & 1)*64;
  int fr = lane & 15, fq = lane >> 4;
  int imgo[4], yy[4], xx_[4];
  #pragma unroll
  for (int mt = 0; mt < 4; ++mt) {
    int r = wm + mt*16 + fr;
    imgo[mt] = r >> 6; int p = r & 63; yy[mt] = p >> 3; xx_[mt] = p & 7;
  }
  f32x4 acc[4][4];
  #pragma unroll
  for (int mt = 0; mt < 4; ++mt)
    #pragma unroll
    for (int nt = 0; nt < 4; ++nt) acc[mt][nt] = vzero4();
  int sn = t >> 1, skh2 = (t & 1) * 32;
  const __half* wrow = &wT[(size_t)sn*1152];
  for (int kk = 0; kk < 9; ++kk) {
    int dy = kk/3 - 1, dx = kk%3 - 1;
    const _Float16* abase[4];
    #pragma unroll
    for (int mt = 0; mt < 4; ++mt) {
      int ny = yy[mt] + dy, nx = xx_[mt] + dx;
      int row = ((unsigned)ny < 8u && (unsigned)nx < 8u) ? (ny*8 + nx) : 64;
      abase[mt] = &s_img[(imgo[mt]*65 + row)*IMG_W];
    }
    #pragma unroll
    for (int half = 0; half < 2; ++half) {
      int kb = kk*128 + half*64 + skh2;
      __syncthreads();
      *(ulonglong2*)&s_B[sn][skh2+0]  = *(const ulonglong2*)&wrow[kb + 0];
      *(ulonglong2*)&s_B[sn][skh2+8]  = *(const ulonglong2*)&wrow[kb + 8];
      *(ulonglong2*)&s_B[sn][skh2+16] = *(const ulonglong2*)&wrow[kb + 16];
      *(ulonglong2*)&s_B[sn][skh2+24] = *(const ulonglong2*)&wrow[kb + 24];
      __syncthreads();
      #pragma unroll
      for (int ks2 = 0; ks2 < 2; ++ks2) {
        f16x8 af[4], bf[4];
        #pragma unroll
        for (int mt = 0; mt < 4; ++mt) af[mt] = *(const f16x8*)&abase[mt][half*64 + ks2*32 + fq*8];
        #pragma unroll
        for (int nt = 0; nt < 4; ++nt) bf[nt] = *(const f16x8*)&s_B[wn + nt*16 + fr][ks2*32 + fq*8];
        #pragma unroll
        for (int mt = 0; mt < 4; ++mt)
          #pragma unroll
          for (int nt = 0; nt < 4; ++nt)
            acc[mt][nt] = __builtin_amdgcn_mfma_f32_16x16x32_f16(af[mt], bf[nt], acc[mt][nt], 0, 0, 0);
      }
    }
  }
  #pragma unroll
  for (int nt = 0; nt < 4; ++nt) {
    int col = wn + nt*16 + fr;
    float bv = bias[col];
    float s = 0.f, q = 0.f;
    #pragma unroll
    for (int mt = 0; mt < 4; ++mt) {
      int rbase = wm + mt*16 + fq*4;
      #pragma unroll
      for (int j = 0; j < 4; ++j) {
        int r = rbase + j;
        int img = r >> 6, p = r & 63;
        float v = acc[mt][nt][j] + bv;
        s += v; q += v*v;
        out[((size_t)(b2*2 + img)*64 + p)*128 + col] = __float2half(v);
      }
    }
    s += __shfl_xor(s, 16); s += __shfl_xor(s, 32);
    q += __shfl_xor(q, 16); q += __shfl_xor(q, 32);
    if (fq == 0) { atomicAdd(&s_sum[col], s); atomicAdd(&s_sq[col], q); }
  }
  __syncthreads();
  if (t < 128) {
    atomicAdd(&stats[t], s_sum[t]);
    atomicAdd(&stats[128 + t], s_sq[t]);
  }
}

__global__ void k_bnfin(float* __restrict__ stats, const float* __restrict__ g,
                        const float* __restrict__ bb, float* __restrict__ bnp) {
  int c = threadIdx.x;
  const float invN = 1.f / (float)NPOSR;
  float m = stats[c] * invN;
  float v = stats[128+c] * invN - m*m;
  float sc = g[c] * rsqrtf(v + 1e-5f);
  bnp[c] = sc;
  bnp[128+c] = bb[c] - m*sc;
  stats[c] = 0.f; stats[128+c] = 0.f;
}

// ---------------- t = window_partition(act + bn2(z1h)) + pos, in-place per image ----------------
__global__ __launch_bounds__(256) void k_make_t(float* __restrict__ act,
    const __half* __restrict__ z1h, const float* __restrict__ bnp,
    const float* __restrict__ pos) {
  __shared__ float s_t[8192];
  int b = blockIdx.x, t = threadIdx.x;
  for (int idx4 = t; idx4 < 2048; idx4 += 256) {
    int n = idx4 >> 7, d4 = idx4 & 127;
    int d = d4*4, c = d & 127, q = d >> 7;
    int y = ((n>>2)<<1) + (q>>1), xx = ((n&3)<<1) + (q&1);
    size_t sp = ((size_t)b*64 + y*8 + xx)*128 + c;
    float4 a  = *(const float4*)&act[sp];
    float4 z  = ld_half4(&z1h[sp]);
    float4 sc = *(const float4*)&bnp[c];
    float4 sh = *(const float4*)&bnp[128+c];
    float4 pe = *(const float4*)&pos[n*512 + d];
    float4 o;
    o.x = a.x + sc.x*z.x + sh.x + pe.x;
    o.y = a.y + sc.y*z.y + sh.y + pe.y;
    o.z = a.z + sc.z*z.z + sh.z + pe.z;
    o.w = a.w + sc.w*z.w + sh.w + pe.w;
    *(float4*)&s_t[n*512 + d] = o;
  }
  __syncthreads();
  for (int idx4 = t; idx4 < 2048; idx4 += 256)
    *(float4*)&act[(size_t)b*8192 + idx4*4] = *(float4*)&s_t[idx4*4];
}

// ---------------- windowed attention from qkvbuf (1 image per block) ----------------
// qkvbuf rows [img*16+tok][1536] f16: [0,512)=q (pre-scaled), [512,1024)=k, [1024,1536)=v.
// attnout[img*16+qi][512] f16.
#define QS 1544   // padded row stride (halfs), 16B-aligned rows

__global__ __launch_bounds__(256) void k_attn16(const __half* __restrict__ qkvbuf,
    __half* __restrict__ attnout) {
  __shared__ __align__(16) _Float16 s_qkv[16][QS];   // 49,408 B
  __shared__ float S[8][16][17];                     //  8,704 B
  int img = blockIdx.x, t = threadIdx.x;
  const __half* src = qkvbuf + (size_t)img*16*1536;
  #pragma unroll
  for (int i = 0; i < 12; ++i) {
    int lin = t + i*256;
    int row = lin / 192, c8 = lin % 192;
    *(f16x8*)&s_qkv[row][c8*8] = *(const f16x8*)&src[(size_t)row*1536 + c8*8];
  }
  __syncthreads();
  // scores S[h][qi][ki] = sum_d q[qi][h*64+d]*k[ki][512+h*64+d] (q pre-scaled)
  {
    int h = t >> 5, qi = (t >> 1) & 15, ko = (t & 1) * 8;
    int rot = t & 31;                     // per-lane half2-granule rotation (bank spread)
    float acc[8];
    #pragma unroll
    for (int k = 0; k < 8; ++k) acc[k] = 0.f;
    const __half2* qr = (const __half2*)&s_qkv[qi][h*64];
    for (int i2 = 0; i2 < 32; ++i2) {
      int d2 = (i2 + rot) & 31;
      float2 q2 = __half22float2(qr[d2]);
      #pragma unroll
      for (int k = 0; k < 8; ++k) {
        float2 k2 = __half22float2(*(const __half2*)&s_qkv[ko + k][512 + h*64 + d2*2]);
        acc[k] += q2.x*k2.x + q2.y*k2.y;
      }
    }
    #pragma unroll
    for (int k = 0; k < 8; ++k) S[h][qi][ko + k] = acc[k];
  }
  __syncthreads();
  if (t < 128) {
    int h = t >> 4, qi = t & 15;
    float* Sr = S[h][qi];
    float mx = -1e30f;
    #pragma unroll
    for (int ki = 0; ki < 16; ++ki) mx = fmaxf(mx, Sr[ki]);
    float sm = 0.f; float e[16];
    #pragma unroll
    for (int ki = 0; ki < 16; ++ki) { e[ki] = expf(Sr[ki] - mx); sm += e[ki]; }
    float inv = 1.f / sm;
    #pragma unroll
    for (int ki = 0; ki < 16; ++ki) Sr[ki] = e[ki]*inv;
  }
  __syncthreads();
  // out[qi][h*64+dh] = sum_ki P * v[ki][1024+h*64+dh]
  {
    int qi = t >> 4, rem = t & 15;
    int h = rem >> 1, dhb = (rem & 1) * 32;
    int rot = (t >> 2) & 15;              // per-lane ki rotation (bank spread)
    float P[16];
    #pragma unroll
    for (int k = 0; k < 16; ++k) P[k] = S[h][qi][(k + rot) & 15];   // P indexed statically below
    __half* orow = attnout + ((size_t)img*16 + qi)*512 + h*64 + dhb;
    #pragma unroll
    for (int j = 0; j < 16; ++j) {
      int dh = dhb + 2*j;
      float a0 = 0.f, a1 = 0.f;
      #pragma unroll
      for (int kk2 = 0; kk2 < 16; ++kk2) {
        int ki = (kk2 + rot) & 15;
        float2 v2 = __half22float2(*(const __half2*)&s_qkv[ki][1024 + h*64 + dh]);
        a0 += P[kk2]*v2.x; a1 += P[kk2]*v2.y;
      }
      *(__half2*)&orow[2*j] = __floats2half2_rn(a0, a1);
    }
  }
}

// ---------------- generic MFMA GEMM: C = act(A@B + bias), 128x128x32 tiles ----------------
template<int A16, int B16, int RELU, int OUT16>
__global__ __launch_bounds__(256) void k_mgemm(const void* __restrict__ Ap,
    const void* __restrict__ Bp, const float* __restrict__ bias,
    void* __restrict__ Cp, int M, int N, int K) {
  __shared__ _Float16 sA[128][40];
  __shared__ _Float16 sB[128][40];
  int t = threadIdx.x;
  int bm = blockIdx.x * 128, bn = blockIdx.y * 128;
  int w = t >> 6, lane = t & 63;
  int wm = (w >> 1) * 64, wn = (w & 1) * 64;
  int fr = lane & 15, fq = lane >> 4;
  f32x4 acc[4][4];
  #pragma unroll
  for (int mt = 0; mt < 4; ++mt)
    #pragma unroll
    for (int nt = 0; nt < 4; ++nt) acc[mt][nt] = vzero4();
  int srow = t >> 1, skh = (t & 1) * 16;
  for (int k0 = 0; k0 < K; k0 += 32) {
    if (A16) {
      const __half* A = (const __half*)Ap;
      const ulonglong2* src = (const ulonglong2*)&A[(size_t)(bm + srow)*K + k0 + skh];
      *(ulonglong2*)&sA[srow][skh]   = src[0];
      *(ulonglong2*)&sA[srow][skh+8] = src[1];
    } else {
      const float* A = (const float*)Ap;
      const float4* src = (const float4*)&A[(size_t)(bm + srow)*K + k0 + skh];
      float4 v0 = src[0], v1 = src[1], v2 = src[2], v3 = src[3];
      f16x8 h0, h1;
      h0[0]=(_Float16)v0.x; h0[1]=(_Float16)v0.y; h0[2]=(_Float16)v0.z; h0[3]=(_Float16)v0.w;
      h0[4]=(_Float16)v1.x; h0[5]=(_Float16)v1.y; h0[6]=(_Float16)v1.z; h0[7]=(_Float16)v1.w;
      h1[0]=(_Float16)v2.x; h1[1]=(_Float16)v2.y; h1[2]=(_Float16)v2.z; h1[3]=(_Float16)v2.w;
      h1[4]=(_Float16)v3.x; h1[5]=(_Float16)v3.y; h1[6]=(_Float16)v3.z; h1[7]=(_Float16)v3.w;
      *(f16x8*)&sA[srow][skh]   = h0;
      *(f16x8*)&sA[srow][skh+8] = h1;
    }
    if (B16) {
      const __half* BT = (const __half*)Bp;
      const ulonglong2* src = (const ulonglong2*)&BT[(size_t)(bn + srow)*K + k0 + skh];
      *(ulonglong2*)&sB[srow][skh]   = src[0];
      *(ulonglong2*)&sB[srow][skh+8] = src[1];
    } else {
      const float* B = (const float*)Bp;
      int kr = t >> 3, n0 = (t & 7) * 16;
      #pragma unroll
      for (int g = 0; g < 4; ++g) {
        float4 v = *(const float4*)&B[(size_t)(k0 + kr)*N + bn + n0 + g*4];
        sB[n0+g*4+0][kr] = (_Float16)v.x;
        sB[n0+g*4+1][kr] = (_Float16)v.y;
        sB[n0+g*4+2][kr] = (_Float16)v.z;
        sB[n0+g*4+3][kr] = (_Float16)v.w;
      }
    }
    __syncthreads();
    f16x8 af[4], bf[4];
    #pragma unroll
    for (int mt = 0; mt < 4; ++mt) af[mt] = *(const f16x8*)&sA[wm + mt*16 + fr][fq*8];
    #pragma unroll
    for (int nt = 0; nt < 4; ++nt) bf[nt] = *(const f16x8*)&sB[wn + nt*16 + fr][fq*8];
    #pragma unroll
    for (int mt = 0; mt < 4; ++mt)
      #pragma unroll
      for (int nt = 0; nt < 4; ++nt)
        acc[mt][nt] = __builtin_amdgcn_mfma_f32_16x16x32_f16(af[mt], bf[nt], acc[mt][nt], 0, 0, 0);
    __syncthreads();
  }
  #pragma unroll
  for (int mt = 0; mt < 4; ++mt)
    #pragma unroll
    for (int nt = 0; nt < 4; ++nt) {
      int col = bn + wn + nt*16 + fr;
      float bv = bias[col];
      #pragma unroll
      for (int j = 0; j < 4; ++j) {
        int row = bm + wm + mt*16 + fq*4 + j;
        float v = acc[mt][nt][j] + bv;
        if (RELU) v = fmaxf(v, 0.f);
        if (OUT16) ((__half*)Cp)[(size_t)row*N + col] = __float2half(v);
        else       ((float*)Cp)[(size_t)row*N + col] = v;
      }
    }
}

// ---------------- t2 = t + LN(gemm_out): updates act (token layout) + writes f16 copy ----------------
__global__ __launch_bounds__(256) void k_lnres(const __half* __restrict__ pout,
    float* __restrict__ tact, __half* __restrict__ t2h) {
  int t = threadIdx.x;
  int tok = blockIdx.x*4 + (t >> 6);
  int lane = t & 63;
  f16x8 hv = *(const f16x8*)&pout[(size_t)tok*512 + lane*8];
  float v[8]; float s1 = 0.f, s2 = 0.f;
  #pragma unroll
  for (int j = 0; j < 8; ++j) { v[j] = (float)hv[j]; s1 += v[j]; s2 += v[j]*v[j]; }
  #pragma unroll
  for (int m = 32; m >= 1; m >>= 1) { s1 += __shfl_xor(s1, m); s2 += __shfl_xor(s2, m); }
  float mean = s1 * (1.f/512.f);
  float var  = s2 * (1.f/512.f) - mean*mean;
  float rs = rsqrtf(var + 1e-6f);
  float* ar = &tact[(size_t)tok*512 + lane*8];
  f16x8 o16;
  #pragma unroll
  for (int j = 0; j < 8; ++j) {
    float t2 = ar[j] + (v[j] - mean)*rs;
    ar[j] = t2;
    o16[j] = (_Float16)t2;
  }
  *(f16x8*)&t2h[(size_t)tok*512 + lane*8] = o16;
}

// ---------------- t2 + LN(fc2out), window_reverse to spatial, per image in-place ----------------
__global__ __launch_bounds__(256) void k_lnres2(const __half* __restrict__ fout,
    float* __restrict__ actimg) {
  __shared__ float s_t2[8192];
  int bimg = blockIdx.x, t = threadIdx.x;
  int lane = t & 63;
  for (int tg = 0; tg < 4; ++tg) {
    int n = tg*4 + (t >> 6);
    size_t row = (size_t)bimg*16 + n;
    f16x8 hv = *(const f16x8*)&fout[row*512 + lane*8];
    float v[8]; float s1 = 0.f, s2 = 0.f;
    #pragma unroll
    for (int j = 0; j < 8; ++j) { v[j] = (float)hv[j]; s1 += v[j]; s2 += v[j]*v[j]; }
    #pragma unroll
    for (int m = 32; m >= 1; m >>= 1) { s1 += __shfl_xor(s1, m); s2 += __shfl_xor(s2, m); }
    float mean = s1 * (1.f/512.f);
    float var  = s2 * (1.f/512.f) - mean*mean;
    float rs = rsqrtf(var + 1e-6f);
    const float* ar = &actimg[row*512 + lane*8];
    #pragma unroll
    for (int j = 0; j < 8; ++j) s_t2[n*512 + lane*8 + j] = ar[j] + (v[j] - mean)*rs;
  }
  __syncthreads();
  for (int idx = t; idx < 2048; idx += 256) {
    int p = idx >> 5, c = (idx & 31)*4;
    int y = p >> 3, x = p & 7;
    int n = (y >> 1)*4 + (x >> 1);
    int d = ((y & 1)*2 + (x & 1))*128 + c;
    *(float4*)&actimg[(size_t)bimg*8192 + p*128 + c] = *(float4*)&s_t2[n*512 + d];
  }
}

// ---------------- row softmax (640) ----------------
__global__ __launch_bounds__(256) void k_softmax(const float* __restrict__ logits, float* __restrict__ out) {
  int b = blockIdx.x, t = threadIdx.x;
  __shared__ float red[256];
  float m = -1e30f;
  for (int j = t; j < 640; j += 256) m = fmaxf(m, logits[(size_t)b*640 + j]);
  red[t] = m; __syncthreads();
  for (int s = 128; s > 0; s >>= 1) { if (t < s) red[t] = fmaxf(red[t], red[t+s]); __syncthreads(); }
  m = red[0]; __syncthreads();
  float sum = 0.f;
  for (int j = t; j < 640; j += 256) sum += expf(logits[(size_t)b*640 + j] - m);
  red[t] = sum; __syncthreads();
  for (int s = 128; s > 0; s >>= 1) { if (t < s) red[t] += red[t+s]; __syncthreads(); }
  float inv = 1.f / red[0];
  for (int j = t; j < 640; j += 256) out[(size_t)b*640 + j] = expf(logits[(size_t)b*640 + j] - m) * inv;
}

// ---------------- host ----------------
extern "C" void kernel_launch(void* const* d_in, const int* in_sizes, int n_in,
                              void* d_out, int out_size, void* d_ws, size_t ws_size,
                              hipStream_t stream) {
  (void)in_sizes; (void)n_in;
  float* out = (float*)d_out;
  if (ws_size < (size_t)WS_NEED_FLOATS * 4) {
    k_sentinel<<<2048, 256, 0, stream>>>(out, out_size, (float)(ws_size >> 20));
    return;
  }

  const int*   x       = (const int*)d_in[0];
  const float* pos     = (const float*)d_in[1];
  const float* conv1_w = (const float*)d_in[2];
  const float* conv1_b = (const float*)d_in[3];
  const float* rb1_w   = (const float*)d_in[4];
  const float* rb1_b   = (const float*)d_in[5];
  const float* bn1_g   = (const float*)d_in[6];
  const float* bn1_b   = (const float*)d_in[7];
  const float* rb2_w   = (const float*)d_in[8];
  const float* rb2_b   = (const float*)d_in[9];
  const float* bn2_g   = (const float*)d_in[10];
  const float* bn2_b   = (const float*)d_in[11];
  const float* qkv_w   = (const float*)d_in[12];
  const float* qkv_b   = (const float*)d_in[13];
  const float* proj_w  = (const float*)d_in[14];
  const float* proj_b  = (const float*)d_in[15];
  const float* fc1_w   = (const float*)d_in[16];
  const float* fc1_b   = (const float*)d_in[17];
  const float* fc2_w   = (const float*)d_in[18];
  const float* fc2_b   = (const float*)d_in[19];
  const float* lin1_w  = (const float*)d_in[20];
  const float* lin1_b  = (const float*)d_in[21];
  const float* lin2_w  = (const float*)d_in[22];
  const float* lin2_b  = (const float*)d_in[23];

  float*  ws    = (float*)d_ws;
  float*  act   = ws + OFF_ACT;
  __half* big2h = (__half*)(ws + OFF_BIG2);
  float*  wT1   = ws + OFF_WT1;
  __half* wTa16 = (__half*)(ws + OFF_WTA);
  __half* wTb16 = (__half*)(ws + OFF_WTB);
  __half* wTt   = (__half*)(ws + OFF_WTT);
  float*  stats = ws + OFF_STATS;
  float*  bnp   = ws + OFF_BNP;
  float*  biasbuf = ws + OFF_BIAS;

  __half* z1h     = big2h;
  __half* qkvbuf  = big2h + H_QKVB;     // 25.2M halfs
  __half* attnout = big2h + H_ATT;      // 8.4M halfs
  __half* projout = big2h + H_PRJ;      // overlays qkvbuf (dead after attn)
  __half* t2h     = big2h + H_T2H;      // overlays qkvbuf tail
  __half* h1      = attnout;            // attnout dead after proj gemm
  __half* fc2out  = projout;            // projout dead after lnres
  __half* qkvT    = wTt + T_QKV;
  __half* projT   = wTt + T_PRJ;
  __half* fc1T    = wTt + T_F1;
  __half* fc2T    = wTt + T_F2;
  __half* L1h     = big2h;              // head
  float*  logits  = (float*)(big2h + H_LOG);
  __half* lin2T   = wTt;

  k_zero<<<1, 256, 0, stream>>>(stats);
  k_wprep<<<64, 256, 0, stream>>>(conv1_w, wT1, 1, 12);
  k_wprep16<<<2048, 256, 0, stream>>>(rb1_w, wTa16, 10);
  k_wprep16<<<2048, 256, 0, stream>>>(rb2_w, wTb16, 10);
  k_conv1<<<NBATCH, 256, 0, stream>>>(x, wT1, conv1_b, act);

  for (int l = 0; l < 10; ++l) {
    k_conv_mfma<float><<<NBATCH/2, 256, 0, stream>>>(act, wTa16 + (size_t)l*147456,
        rb1_b + l*128, (const float*)nullptr, 0, z1h, stats);
    k_bnfin<<<1, 128, 0, stream>>>(stats, bn1_g + l*128, bn1_b + l*128, bnp);
    k_conv_mfma<__half><<<NBATCH/2, 256, 0, stream>>>(z1h, wTb16 + (size_t)l*147456,
        rb2_b + l*128, bnp, 1, z1h, stats);
    k_bnfin<<<1, 128, 0, stream>>>(stats, bn2_g + l*128, bn2_b + l*128, bnp);
    k_make_t<<<NBATCH, 256, 0, stream>>>(act, z1h, bnp, pos);   // z1h dead after this

    k_wt16x4<<<2048, 256, 0, stream>>>(qkv_w + (size_t)l*786432,
        proj_w + (size_t)l*262144, fc1_w + (size_t)l*262144, fc2_w + (size_t)l*262144,
        qkv_b + l*1536, wTt, biasbuf);

    for (int ch = 0; ch < NBATCH/CH; ++ch) {
      float* tchunk = act + (size_t)ch*CH*8192;
      // qkv = t @ Wqkv + b (q pre-scaled)
      k_mgemm<0,1,0,1><<<dim3(CHT/128, 12), 256, 0, stream>>>(tchunk, qkvT,
          biasbuf, qkvbuf, CHT, 1536, 512);
      k_attn16<<<CH, 256, 0, stream>>>(qkvbuf, attnout);
      k_mgemm<1,1,0,1><<<dim3(CHT/128, 4), 256, 0, stream>>>(attnout, projT,
          proj_b + l*512, projout, CHT, 512, 512);
      k_lnres<<<CHT/4, 256, 0, stream>>>(projout, tchunk, t2h);
      k_mgemm<1,1,1,1><<<dim3(CHT/128, 4), 256, 0, stream>>>(t2h, fc1T,
          fc1_b + l*512, h1, CHT, 512, 512);
      k_mgemm<1,1,0,1><<<dim3(CHT/128, 4), 256, 0, stream>>>(h1, fc2T,
          fc2_b + l*512, fc2out, CHT, 512, 512);
      k_lnres2<<<CH, 256, 0, stream>>>(fc2out, tchunk);
    }
  }
  k_mgemm<0,0,1,1><<<dim3(4096/128, 8), 256, 0, stream>>>(act, lin1_w, lin1_b, L1h,
      4096, 1024, 8192);
  k_wt16<<<512, 256, 0, stream>>>(lin2_w, lin2T, 1024, 640);
  k_mgemm<1,1,0,0><<<dim3(4096/128, 5), 256, 0, stream>>>(L1h, lin2T, lin2_b, logits,
      4096, 640, 1024);
  k_softmax<<<NBATCH, 256, 0, stream>>>(logits, out);
}

// Round 9
// 10156.314 us; speedup vs baseline: 29.9298x; 1.0279x over previous
//
#include <hip/hip_runtime.h>
#include <hip/hip_fp16.h>
#include <math.h>

// betaChessAI forward: 10 blocks of {conv-bn-conv-bn residual, windowed attention, MLP}
// Layouts:
//   spatial activations: act[(b*64 + p)*128 + c], p = y*8+x   (== feat layout for head)
//   token activations:   t[(b*16 + n)*512 + d],  d = (p1*2+p2)*128 + c, n = hy*4+wx
// Workspace (float slots), ~210.4 MB:
//   act f32 (33.55M) | big2 (16.78M f32 = 33.55M halfs) | wT1 f32 | wTa16/wTb16 f16 | wTt f16 | stats | bnp | biasbuf

#define NBATCH 4096
#define NPOSR  (NBATCH*64)
#define CH     1024                    // images per attention chunk
#define CHT    (CH*16)                 // tokens per chunk = 16384

#define OFF_ACT   0
#define OFF_BIG2  33554432
#define OFF_WT1   (OFF_BIG2 + 16777216)
#define OFF_WTA   (OFF_WT1 + 13824)    // f16 [10][128][1152] in 737,280 f32 slots
#define OFF_WTB   (OFF_WTA + 737280)
#define OFF_WTT   (OFF_WTB + 737280)   // f16 transformer weights, 1,572,864 halfs
#define OFF_STATS (OFF_WTT + 786432)
#define OFF_BNP   (OFF_STATS + 256)
#define OFF_BIAS  (OFF_BNP + 256)      // scaled qkv bias, 1536 f32
#define WS_NEED_FLOATS (OFF_BIAS + 1536)

// big2 half-offsets (transformer phase, CH=1024):
#define H_QKVB 0
#define H_ATT  25165824
#define H_PRJ  0
#define H_T2H  8388608
#define H_LOG  8388608                 // head phase: logits f32 at halfs [8.39M, 13.63M)

// wTt half-offsets
#define T_QKV  0
#define T_PRJ  786432
#define T_F1   1048576
#define T_F2   1310720

typedef _Float16 f16x8 __attribute__((ext_vector_type(8)));
typedef _Float16 f16x4 __attribute__((ext_vector_type(4)));
typedef float f32x4 __attribute__((ext_vector_type(4)));

__device__ inline f32x4 vzero4() { f32x4 z; z[0]=0.f; z[1]=0.f; z[2]=0.f; z[3]=0.f; return z; }

__device__ inline float4 ld_half4(const __half* p) {
  float2 a = __half22float2(*(const __half2*)p);
  float2 b = __half22float2(*(const __half2*)(p + 2));
  return make_float4(a.x, a.y, b.x, b.y);
}

// async global->LDS 16B per lane: lds dest = (wave-uniform base) + lane*16B
__device__ __forceinline__ void gll16(const void* g, void* lds) {
  __builtin_amdgcn_global_load_lds(
      (__attribute__((address_space(1))) void*)g,
      (__attribute__((address_space(3))) void*)lds,
      16, 0, 0);
}

// ---------------- utility ----------------
__global__ void k_zero(float* __restrict__ s) { s[threadIdx.x] = 0.f; }

__global__ void k_sentinel(float* __restrict__ out, int n, float val) {
  for (int i = blockIdx.x*blockDim.x + threadIdx.x; i < n; i += gridDim.x*blockDim.x)
    out[i] = val;
}

// src[l][co][ci][kk] (co=128,ci=12,kk=9) -> dst[(kk*12+ci)*128+co]  (conv1 f32 path)
__global__ void k_wprep(const float* __restrict__ src, float* __restrict__ dst, int L, int Cin) {
  int total = L * 128 * Cin * 9;
  for (int idx = blockIdx.x*blockDim.x + threadIdx.x; idx < total; idx += gridDim.x*blockDim.x) {
    int kk = idx % 9; int t2 = idx / 9;
    int ci = t2 % Cin; t2 /= Cin;
    int co = t2 % 128; int l  = t2 / 128;
    dst[((size_t)(l*9 + kk)*Cin + ci)*128 + co] = src[idx];
  }
}

// src[l][co][ci][kk] (128x128x9) -> dst f16 [(l*128+co)*1152 + kk*128 + ci]
__global__ void k_wprep16(const float* __restrict__ src, __half* __restrict__ dst, int L) {
  int total = L * 128 * 128 * 9;
  for (int idx = blockIdx.x*blockDim.x + threadIdx.x; idx < total; idx += gridDim.x*blockDim.x) {
    int kk = idx % 9; int t2 = idx / 9;
    int ci = t2 % 128; t2 /= 128;
    int co = t2 % 128; int l  = t2 / 128;
    dst[((size_t)(l*128 + co))*1152 + kk*128 + ci] = __float2half(src[idx]);
  }
}

// W f32 [K][N] -> WT f16 [N][K]
__global__ void k_wt16(const float* __restrict__ W, __half* __restrict__ WT, int K, int N) {
  int total = K * N;
  for (int idx = blockIdx.x*blockDim.x + threadIdx.x; idx < total; idx += gridDim.x*blockDim.x) {
    int k = idx / N, n = idx % N;
    WT[(size_t)n*K + k] = __float2half(W[idx]);
  }
}

// One layer's qkv/proj/fc1/fc2 f32 -> transposed f16 into wTt.
// q columns (n<512) of Wq and qkv bias are pre-scaled by hd^-0.5 = 0.125.
__global__ void k_wt16x4(const float* __restrict__ Wq, const float* __restrict__ Wp,
                         const float* __restrict__ W1, const float* __restrict__ W2,
                         const float* __restrict__ bq,
                         __half* __restrict__ wTt, float* __restrict__ biasbuf) {
  int gid0 = blockIdx.x*blockDim.x + threadIdx.x;
  if (gid0 < 1536) biasbuf[gid0] = bq[gid0] * (gid0 < 512 ? 0.125f : 1.f);
  const int TOT = 786432 + 3*262144;
  for (int idx = gid0; idx < TOT; idx += gridDim.x*blockDim.x) {
    if (idx < 786432) {
      int k = idx / 1536, n = idx % 1536;
      float v = Wq[idx] * (n < 512 ? 0.125f : 1.f);
      wTt[T_QKV + (size_t)n*512 + k] = __float2half(v);
    } else {
      int r0 = idx - 786432;
      int s = r0 / 262144, r = r0 % 262144;
      int k = r / 512, n = r % 512;
      const float* W = (s == 0) ? Wp : (s == 1) ? W1 : W2;
      wTt[T_PRJ + s*262144 + (size_t)n*512 + k] = __float2half(W[r]);
    }
  }
}

// ---------------- encode + conv1 (one-hot lookup), output f32 act ----------------
__global__ __launch_bounds__(256) void k_conv1(const int* __restrict__ xin,
    const float* __restrict__ wT1, const float* __restrict__ b1,
    float* __restrict__ out) {
  __shared__ int s_w[64], s_b[64];
  int b = blockIdx.x, t = threadIdx.x;
  if (t < 64) { s_w[t] = xin[b*128 + t]; s_b[t] = xin[b*128 + 64 + t]; }
  __syncthreads();
  int p = t >> 2, i = t & 3;
  int y = p >> 3, x = p & 7;
  float acc[32];
  #pragma unroll
  for (int j = 0; j < 32; ++j) acc[j] = b1[i*32 + j];
  #pragma unroll
  for (int kk = 0; kk < 9; ++kk) {
    int ny = y + kk/3 - 1, nx = x + kk%3 - 1;
    if (ny < 0 || ny > 7 || nx < 0 || nx > 7) continue;
    int np = ny*8 + nx;
    int wp = s_w[np], bp = s_b[np];
    if (wp >= 1 && wp <= 6) {
      const float* w = &wT1[(size_t)(kk*12 + (wp-1))*128 + i*32];
      #pragma unroll
      for (int j = 0; j < 32; ++j) acc[j] += w[j];
    }
    if (bp >= 1 && bp <= 6) {
      const float* w = &wT1[(size_t)(kk*12 + 6 + (bp-1))*128 + i*32];
      #pragma unroll
      for (int j = 0; j < 32; ++j) acc[j] += w[j];
    }
  }
  float* o = &out[((size_t)b*64 + p)*128 + i*32];
  #pragma unroll
  for (int j = 0; j < 8; ++j)
    *(float4*)&o[j*4] = make_float4(acc[j*4], acc[j*4+1], acc[j*4+2], acc[j*4+3]);
}

// ---------------- MFMA residual 3x3 conv + fused BN stats ----------------
// 2 images per block, M=128, N=128, K=1152 = 36 windows of 32.
// Double-buffered weight staging via global_load_lds; 1 barrier per window.
__device__ inline float cvt_in(float v) { return v; }
__device__ inline float cvt_in(__half v) { return __half2float(v); }

#define IMG_W 136

template<typename TIN>
__global__ __launch_bounds__(256) void k_conv_mfma(const TIN* __restrict__ in,
    const __half* __restrict__ wT /* [128][1152] f16 */, const float* __restrict__ bias,
    const float* __restrict__ bnp, int use_bn, __half* __restrict__ out,
    float* __restrict__ stats) {
  __shared__ __align__(16) _Float16 s_img[2*65*IMG_W];  // 35,360 B (row 64 = zeros)
  __shared__ __align__(16) _Float16 s_B[2][4096];       // 2 x [128][32] linear, 16 KB
  __shared__ float s_sum[128], s_sq[128];               // 1 KB
  int b2 = blockIdx.x, t = threadIdx.x;
  int w = t >> 6, lane = t & 63;

  // issue weight window 'win' into buffer 'buf' (async)
  auto issueB = [&](int win, int buf) {
    #pragma unroll
    for (int i = 0; i < 2; ++i) {
      int rbase = (w*2 + i)*16;
      const __half* g = &wT[(size_t)(rbase + (lane>>2))*1152 + win*32 + (lane&3)*8];
      gll16(g, &s_B[buf][rbase*32]);
    }
  };
  issueB(0, 0);

  // stage 2 images: bn+relu, -> f16
  for (int idx4 = t; idx4 < 4096; idx4 += 256) {
    int img = idx4 >> 11, rr = (idx4 >> 5) & 63, c4 = (idx4 & 31) * 4;
    const TIN* src = &in[((size_t)(b2*2 + img)*64 + rr)*128 + c4];
    float v0 = cvt_in(src[0]), v1 = cvt_in(src[1]), v2 = cvt_in(src[2]), v3 = cvt_in(src[3]);
    if (use_bn) {
      v0 = bnp[c4+0]*v0 + bnp[128+c4+0];
      v1 = bnp[c4+1]*v1 + bnp[128+c4+1];
      v2 = bnp[c4+2]*v2 + bnp[128+c4+2];
      v3 = bnp[c4+3]*v3 + bnp[128+c4+3];
    }
    f16x4 h;
    h[0] = (_Float16)fmaxf(v0, 0.f); h[1] = (_Float16)fmaxf(v1, 0.f);
    h[2] = (_Float16)fmaxf(v2, 0.f); h[3] = (_Float16)fmaxf(v3, 0.f);
    *(f16x4*)&s_img[(img*65 + rr)*IMG_W + c4] = h;
  }
  {
    int img = t >> 7, c = t & 127;
    s_img[(img*65 + 64)*IMG_W + c] = (_Float16)0.f;
    if (t < 128) { s_sum[t] = 0.f; s_sq[t] = 0.f; }
  }
  int wm = (w >> 1)*64, wn = (w & 1)*64;
  int fr = lane & 15, fq = lane >> 4;
  int imgo[4], yy[4], xx_[4];
  #pragma unroll
  for (int mt = 0; mt < 4; ++mt) {
    int r = wm + mt*16 + fr;
    imgo[mt] = r >> 6; int p = r & 63; yy[mt] = p >> 3; xx_[mt] = p & 7;
  }
  f32x4 acc[4][4];
  #pragma unroll
  for (int mt = 0; mt < 4; ++mt)
    #pragma unroll
    for (int nt = 0; nt < 4; ++nt) acc[mt][nt] = vzero4();
  __syncthreads();   // image + weight window 0 ready

  #pragma unroll
  for (int kk = 0; kk < 9; ++kk) {
    int dy = kk/3 - 1, dx = kk%3 - 1;
    const _Float16* abase[4];
    #pragma unroll
    for (int mt = 0; mt < 4; ++mt) {
      int ny = yy[mt] + dy, nx = xx_[mt] + dx;
      int row = ((unsigned)ny < 8u && (unsigned)nx < 8u) ? (ny*8 + nx) : 64;
      abase[mt] = &s_img[(imgo[mt]*65 + row)*IMG_W];
    }
    #pragma unroll
    for (int q = 0; q < 4; ++q) {
      int win = kk*4 + q;
      int buf = win & 1;
      if (win + 1 < 36) issueB(win + 1, buf ^ 1);
      f16x8 af[4], bf[4];
      #pragma unroll
      for (int mt = 0; mt < 4; ++mt) af[mt] = *(const f16x8*)&abase[mt][q*32 + fq*8];
      #pragma unroll
      for (int nt = 0; nt < 4; ++nt) bf[nt] = *(const f16x8*)&s_B[buf][(wn + nt*16 + fr)*32 + fq*8];
      #pragma unroll
      for (int mt = 0; mt < 4; ++mt)
        #pragma unroll
        for (int nt = 0; nt < 4; ++nt)
          acc[mt][nt] = __builtin_amdgcn_mfma_f32_16x16x32_f16(af[mt], bf[nt], acc[mt][nt], 0, 0, 0);
      __syncthreads();
    }
  }
  // epilogue: bias, write f16, fused per-channel stats
  #pragma unroll
  for (int nt = 0; nt < 4; ++nt) {
    int col = wn + nt*16 + fr;
    float bv = bias[col];
    float s = 0.f, q = 0.f;
    #pragma unroll
    for (int mt = 0; mt < 4; ++mt) {
      int rbase = wm + mt*16 + fq*4;
      #pragma unroll
      for (int j = 0; j < 4; ++j) {
        int r = rbase + j;
        int img = r >> 6, p = r & 63;
        float v = acc[mt][nt][j] + bv;
        s += v; q += v*v;
        out[((size_t)(b2*2 + img)*64 + p)*128 + col] = __float2half(v);
      }
    }
    s += __shfl_xor(s, 16); s += __shfl_xor(s, 32);
    q += __shfl_xor(q, 16); q += __shfl_xor(q, 32);
    if (fq == 0) { atomicAdd(&s_sum[col], s); atomicAdd(&s_sq[col], q); }
  }
  __syncthreads();
  if (t < 128) {
    atomicAdd(&stats[t], s_sum[t]);
    atomicAdd(&stats[128 + t], s_sq[t]);
  }
}

__global__ void k_bnfin(float* __restrict__ stats, const float* __restrict__ g,
                        const float* __restrict__ bb, float* __restrict__ bnp) {
  int c = threadIdx.x;
  const float invN = 1.f / (float)NPOSR;
  float m = stats[c] * invN;
  float v = stats[128+c] * invN - m*m;
  float sc = g[c] * rsqrtf(v + 1e-5f);
  bnp[c] = sc;
  bnp[128+c] = bb[c] - m*sc;
  stats[c] = 0.f; stats[128+c] = 0.f;
}

// ---------------- t = window_partition(act + bn2(z1h)) + pos, in-place per image ----------------
__global__ __launch_bounds__(256) void k_make_t(float* __restrict__ act,
    const __half* __restrict__ z1h, const float* __restrict__ bnp,
    const float* __restrict__ pos) {
  __shared__ float s_t[8192];
  int b = blockIdx.x, t = threadIdx.x;
  for (int idx4 = t; idx4 < 2048; idx4 += 256) {
    int n = idx4 >> 7, d4 = idx4 & 127;
    int d = d4*4, c = d & 127, q = d >> 7;
    int y = ((n>>2)<<1) + (q>>1), xx = ((n&3)<<1) + (q&1);
    size_t sp = ((size_t)b*64 + y*8 + xx)*128 + c;
    float4 a  = *(const float4*)&act[sp];
    float4 z  = ld_half4(&z1h[sp]);
    float4 sc = *(const float4*)&bnp[c];
    float4 sh = *(const float4*)&bnp[128+c];
    float4 pe = *(const float4*)&pos[n*512 + d];
    float4 o;
    o.x = a.x + sc.x*z.x + sh.x + pe.x;
    o.y = a.y + sc.y*z.y + sh.y + pe.y;
    o.z = a.z + sc.z*z.z + sh.z + pe.z;
    o.w = a.w + sc.w*z.w + sh.w + pe.w;
    *(float4*)&s_t[n*512 + d] = o;
  }
  __syncthreads();
  for (int idx4 = t; idx4 < 2048; idx4 += 256)
    *(float4*)&act[(size_t)b*8192 + idx4*4] = *(float4*)&s_t[idx4*4];
}

// ---------------- windowed attention from qkvbuf (1 image per block) ----------------
#define QS 1544   // padded row stride (halfs), 16B-aligned rows

__global__ __launch_bounds__(256) void k_attn16(const __half* __restrict__ qkvbuf,
    __half* __restrict__ attnout) {
  __shared__ __align__(16) _Float16 s_qkv[16][QS];   // 49,408 B
  __shared__ float S[8][16][17];                     //  8,704 B
  int img = blockIdx.x, t = threadIdx.x;
  const __half* src = qkvbuf + (size_t)img*16*1536;
  #pragma unroll
  for (int i = 0; i < 12; ++i) {
    int lin = t + i*256;
    int row = lin / 192, c8 = lin % 192;
    *(f16x8*)&s_qkv[row][c8*8] = *(const f16x8*)&src[(size_t)row*1536 + c8*8];
  }
  __syncthreads();
  {
    int h = t >> 5, qi = (t >> 1) & 15, ko = (t & 1) * 8;
    int rot = t & 31;
    float acc[8];
    #pragma unroll
    for (int k = 0; k < 8; ++k) acc[k] = 0.f;
    const __half2* qr = (const __half2*)&s_qkv[qi][h*64];
    for (int i2 = 0; i2 < 32; ++i2) {
      int d2 = (i2 + rot) & 31;
      float2 q2 = __half22float2(qr[d2]);
      #pragma unroll
      for (int k = 0; k < 8; ++k) {
        float2 k2 = __half22float2(*(const __half2*)&s_qkv[ko + k][512 + h*64 + d2*2]);
        acc[k] += q2.x*k2.x + q2.y*k2.y;
      }
    }
    #pragma unroll
    for (int k = 0; k < 8; ++k) S[h][qi][ko + k] = acc[k];
  }
  __syncthreads();
  if (t < 128) {
    int h = t >> 4, qi = t & 15;
    float* Sr = S[h][qi];
    float mx = -1e30f;
    #pragma unroll
    for (int ki = 0; ki < 16; ++ki) mx = fmaxf(mx, Sr[ki]);
    float sm = 0.f; float e[16];
    #pragma unroll
    for (int ki = 0; ki < 16; ++ki) { e[ki] = expf(Sr[ki] - mx); sm += e[ki]; }
    float inv = 1.f / sm;
    #pragma unroll
    for (int ki = 0; ki < 16; ++ki) Sr[ki] = e[ki]*inv;
  }
  __syncthreads();
  {
    int qi = t >> 4, rem = t & 15;
    int h = rem >> 1, dhb = (rem & 1) * 32;
    int rot = (t >> 2) & 15;
    float P[16];
    #pragma unroll
    for (int k = 0; k < 16; ++k) P[k] = S[h][qi][(k + rot) & 15];
    __half* orow = attnout + ((size_t)img*16 + qi)*512 + h*64 + dhb;
    #pragma unroll
    for (int j = 0; j < 16; ++j) {
      int dh = dhb + 2*j;
      float a0 = 0.f, a1 = 0.f;
      #pragma unroll
      for (int kk2 = 0; kk2 < 16; ++kk2) {
        int ki = (kk2 + rot) & 15;
        float2 v2 = __half22float2(*(const __half2*)&s_qkv[ki][1024 + h*64 + dh]);
        a0 += P[kk2]*v2.x; a1 += P[kk2]*v2.y;
      }
      *(__half2*)&orow[2*j] = __floats2half2_rn(a0, a1);
    }
  }
}

// ---------------- generic MFMA GEMM: C = act(A@B + bias) ----------------
// Tile BM(=MTI*32) x 128 x 32; linear LDS; global_load_lds for f16 operands;
// double-buffered, 1 barrier per 32-K window.
template<int MTI, int A16, int B16, int RELU, int OUT16>
__global__ __launch_bounds__(256) void k_mgemm(const void* __restrict__ Ap,
    const void* __restrict__ Bp, const float* __restrict__ bias,
    void* __restrict__ Cp, int M, int N, int K) {
  constexpr int BM = MTI*32;
  __shared__ __align__(16) _Float16 sA[2][BM*32];
  __shared__ __align__(16) _Float16 sB[2][128*32];
  int t = threadIdx.x;
  int bm = blockIdx.x * BM, bn = blockIdx.y * 128;
  int w = t >> 6, lane = t & 63;
  int wm = (w >> 1) * (MTI*16), wn = (w & 1) * 64;
  int fr = lane & 15, fq = lane >> 4;

  auto stageA = [&](int k0, int buf) {
    if (A16) {
      const __half* A = (const __half*)Ap;
      constexpr int NI = MTI/2;   // issues per wave (2 for BM=128, 1 for BM=64)
      #pragma unroll
      for (int i = 0; i < NI; ++i) {
        int rbase = (w*NI + i)*16;
        gll16(&A[(size_t)(bm + rbase + (lane>>2))*K + k0 + (lane&3)*8],
              &sA[buf][rbase*32]);
      }
    } else {
      const float* A = (const float*)Ap;
      if (MTI == 4) {
        int srow = t >> 1, skh = (t & 1) * 16;
        const float4* src = (const float4*)&A[(size_t)(bm + srow)*K + k0 + skh];
        float4 v0 = src[0], v1 = src[1], v2 = src[2], v3 = src[3];
        f16x8 h0, h1;
        h0[0]=(_Float16)v0.x; h0[1]=(_Float16)v0.y; h0[2]=(_Float16)v0.z; h0[3]=(_Float16)v0.w;
        h0[4]=(_Float16)v1.x; h0[5]=(_Float16)v1.y; h0[6]=(_Float16)v1.z; h0[7]=(_Float16)v1.w;
        h1[0]=(_Float16)v2.x; h1[1]=(_Float16)v2.y; h1[2]=(_Float16)v2.z; h1[3]=(_Float16)v2.w;
        h1[4]=(_Float16)v3.x; h1[5]=(_Float16)v3.y; h1[6]=(_Float16)v3.z; h1[7]=(_Float16)v3.w;
        *(f16x8*)&sA[buf][srow*32 + skh]     = h0;
        *(f16x8*)&sA[buf][srow*32 + skh + 8] = h1;
      } else {
        int srow = t >> 2, g8 = (t & 3) * 8;
        const float4* src = (const float4*)&A[(size_t)(bm + srow)*K + k0 + g8];
        float4 v0 = src[0], v1 = src[1];
        f16x8 h0;
        h0[0]=(_Float16)v0.x; h0[1]=(_Float16)v0.y; h0[2]=(_Float16)v0.z; h0[3]=(_Float16)v0.w;
        h0[4]=(_Float16)v1.x; h0[5]=(_Float16)v1.y; h0[6]=(_Float16)v1.z; h0[7]=(_Float16)v1.w;
        *(f16x8*)&sA[buf][srow*32 + g8] = h0;
      }
    }
  };
  auto stageB = [&](int k0, int buf) {
    if (B16) {
      const __half* BT = (const __half*)Bp;
      #pragma unroll
      for (int i = 0; i < 2; ++i) {
        int rbase = (w*2 + i)*16;
        gll16(&BT[(size_t)(bn + rbase + (lane>>2))*K + k0 + (lane&3)*8],
              &sB[buf][rbase*32]);
      }
    } else {
      const float* B = (const float*)Bp;
      int kr = t >> 3, n0 = (t & 7) * 16;
      #pragma unroll
      for (int g = 0; g < 4; ++g) {
        float4 v = *(const float4*)&B[(size_t)(k0 + kr)*N + bn + n0 + g*4];
        sB[buf][(n0+g*4+0)*32 + kr] = (_Float16)v.x;
        sB[buf][(n0+g*4+1)*32 + kr] = (_Float16)v.y;
        sB[buf][(n0+g*4+2)*32 + kr] = (_Float16)v.z;
        sB[buf][(n0+g*4+3)*32 + kr] = (_Float16)v.w;
      }
    }
  };

  f32x4 acc[MTI][4];
  #pragma unroll
  for (int mt = 0; mt < MTI; ++mt)
    #pragma unroll
    for (int nt = 0; nt < 4; ++nt) acc[mt][nt] = vzero4();

  stageA(0, 0); stageB(0, 0);
  __syncthreads();
  int KW = K >> 5;
  for (int kw = 0; kw < KW; ++kw) {
    int buf = kw & 1;
    if (kw + 1 < KW) { stageA((kw+1)*32, buf ^ 1); stageB((kw+1)*32, buf ^ 1); }
    f16x8 af[MTI], bf[4];
    #pragma unroll
    for (int mt = 0; mt < MTI; ++mt) af[mt] = *(const f16x8*)&sA[buf][(wm + mt*16 + fr)*32 + fq*8];
    #pragma unroll
    for (int nt = 0; nt < 4; ++nt) bf[nt] = *(const f16x8*)&sB[buf][(wn + nt*16 + fr)*32 + fq*8];
    #pragma unroll
    for (int mt = 0; mt < MTI; ++mt)
      #pragma unroll
      for (int nt = 0; nt < 4; ++nt)
        acc[mt][nt] = __builtin_amdgcn_mfma_f32_16x16x32_f16(af[mt], bf[nt], acc[mt][nt], 0, 0, 0);
    __syncthreads();
  }
  #pragma unroll
  for (int mt = 0; mt < MTI; ++mt)
    #pragma unroll
    for (int nt = 0; nt < 4; ++nt) {
      int col = bn + wn + nt*16 + fr;
      float bv = bias[col];
      #pragma unroll
      for (int j = 0; j < 4; ++j) {
        int row = bm + wm + mt*16 + fq*4 + j;
        float v = acc[mt][nt][j] + bv;
        if (RELU) v = fmaxf(v, 0.f);
        if (OUT16) ((__half*)Cp)[(size_t)row*N + col] = __float2half(v);
        else       ((float*)Cp)[(size_t)row*N + col] = v;
      }
    }
}

// ---------------- t2 = t + LN(gemm_out): updates act (token layout) + writes f16 copy ----------------
__global__ __launch_bounds__(256) void k_lnres(const __half* __restrict__ pout,
    float* __restrict__ tact, __half* __restrict__ t2h) {
  int t = threadIdx.x;
  int tok = blockIdx.x*4 + (t >> 6);
  int lane = t & 63;
  f16x8 hv = *(const f16x8*)&pout[(size_t)tok*512 + lane*8];
  float v[8]; float s1 = 0.f, s2 = 0.f;
  #pragma unroll
  for (int j = 0; j < 8; ++j) { v[j] = (float)hv[j]; s1 += v[j]; s2 += v[j]*v[j]; }
  #pragma unroll
  for (int m = 32; m >= 1; m >>= 1) { s1 += __shfl_xor(s1, m); s2 += __shfl_xor(s2, m); }
  float mean = s1 * (1.f/512.f);
  float var  = s2 * (1.f/512.f) - mean*mean;
  float rs = rsqrtf(var + 1e-6f);
  float* ar = &tact[(size_t)tok*512 + lane*8];
  f16x8 o16;
  #pragma unroll
  for (int j = 0; j < 8; ++j) {
    float t2 = ar[j] + (v[j] - mean)*rs;
    ar[j] = t2;
    o16[j] = (_Float16)t2;
  }
  *(f16x8*)&t2h[(size_t)tok*512 + lane*8] = o16;
}

// ---------------- t2 + LN(fc2out), window_reverse to spatial, per image in-place ----------------
__global__ __launch_bounds__(256) void k_lnres2(const __half* __restrict__ fout,
    float* __restrict__ actimg) {
  __shared__ float s_t2[8192];
  int bimg = blockIdx.x, t = threadIdx.x;
  int lane = t & 63;
  for (int tg = 0; tg < 4; ++tg) {
    int n = tg*4 + (t >> 6);
    size_t row = (size_t)bimg*16 + n;
    f16x8 hv = *(const f16x8*)&fout[row*512 + lane*8];
    float v[8]; float s1 = 0.f, s2 = 0.f;
    #pragma unroll
    for (int j = 0; j < 8; ++j) { v[j] = (float)hv[j]; s1 += v[j]; s2 += v[j]*v[j]; }
    #pragma unroll
    for (int m = 32; m >= 1; m >>= 1) { s1 += __shfl_xor(s1, m); s2 += __shfl_xor(s2, m); }
    float mean = s1 * (1.f/512.f);
    float var  = s2 * (1.f/512.f) - mean*mean;
    float rs = rsqrtf(var + 1e-6f);
    const float* ar = &actimg[row*512 + lane*8];
    #pragma unroll
    for (int j = 0; j < 8; ++j) s_t2[n*512 + lane*8 + j] = ar[j] + (v[j] - mean)*rs;
  }
  __syncthreads();
  for (int idx = t; idx < 2048; idx += 256) {
    int p = idx >> 5, c = (idx & 31)*4;
    int y = p >> 3, x = p & 7;
    int n = (y >> 1)*4 + (x >> 1);
    int d = ((y & 1)*2 + (x & 1))*128 + c;
    *(float4*)&actimg[(size_t)bimg*8192 + p*128 + c] = *(float4*)&s_t2[n*512 + d];
  }
}

// ---------------- row softmax (640) ----------------
__global__ __launch_bounds__(256) void k_softmax(const float* __restrict__ logits, float* __restrict__ out) {
  int b = blockIdx.x, t = threadIdx.x;
  __shared__ float red[256];
  float m = -1e30f;
  for (int j = t; j < 640; j += 256) m = fmaxf(m, logits[(size_t)b*640 + j]);
  red[t] = m; __syncthreads();
  for (int s = 128; s > 0; s >>= 1) { if (t < s) red[t] = fmaxf(red[t], red[t+s]); __syncthreads(); }
  m = red[0]; __syncthreads();
  float sum = 0.f;
  for (int j = t; j < 640; j += 256) sum += expf(logits[(size_t)b*640 + j] - m);
  red[t] = sum; __syncthreads();
  for (int s = 128; s > 0; s >>= 1) { if (t < s) red[t] += red[t+s]; __syncthreads(); }
  float inv = 1.f / red[0];
  for (int j = t; j < 640; j += 256) out[(size_t)b*640 + j] = expf(logits[(size_t)b*640 + j] - m) * inv;
}

// ---------------- host ----------------
extern "C" void kernel_launch(void* const* d_in, const int* in_sizes, int n_in,
                              void* d_out, int out_size, void* d_ws, size_t ws_size,
                              hipStream_t stream) {
  (void)in_sizes; (void)n_in;
  float* out = (float*)d_out;
  if (ws_size < (size_t)WS_NEED_FLOATS * 4) {
    k_sentinel<<<2048, 256, 0, stream>>>(out, out_size, (float)(ws_size >> 20));
    return;
  }

  const int*   x       = (const int*)d_in[0];
  const float* pos     = (const float*)d_in[1];
  const float* conv1_w = (const float*)d_in[2];
  const float* conv1_b = (const float*)d_in[3];
  const float* rb1_w   = (const float*)d_in[4];
  const float* rb1_b   = (const float*)d_in[5];
  const float* bn1_g   = (const float*)d_in[6];
  const float* bn1_b   = (const float*)d_in[7];
  const float* rb2_w   = (const float*)d_in[8];
  const float* rb2_b   = (const float*)d_in[9];
  const float* bn2_g   = (const float*)d_in[10];
  const float* bn2_b   = (const float*)d_in[11];
  const float* qkv_w   = (const float*)d_in[12];
  const float* qkv_b   = (const float*)d_in[13];
  const float* proj_w  = (const float*)d_in[14];
  const float* proj_b  = (const float*)d_in[15];
  const float* fc1_w   = (const float*)d_in[16];
  const float* fc1_b   = (const float*)d_in[17];
  const float* fc2_w   = (const float*)d_in[18];
  const float* fc2_b   = (const float*)d_in[19];
  const float* lin1_w  = (const float*)d_in[20];
  const float* lin1_b  = (const float*)d_in[21];
  const float* lin2_w  = (const float*)d_in[22];
  const float* lin2_b  = (const float*)d_in[23];

  float*  ws    = (float*)d_ws;
  float*  act   = ws + OFF_ACT;
  __half* big2h = (__half*)(ws + OFF_BIG2);
  float*  wT1   = ws + OFF_WT1;
  __half* wTa16 = (__half*)(ws + OFF_WTA);
  __half* wTb16 = (__half*)(ws + OFF_WTB);
  __half* wTt   = (__half*)(ws + OFF_WTT);
  float*  stats = ws + OFF_STATS;
  float*  bnp   = ws + OFF_BNP;
  float*  biasbuf = ws + OFF_BIAS;

  __half* z1h     = big2h;
  __half* qkvbuf  = big2h + H_QKVB;
  __half* attnout = big2h + H_ATT;
  __half* projout = big2h + H_PRJ;
  __half* t2h     = big2h + H_T2H;
  __half* h1      = attnout;
  __half* fc2out  = projout;
  __half* qkvT    = wTt + T_QKV;
  __half* projT   = wTt + T_PRJ;
  __half* fc1T    = wTt + T_F1;
  __half* fc2T    = wTt + T_F2;
  __half* L1h     = big2h;
  float*  logits  = (float*)(big2h + H_LOG);
  __half* lin2T   = wTt;

  k_zero<<<1, 256, 0, stream>>>(stats);
  k_wprep<<<64, 256, 0, stream>>>(conv1_w, wT1, 1, 12);
  k_wprep16<<<2048, 256, 0, stream>>>(rb1_w, wTa16, 10);
  k_wprep16<<<2048, 256, 0, stream>>>(rb2_w, wTb16, 10);
  k_conv1<<<NBATCH, 256, 0, stream>>>(x, wT1, conv1_b, act);

  for (int l = 0; l < 10; ++l) {
    k_conv_mfma<float><<<NBATCH/2, 256, 0, stream>>>(act, wTa16 + (size_t)l*147456,
        rb1_b + l*128, (const float*)nullptr, 0, z1h, stats);
    k_bnfin<<<1, 128, 0, stream>>>(stats, bn1_g + l*128, bn1_b + l*128, bnp);
    k_conv_mfma<__half><<<NBATCH/2, 256, 0, stream>>>(z1h, wTb16 + (size_t)l*147456,
        rb2_b + l*128, bnp, 1, z1h, stats);
    k_bnfin<<<1, 128, 0, stream>>>(stats, bn2_g + l*128, bn2_b + l*128, bnp);
    k_make_t<<<NBATCH, 256, 0, stream>>>(act, z1h, bnp, pos);   // z1h dead after this

    k_wt16x4<<<2048, 256, 0, stream>>>(qkv_w + (size_t)l*786432,
        proj_w + (size_t)l*262144, fc1_w + (size_t)l*262144, fc2_w + (size_t)l*262144,
        qkv_b + l*1536, wTt, biasbuf);

    for (int ch = 0; ch < NBATCH/CH; ++ch) {
      float* tchunk = act + (size_t)ch*CH*8192;
      // qkv = t @ Wqkv + b (q pre-scaled)
      k_mgemm<4,0,1,0,1><<<dim3(CHT/128, 12), 256, 0, stream>>>(tchunk, qkvT,
          biasbuf, qkvbuf, CHT, 1536, 512);
      k_attn16<<<CH, 256, 0, stream>>>(qkvbuf, attnout);
      k_mgemm<4,1,1,0,1><<<dim3(CHT/128, 4), 256, 0, stream>>>(attnout, projT,
          proj_b + l*512, projout, CHT, 512, 512);
      k_lnres<<<CHT/4, 256, 0, stream>>>(projout, tchunk, t2h);
      k_mgemm<4,1,1,1,1><<<dim3(CHT/128, 4), 256, 0, stream>>>(t2h, fc1T,
          fc1_b + l*512, h1, CHT, 512, 512);
      k_mgemm<4,1,1,0,1><<<dim3(CHT/128, 4), 256, 0, stream>>>(h1, fc2T,
          fc2_b + l*512, fc2out, CHT, 512, 512);
      k_lnres2<<<CH, 256, 0, stream>>>(fc2out, tchunk);
    }
  }
  k_mgemm<2,0,0,1,1><<<dim3(4096/64, 8), 256, 0, stream>>>(act, lin1_w, lin1_b, L1h,
      4096, 1024, 8192);
  k_wt16<<<512, 256, 0, stream>>>(lin2_w, lin2T, 1024, 640);
  k_mgemm<2,1,1,0,0><<<dim3(4096/64, 5), 256, 0, stream>>>(L1h, lin2T, lin2_b, logits,
      4096, 640, 1024);
  k_softmax<<<NBATCH, 256, 0, stream>>>(logits, out);
}